// Round 4
// baseline (530.056 us; speedup 1.0000x reference)
//
#include <hip/hip_runtime.h>

// ============================================================================
// ExplicitSVDBlock round 9 -- ABLATION ROUND (within-probe A/B, rule m164/m165):
//  gemm256_geglu_kernel templated <V>:
//   V0 = full (real output -> hb, used by U2 GEMM)
//   V1 = no in-loop staging/vmcnt (stale LDS; timing isolates staging cost)
//   V2 = no GEGLU epilogue (acc sum + coalesced f32x4 store; keeps MFMAs live)
//   V3 = no in-loop fragment ds_reads (prologue frags reused)
//   V4 = bare skeleton (barriers + MFMA only)
//  V1..V4 write to dead workspace (VTB/OB region). This round's total dur
//  is deliberately inflated ~+180us to attribute the V1 GEMM's 5x overhead.
// ============================================================================

typedef unsigned short u16;
typedef unsigned int u32;
typedef u16 u16x8 __attribute__((ext_vector_type(8)));
typedef __bf16 bf16x8 __attribute__((ext_vector_type(8)));
typedef float f32x4 __attribute__((ext_vector_type(4)));

__device__ __forceinline__ u16 f2bf(float f) {
    u32 u = __builtin_bit_cast(u32, f);
    u += 0x7fff + ((u >> 16) & 1);          // RNE
    return (u16)(u >> 16);
}
__device__ __forceinline__ float bf2f(u16 h) {
    u32 u = ((u32)h) << 16;
    return __builtin_bit_cast(float, u);
}
__device__ __forceinline__ u32 packbf(float a, float b) {
    return __builtin_amdgcn_perm(__builtin_bit_cast(u32, b),
                                 __builtin_bit_cast(u32, a), 0x07060302u);
}

__device__ __forceinline__ void gload16(const void* g, void* l) {
    __builtin_amdgcn_global_load_lds(
        (const __attribute__((address_space(1))) void*)g,
        (__attribute__((address_space(3))) void*)l, 16, 0, 0);
}

// ---------------------------------------------------------------------------
// Workspace layout. Total 109 MB.
// ---------------------------------------------------------------------------
#define MB 1048576u
#define OFF_UQKVT (0*MB)    // bf16 [1536][1024]
#define OFF_VQKVT (3*MB)    // bf16 [3][1024][512]
#define OFF_WOB   (6*MB)    // bf16 [1024][1024]
#define OFF_U1T   (8*MB)    // bf16 [1024][1024]
#define OFF_V1TP  (10*MB)   // bf16 [4096][1024]  col-interleaved for geglu
#define OFF_U2T   (18*MB)   // bf16 [1024][2048]
#define OFF_V2T   (22*MB)   // bf16 [1024][1024]
#define OFF_BQKV  (24*MB)   // f32 [3][1024]; +16KB: b1p f32 [4096]
#define OFF_B1P   (24*MB + 16384u)
#define OFF_XN    (25*MB)   // bf16 [4096][1024]
#define OFF_TBUF  (33*MB)   // bf16 [4096][1536]
#define OFF_QB    (45*MB)   // bf16 [4096][1024] (q) -- dead after attn
#define OFF_KB    (53*MB)   // bf16 [4096][1024] (k) -- dead after attn
#define OFF_HB    (45*MB)   // bf16 [4096][2048] (h; reuses q/k space)
#define OFF_VTB   (61*MB)   // bf16 [32][64][2048] -- dead after attn (scratch)
#define OFF_OB    (69*MB)   // bf16 [4096][1024]   -- dead after Wo   (scratch)
#define OFF_X2    (93*MB)   // f32  [4096][1024]

// ---------------------------------------------------------------------------
// Fused weight prep (single launch, block-range dispatch). Grid = 12304.
// ---------------------------------------------------------------------------
__global__ __launch_bounds__(256) void prep_kernel(
    const float* __restrict__ Uq, const float* __restrict__ Uk,
    const float* __restrict__ Uv, const float* __restrict__ Vq,
    const float* __restrict__ Vk, const float* __restrict__ Vv,
    const float* __restrict__ Wo, const float* __restrict__ U1,
    const float* __restrict__ V1, const float* __restrict__ U2,
    const float* __restrict__ V2,
    const float* __restrict__ bq, const float* __restrict__ bk,
    const float* __restrict__ bv, const float* __restrict__ b1,
    u16* __restrict__ UQKVT, u16* __restrict__ VQKVT, u16* __restrict__ WOB,
    u16* __restrict__ U1T, u16* __restrict__ V1TP, u16* __restrict__ U2T,
    u16* __restrict__ V2T, float* __restrict__ BQKV, float* __restrict__ B1P)
{
    __shared__ float tile[32][33];
    int bid = blockIdx.x;

    if (bid >= 12288) {            // biascat
        int id = (bid - 12288) * 256 + threadIdx.x;   // 0..4095
        if (id < 3072) {
            float v = (id < 1024) ? bq[id] : (id < 2048 ? bk[id - 1024] : bv[id - 2048]);
            BQKV[id] = v;
        }
        int g = id >> 7, q = id & 127;
        B1P[id] = b1[(q < 64) ? (g*64 + q) : (2048 + g*64 + (q - 64))];
        return;
    }
    if (bid >= 11264) {            // Wo convert
        int i4 = ((bid - 11264) * 256 + threadIdx.x) * 4;
        float4 v = *(const float4*)(Wo + i4);
        u16 tmp[4] = {f2bf(v.x), f2bf(v.y), f2bf(v.z), f2bf(v.w)};
        *(uint2*)(WOB + i4) = *(const uint2*)tmp;
        return;
    }

    const float* src; u16* dst; int K, N, src_ld, nx; bool gg = false;
    if (bid < 3072) {
        int t = bid / 512; bid -= t * 512;
        if (t < 3) { src = t==0 ? Uq : (t==1 ? Uk : Uv);
                     dst = UQKVT + t * 512*1024; K = 1024; N = 512; src_ld = 512; nx = 16; }
        else { int z = t - 3; src = z==0 ? Vq : (z==1 ? Vk : Vv);
               dst = VQKVT + z * 524288; K = 512; N = 1024; src_ld = 1024; nx = 32; }
    } else if (bid < 4096)  { src = U1; dst = U1T;  K = 1024; N = 1024; src_ld = 1024; nx = 32;  bid -= 3072; }
    else if (bid < 8192)    { src = V1; dst = V1TP; K = 1024; N = 4096; src_ld = 4096; nx = 128; bid -= 4096; gg = true; }
    else if (bid < 10240)   { src = U2; dst = U2T;  K = 2048; N = 1024; src_ld = 1024; nx = 32;  bid -= 8192; }
    else                    { src = V2; dst = V2T;  K = 1024; N = 1024; src_ld = 1024; nx = 32;  bid -= 10240; }

    int tx = threadIdx.x & 31, ty = threadIdx.x >> 5;
    int n0 = (bid % nx) * 32, k0 = (bid / nx) * 32;
    int srccol;
    if (gg) { int p = n0 + tx; int g = p >> 7, q = p & 127;
              srccol = (q < 64) ? (g*64 + q) : (2048 + g*64 + (q - 64)); }
    else srccol = n0 + tx;
    for (int i = 0; i < 4; i++)
        tile[ty + i*8][tx] = src[(size_t)(k0 + ty + i*8) * src_ld + srccol];
    __syncthreads();
    for (int i = 0; i < 4; i++)
        dst[(size_t)(n0 + ty + i*8) * K + k0 + tx] = f2bf(tile[tx][ty + i*8]);
}

// ---------------------------------------------------------------------------
// LayerNorm
// ---------------------------------------------------------------------------
__global__ __launch_bounds__(256) void ln_kernel(
    const float* __restrict__ x, const float* __restrict__ g,
    const float* __restrict__ bta, u16* __restrict__ out)
{
    int w = threadIdx.x >> 6, lane = threadIdx.x & 63;
    int row = blockIdx.x * 4 + w;
    const float* xr = x + (size_t)row * 1024;
    float vals[16];
    float s = 0.f, s2 = 0.f;
    #pragma unroll
    for (int ii = 0; ii < 16; ii++) {
        float v = xr[lane + ii*64];
        vals[ii] = v; s += v; s2 += v * v;
    }
    #pragma unroll
    for (int off = 1; off < 64; off <<= 1) {
        s  += __shfl_xor(s, off);
        s2 += __shfl_xor(s2, off);
    }
    float mu = s * (1.f/1024.f);
    float var = s2 * (1.f/1024.f) - mu * mu;
    float rs = rsqrtf(var + 1e-5f);
    #pragma unroll
    for (int ii = 0; ii < 16; ii++) {
        int col = lane + ii*64;
        out[(size_t)row * 1024 + col] = f2bf((vals[ii] - mu) * rs * g[col] + bta[col]);
    }
}

// ---------------------------------------------------------------------------
// 256x256 pipelined GEMM + fused GEGLU epilogue, ABLATION TEMPLATE.
//   V=0 full; V=1 no staging; V=2 no epilogue; V=3 no ds_reads; V=4 bare.
// Structure identical to r8 (2 barriers/tile, pipelined fragment reads).
// ---------------------------------------------------------------------------
template<int V>
__global__ __launch_bounds__(512, 2) void gemm256_geglu_kernel(
    const u16* __restrict__ A, const u16* __restrict__ Bt,
    u16* __restrict__ hb, const float* __restrict__ bias, int Kdim)
{
    constexpr bool S = (V==0 || V==2 || V==3);   // in-loop staging + vmcnt
    constexpr bool D = (V==0 || V==1 || V==2);   // in-loop fragment ds_reads
    constexpr bool E = (V==0 || V==1 || V==3);   // full GEGLU epilogue

    __shared__ u16 As[2][16384];   // [256 rows][64 cols]
    __shared__ u16 Bs[2][16384];
    int tid = threadIdx.x;
    int wg = (blockIdx.x & 7) * 32 + (blockIdx.x >> 3);
    int m0 = (wg >> 4) * 256, n0 = (wg & 15) * 256;
    int w = tid >> 6, lane = tid & 63, quad = lane >> 4, l15 = lane & 15;
    int wr = (w >> 2) * 16, wc = (w & 3) * 16;
    int xsw = l15 & 7;
    int s0 = (quad ^ xsw) * 8, s1 = s0 ^ 32;   // swizzled K-slot offsets (elems)

    int srow = tid >> 3;                          // 0..63
    int scol = ((tid & 7) ^ (srow & 7)) * 8;      // inverse swizzle on source
    const u16* Ap = A  + (size_t)(m0 + srow) * Kdim + scol;
    const u16* Bp = Bt + (size_t)(n0 + srow) * Kdim + scol;

    int abase = (wr + l15) * 64;   // elem offset of A row (mi=0)
    int bbase = (wc + l15) * 64;   // elem offset of B row (ni=0)

    f32x4 acc[8][4] = {};

#define STG_A(buf, t, h) do {                                                      \
    gload16(Ap + (size_t)(t)*64 + (size_t)((h)*128     )*Kdim,                     \
            &As[buf][(h)*8192 + tid*8]);                                           \
    gload16(Ap + (size_t)(t)*64 + (size_t)((h)*128 + 64)*Kdim,                     \
            &As[buf][(h)*8192 + 4096 + tid*8]);                                    \
} while (0)
#define STG_B(buf, t, h) do {                                                      \
    gload16(Bp + (size_t)(t)*64 + (size_t)((h)*128     )*Kdim,                     \
            &Bs[buf][(h)*8192 + tid*8]);                                           \
    gload16(Bp + (size_t)(t)*64 + (size_t)((h)*128 + 64)*Kdim,                     \
            &Bs[buf][(h)*8192 + 4096 + tid*8]);                                    \
} while (0)
#define SB()  __builtin_amdgcn_sched_barrier(0)

    int nt = Kdim >> 6;   // K-tiles of 64 (V1: 16)

    // ---- prologue: stage tiles 0,1 fully; confirm t0; preload lo frags ----
    STG_A(0, 0, 0); STG_A(0, 0, 1); STG_B(0, 0, 0); STG_B(0, 0, 1);
    STG_A(1, 1, 0); STG_A(1, 1, 1); STG_B(1, 1, 0); STG_B(1, 1, 1);
    asm volatile("s_waitcnt vmcnt(8)" ::: "memory");
    __builtin_amdgcn_s_barrier();
    SB();

    bf16x8 afl[4][2], afh[4][2], bfl[2][2], bfh[2][2];
    {
        const u16* A0 = As[0];
        const u16* B0 = Bs[0];
        #pragma unroll
        for (int i = 0; i < 4; i++) {
            afl[i][0] = *(const bf16x8*)&A0[abase + i*2048 + s0];
            afl[i][1] = *(const bf16x8*)&A0[abase + i*2048 + s1];
        }
        #pragma unroll
        for (int j = 0; j < 2; j++) {
            bfl[j][0] = *(const bf16x8*)&B0[bbase + j*4096 + s0];
            bfl[j][1] = *(const bf16x8*)&B0[bbase + j*4096 + s1];
        }
    }
    if constexpr (!D) {   // V3/V4: init hi frags once (no in-loop reads)
        #pragma unroll
        for (int i = 0; i < 4; i++) { afh[i][0] = afl[i][0]; afh[i][1] = afl[i][1]; }
        #pragma unroll
        for (int j = 0; j < 2; j++) { bfh[j][0] = bfl[j][0]; bfh[j][1] = bfl[j][1]; }
    }

    for (int t = 0; t < nt; ++t) {
        int buf = t & 1;
        const u16* Asc = As[buf];
        const u16* Bsc = Bs[buf];
        const u16* Asn = As[buf ^ 1];
        const u16* Bsn = Bs[buf ^ 1];
        bool more = (t + 1 < nt);
        bool st   = (t + 2 < nt);

        // ---- q0: issue B-hi(t); MFMA lo x lo ----
        if constexpr (D) {
            #pragma unroll
            for (int j = 0; j < 2; j++) {
                bfh[j][0] = *(const bf16x8*)&Bsc[bbase + 8192 + j*4096 + s0];
                bfh[j][1] = *(const bf16x8*)&Bsc[bbase + 8192 + j*4096 + s1];
            }
            SB();
        }
        __builtin_amdgcn_s_setprio(1);
        #pragma unroll
        for (int i = 0; i < 4; i++)
            #pragma unroll
            for (int j = 0; j < 2; j++) {
                acc[i][j] = __builtin_amdgcn_mfma_f32_16x16x32_bf16(afl[i][0], bfl[j][0], acc[i][j], 0, 0, 0);
                acc[i][j] = __builtin_amdgcn_mfma_f32_16x16x32_bf16(afl[i][1], bfl[j][1], acc[i][j], 0, 0, 0);
            }
        __builtin_amdgcn_s_setprio(0);

        // ---- q1: issue A-hi(t); MFMA lo x hi ----
        if constexpr (D) {
            #pragma unroll
            for (int i = 0; i < 4; i++) {
                afh[i][0] = *(const bf16x8*)&Asc[abase + 8192 + i*2048 + s0];
                afh[i][1] = *(const bf16x8*)&Asc[abase + 8192 + i*2048 + s1];
            }
            SB();
        }
        __builtin_amdgcn_s_setprio(1);
        #pragma unroll
        for (int i = 0; i < 4; i++)
            #pragma unroll
            for (int j = 0; j < 2; j++) {
                acc[i][2+j] = __builtin_amdgcn_mfma_f32_16x16x32_bf16(afl[i][0], bfh[j][0], acc[i][2+j], 0, 0, 0);
                acc[i][2+j] = __builtin_amdgcn_mfma_f32_16x16x32_bf16(afl[i][1], bfh[j][1], acc[i][2+j], 0, 0, 0);
            }
        __builtin_amdgcn_s_setprio(0);

        // ---- sync block (once per tile) ----
        if (more) {
            SB();
            asm volatile("s_waitcnt lgkmcnt(0)" ::: "memory");
            __builtin_amdgcn_s_barrier();                        // B1: buf reusable
            SB();
            if constexpr (S) {
                if (st) { STG_A(buf, t+2, 0); STG_A(buf, t+2, 1);
                          STG_B(buf, t+2, 0); STG_B(buf, t+2, 1); }
                SB();
                if (st) asm volatile("s_waitcnt vmcnt(8)" ::: "memory");
                else    asm volatile("s_waitcnt vmcnt(0)" ::: "memory");
            }
            __builtin_amdgcn_s_barrier();                        // B2: buf^1 valid
            SB();
            if constexpr (D) {
                #pragma unroll
                for (int i = 0; i < 4; i++) {
                    afl[i][0] = *(const bf16x8*)&Asn[abase + i*2048 + s0];
                    afl[i][1] = *(const bf16x8*)&Asn[abase + i*2048 + s1];
                }
                SB();
            }
        }

        // ---- q2: MFMA hi x lo ----
        __builtin_amdgcn_s_setprio(1);
        #pragma unroll
        for (int i = 0; i < 4; i++)
            #pragma unroll
            for (int j = 0; j < 2; j++) {
                acc[4+i][j] = __builtin_amdgcn_mfma_f32_16x16x32_bf16(afh[i][0], bfl[j][0], acc[4+i][j], 0, 0, 0);
                acc[4+i][j] = __builtin_amdgcn_mfma_f32_16x16x32_bf16(afh[i][1], bfl[j][1], acc[4+i][j], 0, 0, 0);
            }
        __builtin_amdgcn_s_setprio(0);

        // ---- q3: issue B-lo(t+1); MFMA hi x hi ----
        if constexpr (D) {
            if (more) {
                #pragma unroll
                for (int j = 0; j < 2; j++) {
                    bfl[j][0] = *(const bf16x8*)&Bsn[bbase + j*4096 + s0];
                    bfl[j][1] = *(const bf16x8*)&Bsn[bbase + j*4096 + s1];
                }
                SB();
            }
        }
        __builtin_amdgcn_s_setprio(1);
        #pragma unroll
        for (int i = 0; i < 4; i++)
            #pragma unroll
            for (int j = 0; j < 2; j++) {
                acc[4+i][2+j] = __builtin_amdgcn_mfma_f32_16x16x32_bf16(afh[i][0], bfh[j][0], acc[4+i][2+j], 0, 0, 0);
                acc[4+i][2+j] = __builtin_amdgcn_mfma_f32_16x16x32_bf16(afh[i][1], bfh[j][1], acc[4+i][2+j], 0, 0, 0);
            }
        __builtin_amdgcn_s_setprio(0);
    }
#undef STG_A
#undef STG_B
#undef SB

    if constexpr (E) {
        // ---- GEGLU epilogue: pairs (ni=2p, ni=2p+1) = packed cols c, c+64 ----
        #pragma unroll
        for (int mi = 0; mi < 8; mi++) {
            int row = m0 + wr + mi*32 + quad*4;
            #pragma unroll
            for (int p = 0; p < 2; p++) {
                int c1 = n0 + p*128 + wc + l15;
                float bz1 = bias[c1], bz2 = bias[c1 + 64];
                int hcol = (n0 >> 1) + p*64 + wc + l15;
                #pragma unroll
                for (int r = 0; r < 4; r++) {
                    float z1 = acc[mi][2*p][r] + bz1;
                    float z2 = acc[mi][2*p+1][r] + bz2;
                    float uu = 0.7978845608028654f * (z1 + 0.044715f * z1 * z1 * z1);
                    float e = __expf(2.f * uu);
                    float th = (e - 1.f) / (e + 1.f);
                    float hv = 0.5f * z1 * (1.f + th) * z2;
                    hb[(size_t)(row + r) * 2048 + hcol] = f2bf(hv);
                }
            }
        }
    } else {
        // cheap keep-alive store: sum all acc (keeps every MFMA live, rule #17)
        f32x4 ssum = {};
        #pragma unroll
        for (int mi = 0; mi < 8; mi++)
            #pragma unroll
            for (int j = 0; j < 4; j++)
                ssum += acc[mi][j];
        ((f32x4*)hb)[(size_t)blockIdx.x * 512 + tid] = ssum;
    }
}

// ---------------------------------------------------------------------------
// Pipelined GEMM, 128x64 tile (qkv1, Wo, U1, U2, V2).
// ---------------------------------------------------------------------------
__global__ __launch_bounds__(256) void gemm_bt64_kernel(
    const u16* __restrict__ A, int lda, const u16* __restrict__ Bt,
    void* __restrict__ Cout, int ldc, const float* __restrict__ bias,
    const float* __restrict__ resid, int Kdim, int mode)
{
    __shared__ u16 As[2][4096];
    __shared__ u16 Bs[2][2048];
    int tid = threadIdx.x;
    int m0 = blockIdx.y * 128, n0 = blockIdx.x * 64;
    int w = tid >> 6, lane = tid & 63, quad = lane >> 4, l15 = lane & 15;
    int wm = (w >> 1) * 64, wn = (w & 1) * 32;
    int sr = tid >> 2, sc8 = (tid & 3) * 8;

    f32x4 acc[4][2] = {};

    const u16* Ap = A  + (size_t)(m0 + sr) * lda  + sc8;
    const u16* Bp = Bt + (size_t)(n0 + sr) * Kdim + sc8;   // sr<64 rows of B

    #define GSTAGE64(buf, koff) do {                                       \
        gload16(Ap + (koff),                     &As[buf][tid * 8]);       \
        gload16(Ap + (koff) + (size_t)64 * lda,  &As[buf][2048 + tid*8]);  \
        gload16(Bp + (koff),                     &Bs[buf][tid * 8]);       \
    } while (0)

    GSTAGE64(0, 0);
    __syncthreads();

    for (int k0 = 0; k0 < Kdim; k0 += 32) {
        int cur = (k0 >> 5) & 1;
        if (k0 + 32 < Kdim) GSTAGE64(cur ^ 1, k0 + 32);
        const u16* Asc = As[cur];
        const u16* Bsc = Bs[cur];
        bf16x8 af[4], bfr[2];
        #pragma unroll
        for (int i = 0; i < 4; i++)
            af[i] = *(const bf16x8*)&Asc[(wm + i*16 + l15) * 32 + quad * 8];
        #pragma unroll
        for (int j = 0; j < 2; j++)
            bfr[j] = *(const bf16x8*)&Bsc[(wn + j*16 + l15) * 32 + quad * 8];
        #pragma unroll
        for (int i = 0; i < 4; i++)
            #pragma unroll
            for (int j = 0; j < 2; j++)
                acc[i][j] = __builtin_amdgcn_mfma_f32_16x16x32_bf16(af[i], bfr[j], acc[i][j], 0, 0, 0);
        __syncthreads();
    }
    #undef GSTAGE64

    #pragma unroll
    for (int i = 0; i < 4; i++) {
        int row = m0 + wm + i*16 + quad*4;
        #pragma unroll
        for (int j = 0; j < 2; j++) {
            int col = n0 + wn + j*16 + l15;
            float bv = bias ? bias[col] : 0.f;
            #pragma unroll
            for (int r = 0; r < 4; r++) {
                float v = acc[i][j][r] + bv;
                size_t idx = (size_t)(row + r) * ldc + col;
                if (mode == 0) ((float*)Cout)[idx] = v + resid[idx];
                else           ((u16*)Cout)[idx] = f2bf(v);
            }
        }
    }
}

// ---------------------------------------------------------------------------
// QKV stage-2 batched pipelined GEMM (z: 0=q(+rope,pre-scale) 1=k(+rope) 2=v^T)
// ---------------------------------------------------------------------------
__global__ __launch_bounds__(256) void qkv2_kernel(
    const u16* __restrict__ T, const u16* __restrict__ Vw,
    const float* __restrict__ bqkv, u16* __restrict__ qout,
    u16* __restrict__ kout, u16* __restrict__ vtout)
{
    __shared__ u16 As[2][4096];
    __shared__ u16 Bs[2][4096];
    int tid = threadIdx.x;
    int z = blockIdx.z;
    int m0 = blockIdx.y * 128, n0 = blockIdx.x * 128;
    int w = tid >> 6, lane = tid & 63, quad = lane >> 4, l15 = lane & 15;
    int wm = (w >> 1) * 64, wn = (w & 1) * 64;
    int sr = tid >> 2, sc8 = (tid & 3) * 8;

    f32x4 acc[4][4] = {};

    const u16* Ap = T  + (size_t)z * 512 + (size_t)(m0 + sr) * 1536 + sc8;
    const u16* Bp = Vw + (size_t)z * 512 * 1024 + (size_t)(n0 + sr) * 512 + sc8;

    #define QSTAGE(buf, koff) do {                                        \
        gload16(Ap + (koff),                     &As[buf][tid * 8]);      \
        gload16(Ap + (koff) + (size_t)64 * 1536, &As[buf][2048 + tid*8]); \
        gload16(Bp + (koff),                     &Bs[buf][tid * 8]);      \
        gload16(Bp + (koff) + (size_t)64 * 512,  &Bs[buf][2048 + tid*8]); \
    } while (0)

    QSTAGE(0, 0);
    __syncthreads();

    for (int k0 = 0; k0 < 512; k0 += 32) {
        int cur = (k0 >> 5) & 1;
        if (k0 + 32 < 512) QSTAGE(cur ^ 1, k0 + 32);
        const u16* Asc = As[cur];
        const u16* Bsc = Bs[cur];
        bf16x8 af[4], bfr[4];
        #pragma unroll
        for (int i = 0; i < 4; i++)
            af[i] = *(const bf16x8*)&Asc[(wm + i*16 + l15) * 32 + quad * 8];
        #pragma unroll
        for (int j = 0; j < 4; j++)
            bfr[j] = *(const bf16x8*)&Bsc[(wn + j*16 + l15) * 32 + quad * 8];
        #pragma unroll
        for (int i = 0; i < 4; i++)
            #pragma unroll
            for (int j = 0; j < 4; j++)
                acc[i][j] = __builtin_amdgcn_mfma_f32_16x16x32_bf16(af[i], bfr[j], acc[i][j], 0, 0, 0);
        __syncthreads();
    }
    #undef QSTAGE

    const float* bias = bqkv + z * 1024;
    if (z < 2) {
        u16* Ob = z ? kout : qout;
        float qscale = z ? 1.f : 0.18033688011112042f;   // 0.125*log2(e) folded into q
        #pragma unroll
        for (int i = 0; i < 4; i++) {
            int row0 = m0 + wm + i*16 + quad*4;
            #pragma unroll
            for (int j = 0; j < 2; j++) {
                int col = n0 + wn + j*16 + l15;       // (col&63) < 32
                float bj = bias[col], bj2 = bias[col + 32];
                float invf = exp2f((float)(col & 31) * -0.4152410118609203f);
                #pragma unroll
                for (int r = 0; r < 4; r++) {
                    int t = row0 + r;
                    float fr = (float)(t & 2047) * invf;
                    float sn, cs;
                    __sincosf(fr, &sn, &cs);
                    sn *= qscale; cs *= qscale;
                    float v1 = acc[i][j][r] + bj;
                    float v2 = acc[i][j+2][r] + bj2;
                    Ob[(size_t)t * 1024 + col]      = f2bf(v1 * cs - v2 * sn);
                    Ob[(size_t)t * 1024 + col + 32] = f2bf(v2 * cs + v1 * sn);
                }
            }
        }
    } else {
        int bb = m0 >> 11;
        #pragma unroll
        for (int i = 0; i < 4; i++) {
            int row0 = m0 + wm + i*16 + quad*4;
            #pragma unroll
            for (int j = 0; j < 4; j++) {
                int col = n0 + wn + j*16 + l15;
                float bj = bias[col];
                u16 pack[4];
                #pragma unroll
                for (int r = 0; r < 4; r++) pack[r] = f2bf(acc[i][j][r] + bj);
                size_t dst = ((size_t)(bb * 16 + (col >> 6)) * 64 + (col & 63)) * 2048 + (row0 & 2047);
                *(uint2*)&vtout[dst] = *(const uint2*)pack;
            }
        }
    }
}

// ---------------------------------------------------------------------------
// Flash attention v4: S^T form (mfma(K,Q)) -> packed b64 P-writes.
// ---------------------------------------------------------------------------
__global__ __launch_bounds__(256) void attn_kernel(
    const u16* __restrict__ Q, const u16* __restrict__ K,
    const u16* __restrict__ Vt, u16* __restrict__ O)
{
    __shared__ u16 Ks[2][64 * 64];
    __shared__ u16 Vs[2][64 * 64];
    __shared__ u16 Ps[128 * 72];
    int tid = threadIdx.x;
    int bh = blockIdx.x;
    int b = bh >> 4, h = bh & 15;
    int m0 = blockIdx.y * 128;
    int w = tid >> 6, lane = tid & 63, quad = lane >> 4, l15 = lane & 15;
    int wm = w * 32;
    size_t qkbase = (size_t)b * 2048 * 1024 + h * 64;
    const u16* Vg = Vt + (size_t)bh * 64 * 2048;

    bf16x8 qf[2][2];
    #pragma unroll
    for (int i = 0; i < 2; i++)
        #pragma unroll
        for (int ks = 0; ks < 2; ks++)
            qf[i][ks] = *(const bf16x8*)(Q + qkbase +
                (size_t)(m0 + wm + i*16 + l15) * 1024 + ks*32 + quad*8);

    f32x4 oacc[2][4] = {};
    float lsum[2] = {};

    int r0 = tid >> 3, p = tid & 7;
    int c0 = (p ^ (r0 & 7)) * 8;
    int xsw = l15 & 7;

    #define STAGE(buf, key0) do {                                               \
        gload16(K + qkbase + (size_t)((key0) + r0) * 1024 + c0,                 \
                &Ks[buf][r0 * 64 + p * 8]);                                     \
        gload16(K + qkbase + (size_t)((key0) + r0 + 32) * 1024 + c0,            \
                &Ks[buf][(r0 + 32) * 64 + p * 8]);                              \
        gload16(Vg + (size_t)r0 * 2048 + (key0) + c0,                           \
                &Vs[buf][r0 * 64 + p * 8]);                                     \
        gload16(Vg + (size_t)(r0 + 32) * 2048 + (key0) + c0,                    \
                &Vs[buf][(r0 + 32) * 64 + p * 8]);                              \
    } while (0)

    STAGE(0, 0);
    __syncthreads();

    for (int kt = 0; kt < 32; kt++) {
        int cur = kt & 1;
        if (kt < 31) STAGE(cur ^ 1, (kt + 1) * 64);
        const u16* Ksc = Ks[cur];
        const u16* Vsc = Vs[cur];

        f32x4 sacc[4][2] = {};
        #pragma unroll
        for (int ks = 0; ks < 2; ks++) {
            bf16x8 kf[4];
            #pragma unroll
            for (int jj = 0; jj < 4; jj++)
                kf[jj] = *(const bf16x8*)&Ksc[(jj*16 + l15) * 64 + (((ks*4 + quad) ^ xsw) * 8)];
            #pragma unroll
            for (int jj = 0; jj < 4; jj++)
                #pragma unroll
                for (int i = 0; i < 2; i++)
                    sacc[jj][i] = __builtin_amdgcn_mfma_f32_16x16x32_bf16(kf[jj], qf[i][ks], sacc[jj][i], 0, 0, 0);
        }

        #pragma unroll
        for (int i = 0; i < 2; i++) {
            int prow = (wm + i*16 + l15) * 72 + quad*4;
            #pragma unroll
            for (int jj = 0; jj < 4; jj++) {
                float p0 = __builtin_amdgcn_exp2f(sacc[jj][i][0]);
                float p1 = __builtin_amdgcn_exp2f(sacc[jj][i][1]);
                float p2 = __builtin_amdgcn_exp2f(sacc[jj][i][2]);
                float p3 = __builtin_amdgcn_exp2f(sacc[jj][i][3]);
                lsum[i] += (p0 + p1) + (p2 + p3);
                uint2 pk; pk.x = packbf(p0, p1); pk.y = packbf(p2, p3);
                *(uint2*)&Ps[prow + jj*16] = pk;
            }
        }

        #pragma unroll
        for (int ks = 0; ks < 2; ks++) {
            bf16x8 pf[2], vf[4];
            #pragma unroll
            for (int i = 0; i < 2; i++)
                pf[i] = *(const bf16x8*)&Ps[(wm + i*16 + l15) * 72 + ks*32 + quad*8];
            #pragma unroll
            for (int j = 0; j < 4; j++)
                vf[j] = *(const bf16x8*)&Vsc[(j*16 + l15) * 64 + (((ks*4 + quad) ^ xsw) * 8)];
            #pragma unroll
            for (int i = 0; i < 2; i++)
                #pragma unroll
                for (int j = 0; j < 4; j++)
                    oacc[i][j] = __builtin_amdgcn_mfma_f32_16x16x32_bf16(pf[i], vf[j], oacc[i][j], 0, 0, 0);
        }
        __syncthreads();
    }
    #undef STAGE

    float inv[2][4];
    #pragma unroll
    for (int i = 0; i < 2; i++) {
        float s = lsum[i];
        s += __shfl_xor(s, 16);
        s += __shfl_xor(s, 32);
        #pragma unroll
        for (int r = 0; r < 4; r++)
            inv[i][r] = 1.f / __shfl(s, (lane & 48) | (quad*4 + r));
    }
    #pragma unroll
    for (int i = 0; i < 2; i++)
        #pragma unroll
        for (int r = 0; r < 4; r++) {
            int row = m0 + wm + i*16 + quad*4 + r;
            #pragma unroll
            for (int j = 0; j < 4; j++)
                O[qkbase + (size_t)row * 1024 + j*16 + l15] = f2bf(oacc[i][j][r] * inv[i][r]);
        }
}

// ---------------------------------------------------------------------------
// Launch
// ---------------------------------------------------------------------------
extern "C" void kernel_launch(void* const* d_in, const int* in_sizes, int n_in,
                              void* d_out, int out_size, void* d_ws, size_t ws_size,
                              hipStream_t stream) {
    (void)in_sizes; (void)n_in; (void)out_size; (void)ws_size;
    const float* x     = (const float*)d_in[0];
    const float* ln1_g = (const float*)d_in[1];
    const float* ln1_b = (const float*)d_in[2];
    const float* Uq    = (const float*)d_in[3];
    const float* Vq    = (const float*)d_in[4];
    const float* bq    = (const float*)d_in[5];
    const float* Uk    = (const float*)d_in[6];
    const float* Vk    = (const float*)d_in[7];
    const float* bk    = (const float*)d_in[8];
    const float* Uv    = (const float*)d_in[9];
    const float* Vv    = (const float*)d_in[10];
    const float* bv    = (const float*)d_in[11];
    const float* Wo    = (const float*)d_in[12];
    const float* bo    = (const float*)d_in[13];
    const float* ln2_g = (const float*)d_in[14];
    const float* ln2_b = (const float*)d_in[15];
    const float* U1    = (const float*)d_in[16];
    const float* V1    = (const float*)d_in[17];
    const float* b1    = (const float*)d_in[18];
    const float* U2    = (const float*)d_in[19];
    const float* V2    = (const float*)d_in[20];
    const float* b2    = (const float*)d_in[21];
    float* out = (float*)d_out;
    char* ws = (char*)d_ws;

    u16* UQKVT = (u16*)(ws + OFF_UQKVT);
    u16* VQKVT = (u16*)(ws + OFF_VQKVT);
    u16* WOB   = (u16*)(ws + OFF_WOB);
    u16* U1T   = (u16*)(ws + OFF_U1T);
    u16* V1TP  = (u16*)(ws + OFF_V1TP);
    u16* U2T   = (u16*)(ws + OFF_U2T);
    u16* V2T   = (u16*)(ws + OFF_V2T);
    float* BQKV = (float*)(ws + OFF_BQKV);
    float* B1P  = (float*)(ws + OFF_B1P);
    u16* xn  = (u16*)(ws + OFF_XN);
    u16* tbuf= (u16*)(ws + OFF_TBUF);
    u16* qb  = (u16*)(ws + OFF_QB);
    u16* kb  = (u16*)(ws + OFF_KB);
    u16* vtb = (u16*)(ws + OFF_VTB);
    u16* ob  = (u16*)(ws + OFF_OB);
    u16* hb  = (u16*)(ws + OFF_HB);
    u16* scr = (u16*)(ws + OFF_VTB);   // 16MB dead scratch (VTB+OB) during FFN
    float* x2 = (float*)(ws + OFF_X2);

    // ---- all weight prep: single launch ----
    prep_kernel<<<12304, 256, 0, stream>>>(
        Uq, Uk, Uv, Vq, Vk, Vv, Wo, U1, V1, U2, V2, bq, bk, bv, b1,
        UQKVT, VQKVT, WOB, U1T, V1TP, U2T, V2T, BQKV, B1P);

    // ---- LN1 ----
    ln_kernel<<<1024, 256, 0, stream>>>(x, ln1_g, ln1_b, xn);

    // ---- QKV ----
    gemm_bt64_kernel<<<dim3(24, 32), 256, 0, stream>>>(xn, 1024, UQKVT, tbuf, 1536,
                                                       nullptr, nullptr, 1024, 1);
    qkv2_kernel<<<dim3(8, 32, 3), 256, 0, stream>>>(tbuf, VQKVT, BQKV, qb, kb, vtb);

    // ---- attention ----
    attn_kernel<<<dim3(32, 16), 256, 0, stream>>>(qb, kb, vtb, ob);

    // ---- out proj + residual ----
    gemm_bt64_kernel<<<dim3(16, 32), 256, 0, stream>>>(ob, 1024, WOB, x2, 1024,
                                                       bo, x, 1024, 0);
    // ---- LN2 ----
    ln_kernel<<<1024, 256, 0, stream>>>(x2, ln2_g, ln2_b, xn);

    // ---- FFN ----
    gemm_bt64_kernel<<<dim3(16, 32), 256, 0, stream>>>(xn, 1024, U1T, tbuf, 1024,
                                                       nullptr, nullptr, 1024, 1);
    // V0 real + V1..V4 diagnostics (within-probe ablation; scratch outputs)
    gemm256_geglu_kernel<0><<<dim3(256), 512, 0, stream>>>(tbuf, V1TP, hb,  B1P, 1024);
    gemm256_geglu_kernel<1><<<dim3(256), 512, 0, stream>>>(tbuf, V1TP, scr, B1P, 1024);
    gemm256_geglu_kernel<2><<<dim3(256), 512, 0, stream>>>(tbuf, V1TP, scr, B1P, 1024);
    gemm256_geglu_kernel<3><<<dim3(256), 512, 0, stream>>>(tbuf, V1TP, scr, B1P, 1024);
    gemm256_geglu_kernel<4><<<dim3(256), 512, 0, stream>>>(tbuf, V1TP, scr, B1P, 1024);
    gemm_bt64_kernel<<<dim3(16, 32), 256, 0, stream>>>(hb, 2048, U2T, tbuf, 1024,
                                                       nullptr, nullptr, 2048, 1);
    gemm_bt64_kernel<<<dim3(16, 32), 256, 0, stream>>>(tbuf, 1024, V2T, out, 1024,
                                                       b2, x2, 1024, 0);
}

// Round 5
// 476.232 us; speedup vs baseline: 1.1130x; 1.1130x over previous
//
#include <hip/hip_runtime.h>

// ============================================================================
// ExplicitSVDBlock round 10:
//  - attn_kernel v5: NO K/V LDS staging (K/V panels are 256KB/head, L2-fits;
//    Common-mistake #7 / m169). MFMA fragments read directly from global
//    (16B/lane L2 hits). Ps stays in LDS but is wave-local -> ZERO barriers
//    and zero vmcnt drains in the kt loop.
//  - gemm256: launch only V0. V1..V4 instantiations KEPT (never-true runtime
//    branch) -- r9 showed the 5-instantiation module compiles V0 to <58.6us
//    vs 69.5us standalone (rule #19 codegen context).
// ============================================================================

typedef unsigned short u16;
typedef unsigned int u32;
typedef u16 u16x8 __attribute__((ext_vector_type(8)));
typedef __bf16 bf16x8 __attribute__((ext_vector_type(8)));
typedef float f32x4 __attribute__((ext_vector_type(4)));

__device__ __forceinline__ u16 f2bf(float f) {
    u32 u = __builtin_bit_cast(u32, f);
    u += 0x7fff + ((u >> 16) & 1);          // RNE
    return (u16)(u >> 16);
}
__device__ __forceinline__ float bf2f(u16 h) {
    u32 u = ((u32)h) << 16;
    return __builtin_bit_cast(float, u);
}
__device__ __forceinline__ u32 packbf(float a, float b) {
    return __builtin_amdgcn_perm(__builtin_bit_cast(u32, b),
                                 __builtin_bit_cast(u32, a), 0x07060302u);
}

__device__ __forceinline__ void gload16(const void* g, void* l) {
    __builtin_amdgcn_global_load_lds(
        (const __attribute__((address_space(1))) void*)g,
        (__attribute__((address_space(3))) void*)l, 16, 0, 0);
}

// ---------------------------------------------------------------------------
// Workspace layout. Total 109 MB.
// ---------------------------------------------------------------------------
#define MB 1048576u
#define OFF_UQKVT (0*MB)    // bf16 [1536][1024]
#define OFF_VQKVT (3*MB)    // bf16 [3][1024][512]
#define OFF_WOB   (6*MB)    // bf16 [1024][1024]
#define OFF_U1T   (8*MB)    // bf16 [1024][1024]
#define OFF_V1TP  (10*MB)   // bf16 [4096][1024]  col-interleaved for geglu
#define OFF_U2T   (18*MB)   // bf16 [1024][2048]
#define OFF_V2T   (22*MB)   // bf16 [1024][1024]
#define OFF_BQKV  (24*MB)   // f32 [3][1024]; +16KB: b1p f32 [4096]
#define OFF_B1P   (24*MB + 16384u)
#define OFF_XN    (25*MB)   // bf16 [4096][1024]
#define OFF_TBUF  (33*MB)   // bf16 [4096][1536]
#define OFF_QB    (45*MB)   // bf16 [4096][1024] (q) -- dead after attn
#define OFF_KB    (53*MB)   // bf16 [4096][1024] (k) -- dead after attn
#define OFF_HB    (45*MB)   // bf16 [4096][2048] (h; reuses q/k space)
#define OFF_VTB   (61*MB)   // bf16 [32][64][2048] -- dead after attn (scratch)
#define OFF_OB    (69*MB)   // bf16 [4096][1024]
#define OFF_X2    (93*MB)   // f32  [4096][1024]

// ---------------------------------------------------------------------------
// Fused weight prep (single launch, block-range dispatch). Grid = 12304.
// ---------------------------------------------------------------------------
__global__ __launch_bounds__(256) void prep_kernel(
    const float* __restrict__ Uq, const float* __restrict__ Uk,
    const float* __restrict__ Uv, const float* __restrict__ Vq,
    const float* __restrict__ Vk, const float* __restrict__ Vv,
    const float* __restrict__ Wo, const float* __restrict__ U1,
    const float* __restrict__ V1, const float* __restrict__ U2,
    const float* __restrict__ V2,
    const float* __restrict__ bq, const float* __restrict__ bk,
    const float* __restrict__ bv, const float* __restrict__ b1,
    u16* __restrict__ UQKVT, u16* __restrict__ VQKVT, u16* __restrict__ WOB,
    u16* __restrict__ U1T, u16* __restrict__ V1TP, u16* __restrict__ U2T,
    u16* __restrict__ V2T, float* __restrict__ BQKV, float* __restrict__ B1P)
{
    __shared__ float tile[32][33];
    int bid = blockIdx.x;

    if (bid >= 12288) {            // biascat
        int id = (bid - 12288) * 256 + threadIdx.x;   // 0..4095
        if (id < 3072) {
            float v = (id < 1024) ? bq[id] : (id < 2048 ? bk[id - 1024] : bv[id - 2048]);
            BQKV[id] = v;
        }
        int g = id >> 7, q = id & 127;
        B1P[id] = b1[(q < 64) ? (g*64 + q) : (2048 + g*64 + (q - 64))];
        return;
    }
    if (bid >= 11264) {            // Wo convert
        int i4 = ((bid - 11264) * 256 + threadIdx.x) * 4;
        float4 v = *(const float4*)(Wo + i4);
        u16 tmp[4] = {f2bf(v.x), f2bf(v.y), f2bf(v.z), f2bf(v.w)};
        *(uint2*)(WOB + i4) = *(const uint2*)tmp;
        return;
    }

    const float* src; u16* dst; int K, N, src_ld, nx; bool gg = false;
    if (bid < 3072) {
        int t = bid / 512; bid -= t * 512;
        if (t < 3) { src = t==0 ? Uq : (t==1 ? Uk : Uv);
                     dst = UQKVT + t * 512*1024; K = 1024; N = 512; src_ld = 512; nx = 16; }
        else { int z = t - 3; src = z==0 ? Vq : (z==1 ? Vk : Vv);
               dst = VQKVT + z * 524288; K = 512; N = 1024; src_ld = 1024; nx = 32; }
    } else if (bid < 4096)  { src = U1; dst = U1T;  K = 1024; N = 1024; src_ld = 1024; nx = 32;  bid -= 3072; }
    else if (bid < 8192)    { src = V1; dst = V1TP; K = 1024; N = 4096; src_ld = 4096; nx = 128; bid -= 4096; gg = true; }
    else if (bid < 10240)   { src = U2; dst = U2T;  K = 2048; N = 1024; src_ld = 1024; nx = 32;  bid -= 8192; }
    else                    { src = V2; dst = V2T;  K = 1024; N = 1024; src_ld = 1024; nx = 32;  bid -= 10240; }

    int tx = threadIdx.x & 31, ty = threadIdx.x >> 5;
    int n0 = (bid % nx) * 32, k0 = (bid / nx) * 32;
    int srccol;
    if (gg) { int p = n0 + tx; int g = p >> 7, q = p & 127;
              srccol = (q < 64) ? (g*64 + q) : (2048 + g*64 + (q - 64)); }
    else srccol = n0 + tx;
    for (int i = 0; i < 4; i++)
        tile[ty + i*8][tx] = src[(size_t)(k0 + ty + i*8) * src_ld + srccol];
    __syncthreads();
    for (int i = 0; i < 4; i++)
        dst[(size_t)(n0 + ty + i*8) * K + k0 + tx] = f2bf(tile[tx][ty + i*8]);
}

// ---------------------------------------------------------------------------
// LayerNorm
// ---------------------------------------------------------------------------
__global__ __launch_bounds__(256) void ln_kernel(
    const float* __restrict__ x, const float* __restrict__ g,
    const float* __restrict__ bta, u16* __restrict__ out)
{
    int w = threadIdx.x >> 6, lane = threadIdx.x & 63;
    int row = blockIdx.x * 4 + w;
    const float* xr = x + (size_t)row * 1024;
    float vals[16];
    float s = 0.f, s2 = 0.f;
    #pragma unroll
    for (int ii = 0; ii < 16; ii++) {
        float v = xr[lane + ii*64];
        vals[ii] = v; s += v; s2 += v * v;
    }
    #pragma unroll
    for (int off = 1; off < 64; off <<= 1) {
        s  += __shfl_xor(s, off);
        s2 += __shfl_xor(s2, off);
    }
    float mu = s * (1.f/1024.f);
    float var = s2 * (1.f/1024.f) - mu * mu;
    float rs = rsqrtf(var + 1e-5f);
    #pragma unroll
    for (int ii = 0; ii < 16; ii++) {
        int col = lane + ii*64;
        out[(size_t)row * 1024 + col] = f2bf((vals[ii] - mu) * rs * g[col] + bta[col]);
    }
}

// ---------------------------------------------------------------------------
// 256x256 pipelined GEMM + fused GEGLU epilogue, template (V0 real;
// V1..V4 instantiated-only to preserve r9's codegen context, rule #19).
// ---------------------------------------------------------------------------
template<int V>
__global__ __launch_bounds__(512, 2) void gemm256_geglu_kernel(
    const u16* __restrict__ A, const u16* __restrict__ Bt,
    u16* __restrict__ hb, const float* __restrict__ bias, int Kdim)
{
    constexpr bool S = (V==0 || V==2 || V==3);   // in-loop staging + vmcnt
    constexpr bool D = (V==0 || V==1 || V==2);   // in-loop fragment ds_reads
    constexpr bool E = (V==0 || V==1 || V==3);   // full GEGLU epilogue

    __shared__ u16 As[2][16384];   // [256 rows][64 cols]
    __shared__ u16 Bs[2][16384];
    int tid = threadIdx.x;
    int wg = (blockIdx.x & 7) * 32 + (blockIdx.x >> 3);
    int m0 = (wg >> 4) * 256, n0 = (wg & 15) * 256;
    int w = tid >> 6, lane = tid & 63, quad = lane >> 4, l15 = lane & 15;
    int wr = (w >> 2) * 16, wc = (w & 3) * 16;
    int xsw = l15 & 7;
    int s0 = (quad ^ xsw) * 8, s1 = s0 ^ 32;   // swizzled K-slot offsets (elems)

    int srow = tid >> 3;                          // 0..63
    int scol = ((tid & 7) ^ (srow & 7)) * 8;      // inverse swizzle on source
    const u16* Ap = A  + (size_t)(m0 + srow) * Kdim + scol;
    const u16* Bp = Bt + (size_t)(n0 + srow) * Kdim + scol;

    int abase = (wr + l15) * 64;   // elem offset of A row (mi=0)
    int bbase = (wc + l15) * 64;   // elem offset of B row (ni=0)

    f32x4 acc[8][4] = {};

#define STG_A(buf, t, h) do {                                                      \
    gload16(Ap + (size_t)(t)*64 + (size_t)((h)*128     )*Kdim,                     \
            &As[buf][(h)*8192 + tid*8]);                                           \
    gload16(Ap + (size_t)(t)*64 + (size_t)((h)*128 + 64)*Kdim,                     \
            &As[buf][(h)*8192 + 4096 + tid*8]);                                    \
} while (0)
#define STG_B(buf, t, h) do {                                                      \
    gload16(Bp + (size_t)(t)*64 + (size_t)((h)*128     )*Kdim,                     \
            &Bs[buf][(h)*8192 + tid*8]);                                           \
    gload16(Bp + (size_t)(t)*64 + (size_t)((h)*128 + 64)*Kdim,                     \
            &Bs[buf][(h)*8192 + 4096 + tid*8]);                                    \
} while (0)
#define SB()  __builtin_amdgcn_sched_barrier(0)

    int nt = Kdim >> 6;   // K-tiles of 64 (V1: 16)

    // ---- prologue: stage tiles 0,1 fully; confirm t0; preload lo frags ----
    STG_A(0, 0, 0); STG_A(0, 0, 1); STG_B(0, 0, 0); STG_B(0, 0, 1);
    STG_A(1, 1, 0); STG_A(1, 1, 1); STG_B(1, 1, 0); STG_B(1, 1, 1);
    asm volatile("s_waitcnt vmcnt(8)" ::: "memory");
    __builtin_amdgcn_s_barrier();
    SB();

    bf16x8 afl[4][2], afh[4][2], bfl[2][2], bfh[2][2];
    {
        const u16* A0 = As[0];
        const u16* B0 = Bs[0];
        #pragma unroll
        for (int i = 0; i < 4; i++) {
            afl[i][0] = *(const bf16x8*)&A0[abase + i*2048 + s0];
            afl[i][1] = *(const bf16x8*)&A0[abase + i*2048 + s1];
        }
        #pragma unroll
        for (int j = 0; j < 2; j++) {
            bfl[j][0] = *(const bf16x8*)&B0[bbase + j*4096 + s0];
            bfl[j][1] = *(const bf16x8*)&B0[bbase + j*4096 + s1];
        }
    }
    if constexpr (!D) {   // V3/V4: init hi frags once (no in-loop reads)
        #pragma unroll
        for (int i = 0; i < 4; i++) { afh[i][0] = afl[i][0]; afh[i][1] = afl[i][1]; }
        #pragma unroll
        for (int j = 0; j < 2; j++) { bfh[j][0] = bfl[j][0]; bfh[j][1] = bfl[j][1]; }
    }

    for (int t = 0; t < nt; ++t) {
        int buf = t & 1;
        const u16* Asc = As[buf];
        const u16* Bsc = Bs[buf];
        const u16* Asn = As[buf ^ 1];
        const u16* Bsn = Bs[buf ^ 1];
        bool more = (t + 1 < nt);
        bool st   = (t + 2 < nt);

        // ---- q0: issue B-hi(t); MFMA lo x lo ----
        if constexpr (D) {
            #pragma unroll
            for (int j = 0; j < 2; j++) {
                bfh[j][0] = *(const bf16x8*)&Bsc[bbase + 8192 + j*4096 + s0];
                bfh[j][1] = *(const bf16x8*)&Bsc[bbase + 8192 + j*4096 + s1];
            }
            SB();
        }
        __builtin_amdgcn_s_setprio(1);
        #pragma unroll
        for (int i = 0; i < 4; i++)
            #pragma unroll
            for (int j = 0; j < 2; j++) {
                acc[i][j] = __builtin_amdgcn_mfma_f32_16x16x32_bf16(afl[i][0], bfl[j][0], acc[i][j], 0, 0, 0);
                acc[i][j] = __builtin_amdgcn_mfma_f32_16x16x32_bf16(afl[i][1], bfl[j][1], acc[i][j], 0, 0, 0);
            }
        __builtin_amdgcn_s_setprio(0);

        // ---- q1: issue A-hi(t); MFMA lo x hi ----
        if constexpr (D) {
            #pragma unroll
            for (int i = 0; i < 4; i++) {
                afh[i][0] = *(const bf16x8*)&Asc[abase + 8192 + i*2048 + s0];
                afh[i][1] = *(const bf16x8*)&Asc[abase + 8192 + i*2048 + s1];
            }
            SB();
        }
        __builtin_amdgcn_s_setprio(1);
        #pragma unroll
        for (int i = 0; i < 4; i++)
            #pragma unroll
            for (int j = 0; j < 2; j++) {
                acc[i][2+j] = __builtin_amdgcn_mfma_f32_16x16x32_bf16(afl[i][0], bfh[j][0], acc[i][2+j], 0, 0, 0);
                acc[i][2+j] = __builtin_amdgcn_mfma_f32_16x16x32_bf16(afl[i][1], bfh[j][1], acc[i][2+j], 0, 0, 0);
            }
        __builtin_amdgcn_s_setprio(0);

        // ---- sync block (once per tile) ----
        if (more) {
            SB();
            asm volatile("s_waitcnt lgkmcnt(0)" ::: "memory");
            __builtin_amdgcn_s_barrier();                        // B1: buf reusable
            SB();
            if constexpr (S) {
                if (st) { STG_A(buf, t+2, 0); STG_A(buf, t+2, 1);
                          STG_B(buf, t+2, 0); STG_B(buf, t+2, 1); }
                SB();
                if (st) asm volatile("s_waitcnt vmcnt(8)" ::: "memory");
                else    asm volatile("s_waitcnt vmcnt(0)" ::: "memory");
            }
            __builtin_amdgcn_s_barrier();                        // B2: buf^1 valid
            SB();
            if constexpr (D) {
                #pragma unroll
                for (int i = 0; i < 4; i++) {
                    afl[i][0] = *(const bf16x8*)&Asn[abase + i*2048 + s0];
                    afl[i][1] = *(const bf16x8*)&Asn[abase + i*2048 + s1];
                }
                SB();
            }
        }

        // ---- q2: MFMA hi x lo ----
        __builtin_amdgcn_s_setprio(1);
        #pragma unroll
        for (int i = 0; i < 4; i++)
            #pragma unroll
            for (int j = 0; j < 2; j++) {
                acc[4+i][j] = __builtin_amdgcn_mfma_f32_16x16x32_bf16(afh[i][0], bfl[j][0], acc[4+i][j], 0, 0, 0);
                acc[4+i][j] = __builtin_amdgcn_mfma_f32_16x16x32_bf16(afh[i][1], bfl[j][1], acc[4+i][j], 0, 0, 0);
            }
        __builtin_amdgcn_s_setprio(0);

        // ---- q3: issue B-lo(t+1); MFMA hi x hi ----
        if constexpr (D) {
            if (more) {
                #pragma unroll
                for (int j = 0; j < 2; j++) {
                    bfl[j][0] = *(const bf16x8*)&Bsn[bbase + j*4096 + s0];
                    bfl[j][1] = *(const bf16x8*)&Bsn[bbase + j*4096 + s1];
                }
                SB();
            }
        }
        __builtin_amdgcn_s_setprio(1);
        #pragma unroll
        for (int i = 0; i < 4; i++)
            #pragma unroll
            for (int j = 0; j < 2; j++) {
                acc[4+i][2+j] = __builtin_amdgcn_mfma_f32_16x16x32_bf16(afh[i][0], bfh[j][0], acc[4+i][2+j], 0, 0, 0);
                acc[4+i][2+j] = __builtin_amdgcn_mfma_f32_16x16x32_bf16(afh[i][1], bfh[j][1], acc[4+i][2+j], 0, 0, 0);
            }
        __builtin_amdgcn_s_setprio(0);
    }
#undef STG_A
#undef STG_B
#undef SB

    if constexpr (E) {
        // ---- GEGLU epilogue: pairs (ni=2p, ni=2p+1) = packed cols c, c+64 ----
        #pragma unroll
        for (int mi = 0; mi < 8; mi++) {
            int row = m0 + wr + mi*32 + quad*4;
            #pragma unroll
            for (int p = 0; p < 2; p++) {
                int c1 = n0 + p*128 + wc + l15;
                float bz1 = bias[c1], bz2 = bias[c1 + 64];
                int hcol = (n0 >> 1) + p*64 + wc + l15;
                #pragma unroll
                for (int r = 0; r < 4; r++) {
                    float z1 = acc[mi][2*p][r] + bz1;
                    float z2 = acc[mi][2*p+1][r] + bz2;
                    float uu = 0.7978845608028654f * (z1 + 0.044715f * z1 * z1 * z1);
                    float e = __expf(2.f * uu);
                    float th = (e - 1.f) / (e + 1.f);
                    float hv = 0.5f * z1 * (1.f + th) * z2;
                    hb[(size_t)(row + r) * 2048 + hcol] = f2bf(hv);
                }
            }
        }
    } else {
        // cheap keep-alive store: sum all acc (keeps every MFMA live, rule #17)
        f32x4 ssum = {};
        #pragma unroll
        for (int mi = 0; mi < 8; mi++)
            #pragma unroll
            for (int j = 0; j < 4; j++)
                ssum += acc[mi][j];
        ((f32x4*)hb)[(size_t)blockIdx.x * 512 + tid] = ssum;
    }
}

// ---------------------------------------------------------------------------
// Pipelined GEMM, 128x64 tile (qkv1, Wo, U1, U2, V2).
// ---------------------------------------------------------------------------
__global__ __launch_bounds__(256) void gemm_bt64_kernel(
    const u16* __restrict__ A, int lda, const u16* __restrict__ Bt,
    void* __restrict__ Cout, int ldc, const float* __restrict__ bias,
    const float* __restrict__ resid, int Kdim, int mode)
{
    __shared__ u16 As[2][4096];
    __shared__ u16 Bs[2][2048];
    int tid = threadIdx.x;
    int m0 = blockIdx.y * 128, n0 = blockIdx.x * 64;
    int w = tid >> 6, lane = tid & 63, quad = lane >> 4, l15 = lane & 15;
    int wm = (w >> 1) * 64, wn = (w & 1) * 32;
    int sr = tid >> 2, sc8 = (tid & 3) * 8;

    f32x4 acc[4][2] = {};

    const u16* Ap = A  + (size_t)(m0 + sr) * lda  + sc8;
    const u16* Bp = Bt + (size_t)(n0 + sr) * Kdim + sc8;   // sr<64 rows of B

    #define GSTAGE64(buf, koff) do {                                       \
        gload16(Ap + (koff),                     &As[buf][tid * 8]);       \
        gload16(Ap + (koff) + (size_t)64 * lda,  &As[buf][2048 + tid*8]);  \
        gload16(Bp + (koff),                     &Bs[buf][tid * 8]);       \
    } while (0)

    GSTAGE64(0, 0);
    __syncthreads();

    for (int k0 = 0; k0 < Kdim; k0 += 32) {
        int cur = (k0 >> 5) & 1;
        if (k0 + 32 < Kdim) GSTAGE64(cur ^ 1, k0 + 32);
        const u16* Asc = As[cur];
        const u16* Bsc = Bs[cur];
        bf16x8 af[4], bfr[2];
        #pragma unroll
        for (int i = 0; i < 4; i++)
            af[i] = *(const bf16x8*)&Asc[(wm + i*16 + l15) * 32 + quad * 8];
        #pragma unroll
        for (int j = 0; j < 2; j++)
            bfr[j] = *(const bf16x8*)&Bsc[(wn + j*16 + l15) * 32 + quad * 8];
        #pragma unroll
        for (int i = 0; i < 4; i++)
            #pragma unroll
            for (int j = 0; j < 2; j++)
                acc[i][j] = __builtin_amdgcn_mfma_f32_16x16x32_bf16(af[i], bfr[j], acc[i][j], 0, 0, 0);
        __syncthreads();
    }
    #undef GSTAGE64

    #pragma unroll
    for (int i = 0; i < 4; i++) {
        int row = m0 + wm + i*16 + quad*4;
        #pragma unroll
        for (int j = 0; j < 2; j++) {
            int col = n0 + wn + j*16 + l15;
            float bv = bias ? bias[col] : 0.f;
            #pragma unroll
            for (int r = 0; r < 4; r++) {
                float v = acc[i][j][r] + bv;
                size_t idx = (size_t)(row + r) * ldc + col;
                if (mode == 0) ((float*)Cout)[idx] = v + resid[idx];
                else           ((u16*)Cout)[idx] = f2bf(v);
            }
        }
    }
}

// ---------------------------------------------------------------------------
// QKV stage-2 batched pipelined GEMM (z: 0=q(+rope,pre-scale) 1=k(+rope) 2=v^T)
// ---------------------------------------------------------------------------
__global__ __launch_bounds__(256) void qkv2_kernel(
    const u16* __restrict__ T, const u16* __restrict__ Vw,
    const float* __restrict__ bqkv, u16* __restrict__ qout,
    u16* __restrict__ kout, u16* __restrict__ vtout)
{
    __shared__ u16 As[2][4096];
    __shared__ u16 Bs[2][4096];
    int tid = threadIdx.x;
    int z = blockIdx.z;
    int m0 = blockIdx.y * 128, n0 = blockIdx.x * 128;
    int w = tid >> 6, lane = tid & 63, quad = lane >> 4, l15 = lane & 15;
    int wm = (w >> 1) * 64, wn = (w & 1) * 64;
    int sr = tid >> 2, sc8 = (tid & 3) * 8;

    f32x4 acc[4][4] = {};

    const u16* Ap = T  + (size_t)z * 512 + (size_t)(m0 + sr) * 1536 + sc8;
    const u16* Bp = Vw + (size_t)z * 512 * 1024 + (size_t)(n0 + sr) * 512 + sc8;

    #define QSTAGE(buf, koff) do {                                        \
        gload16(Ap + (koff),                     &As[buf][tid * 8]);      \
        gload16(Ap + (koff) + (size_t)64 * 1536, &As[buf][2048 + tid*8]); \
        gload16(Bp + (koff),                     &Bs[buf][tid * 8]);      \
        gload16(Bp + (koff) + (size_t)64 * 512,  &Bs[buf][2048 + tid*8]); \
    } while (0)

    QSTAGE(0, 0);
    __syncthreads();

    for (int k0 = 0; k0 < 512; k0 += 32) {
        int cur = (k0 >> 5) & 1;
        if (k0 + 32 < 512) QSTAGE(cur ^ 1, k0 + 32);
        const u16* Asc = As[cur];
        const u16* Bsc = Bs[cur];
        bf16x8 af[4], bfr[4];
        #pragma unroll
        for (int i = 0; i < 4; i++)
            af[i] = *(const bf16x8*)&Asc[(wm + i*16 + l15) * 32 + quad * 8];
        #pragma unroll
        for (int j = 0; j < 4; j++)
            bfr[j] = *(const bf16x8*)&Bsc[(wn + j*16 + l15) * 32 + quad * 8];
        #pragma unroll
        for (int i = 0; i < 4; i++)
            #pragma unroll
            for (int j = 0; j < 4; j++)
                acc[i][j] = __builtin_amdgcn_mfma_f32_16x16x32_bf16(af[i], bfr[j], acc[i][j], 0, 0, 0);
        __syncthreads();
    }
    #undef QSTAGE

    const float* bias = bqkv + z * 1024;
    if (z < 2) {
        u16* Ob = z ? kout : qout;
        float qscale = z ? 1.f : 0.18033688011112042f;   // 0.125*log2(e) folded into q
        #pragma unroll
        for (int i = 0; i < 4; i++) {
            int row0 = m0 + wm + i*16 + quad*4;
            #pragma unroll
            for (int j = 0; j < 2; j++) {
                int col = n0 + wn + j*16 + l15;       // (col&63) < 32
                float bj = bias[col], bj2 = bias[col + 32];
                float invf = exp2f((float)(col & 31) * -0.4152410118609203f);
                #pragma unroll
                for (int r = 0; r < 4; r++) {
                    int t = row0 + r;
                    float fr = (float)(t & 2047) * invf;
                    float sn, cs;
                    __sincosf(fr, &sn, &cs);
                    sn *= qscale; cs *= qscale;
                    float v1 = acc[i][j][r] + bj;
                    float v2 = acc[i][j+2][r] + bj2;
                    Ob[(size_t)t * 1024 + col]      = f2bf(v1 * cs - v2 * sn);
                    Ob[(size_t)t * 1024 + col + 32] = f2bf(v2 * cs + v1 * sn);
                }
            }
        }
    } else {
        int bb = m0 >> 11;
        #pragma unroll
        for (int i = 0; i < 4; i++) {
            int row0 = m0 + wm + i*16 + quad*4;
            #pragma unroll
            for (int j = 0; j < 4; j++) {
                int col = n0 + wn + j*16 + l15;
                float bj = bias[col];
                u16 pack[4];
                #pragma unroll
                for (int r = 0; r < 4; r++) pack[r] = f2bf(acc[i][j][r] + bj);
                size_t dst = ((size_t)(bb * 16 + (col >> 6)) * 64 + (col & 63)) * 2048 + (row0 & 2047);
                *(uint2*)&vtout[dst] = *(const uint2*)pack;
            }
        }
    }
}

// ---------------------------------------------------------------------------
// Flash attention v5: S^T form, NO K/V LDS staging (L2-resident panels),
// Ps wave-local in LDS -> zero barriers / zero vmcnt drains in the kt loop.
// ---------------------------------------------------------------------------
__global__ __launch_bounds__(256) void attn_kernel(
    const u16* __restrict__ Q, const u16* __restrict__ K,
    const u16* __restrict__ Vt, u16* __restrict__ O)
{
    __shared__ u16 Ps[128 * 72];
    int tid = threadIdx.x;
    int bh = blockIdx.x;
    int b = bh >> 4, h = bh & 15;
    int m0 = blockIdx.y * 128;
    int w = tid >> 6, lane = tid & 63, quad = lane >> 4, l15 = lane & 15;
    int wm = w * 32;
    size_t qkbase = (size_t)b * 2048 * 1024 + h * 64;
    const u16* Kg = K + qkbase;
    const u16* Vg = Vt + (size_t)bh * 64 * 2048;

    bf16x8 qf[2][2];
    #pragma unroll
    for (int i = 0; i < 2; i++)
        #pragma unroll
        for (int ks = 0; ks < 2; ks++)
            qf[i][ks] = *(const bf16x8*)(Q + qkbase +
                (size_t)(m0 + wm + i*16 + l15) * 1024 + ks*32 + quad*8);

    f32x4 oacc[2][4] = {};
    float lsum[2] = {};     // per-lane partial row-sum for qrow = wm + i*16 + l15

    for (int kt = 0; kt < 32; kt++) {
        int key0 = kt * 64;

        // ---- QK^T: K fragments straight from global (L2-hit) ----
        // S^T: sacc[jj][i]; col(l15)=qrow, row(quad*4+r)=key jj*16+quad*4+r
        f32x4 sacc[4][2] = {};
        #pragma unroll
        for (int ks = 0; ks < 2; ks++) {
            bf16x8 kf[4];
            #pragma unroll
            for (int jj = 0; jj < 4; jj++)
                kf[jj] = *(const bf16x8*)(Kg +
                    (size_t)(key0 + jj*16 + l15) * 1024 + ks*32 + quad*8);
            #pragma unroll
            for (int jj = 0; jj < 4; jj++)
                #pragma unroll
                for (int i = 0; i < 2; i++)
                    sacc[jj][i] = __builtin_amdgcn_mfma_f32_16x16x32_bf16(kf[jj], qf[i][ks], sacc[jj][i], 0, 0, 0);
        }

        // ---- p = 2^s; per-lane partials; packed b64 write (wave-local) ----
        #pragma unroll
        for (int i = 0; i < 2; i++) {
            int prow = (wm + i*16 + l15) * 72 + quad*4;
            #pragma unroll
            for (int jj = 0; jj < 4; jj++) {
                float p0 = __builtin_amdgcn_exp2f(sacc[jj][i][0]);
                float p1 = __builtin_amdgcn_exp2f(sacc[jj][i][1]);
                float p2 = __builtin_amdgcn_exp2f(sacc[jj][i][2]);
                float p3 = __builtin_amdgcn_exp2f(sacc[jj][i][3]);
                lsum[i] += (p0 + p1) + (p2 + p3);
                uint2 pk; pk.x = packbf(p0, p1); pk.y = packbf(p2, p3);
                *(uint2*)&Ps[prow + jj*16] = pk;
            }
        }

        // ---- PV: V fragments straight from global; P from wave-local LDS ----
        #pragma unroll
        for (int ks = 0; ks < 2; ks++) {
            bf16x8 pf[2], vf[4];
            #pragma unroll
            for (int i = 0; i < 2; i++)
                pf[i] = *(const bf16x8*)&Ps[(wm + i*16 + l15) * 72 + ks*32 + quad*8];
            #pragma unroll
            for (int j = 0; j < 4; j++)
                vf[j] = *(const bf16x8*)(Vg +
                    (size_t)(j*16 + l15) * 2048 + key0 + ks*32 + quad*8);
            #pragma unroll
            for (int i = 0; i < 2; i++)
                #pragma unroll
                for (int j = 0; j < 4; j++)
                    oacc[i][j] = __builtin_amdgcn_mfma_f32_16x16x32_bf16(pf[i], vf[j], oacc[i][j], 0, 0, 0);
        }
    }

    // finalize row sums: reduce across quads, then redistribute to C-layout rows
    float inv[2][4];
    #pragma unroll
    for (int i = 0; i < 2; i++) {
        float s = lsum[i];
        s += __shfl_xor(s, 16);
        s += __shfl_xor(s, 32);
        #pragma unroll
        for (int r = 0; r < 4; r++)
            inv[i][r] = 1.f / __shfl(s, (lane & 48) | (quad*4 + r));
    }
    #pragma unroll
    for (int i = 0; i < 2; i++)
        #pragma unroll
        for (int r = 0; r < 4; r++) {
            int row = m0 + wm + i*16 + quad*4 + r;
            #pragma unroll
            for (int j = 0; j < 4; j++)
                O[qkbase + (size_t)row * 1024 + j*16 + l15] = f2bf(oacc[i][j][r] * inv[i][r]);
        }
}

// ---------------------------------------------------------------------------
// Launch
// ---------------------------------------------------------------------------
extern "C" void kernel_launch(void* const* d_in, const int* in_sizes, int n_in,
                              void* d_out, int out_size, void* d_ws, size_t ws_size,
                              hipStream_t stream) {
    (void)n_in; (void)out_size; (void)ws_size;
    const float* x     = (const float*)d_in[0];
    const float* ln1_g = (const float*)d_in[1];
    const float* ln1_b = (const float*)d_in[2];
    const float* Uq    = (const float*)d_in[3];
    const float* Vq    = (const float*)d_in[4];
    const float* bq    = (const float*)d_in[5];
    const float* Uk    = (const float*)d_in[6];
    const float* Vk    = (const float*)d_in[7];
    const float* bk    = (const float*)d_in[8];
    const float* Uv    = (const float*)d_in[9];
    const float* Vv    = (const float*)d_in[10];
    const float* bv    = (const float*)d_in[11];
    const float* Wo    = (const float*)d_in[12];
    const float* bo    = (const float*)d_in[13];
    const float* ln2_g = (const float*)d_in[14];
    const float* ln2_b = (const float*)d_in[15];
    const float* U1    = (const float*)d_in[16];
    const float* V1    = (const float*)d_in[17];
    const float* b1    = (const float*)d_in[18];
    const float* U2    = (const float*)d_in[19];
    const float* V2    = (const float*)d_in[20];
    const float* b2    = (const float*)d_in[21];
    float* out = (float*)d_out;
    char* ws = (char*)d_ws;

    u16* UQKVT = (u16*)(ws + OFF_UQKVT);
    u16* VQKVT = (u16*)(ws + OFF_VQKVT);
    u16* WOB   = (u16*)(ws + OFF_WOB);
    u16* U1T   = (u16*)(ws + OFF_U1T);
    u16* V1TP  = (u16*)(ws + OFF_V1TP);
    u16* U2T   = (u16*)(ws + OFF_U2T);
    u16* V2T   = (u16*)(ws + OFF_V2T);
    float* BQKV = (float*)(ws + OFF_BQKV);
    float* B1P  = (float*)(ws + OFF_B1P);
    u16* xn  = (u16*)(ws + OFF_XN);
    u16* tbuf= (u16*)(ws + OFF_TBUF);
    u16* qb  = (u16*)(ws + OFF_QB);
    u16* kb  = (u16*)(ws + OFF_KB);
    u16* vtb = (u16*)(ws + OFF_VTB);
    u16* ob  = (u16*)(ws + OFF_OB);
    u16* hb  = (u16*)(ws + OFF_HB);
    u16* scr = (u16*)(ws + OFF_VTB);   // dead scratch during FFN
    float* x2 = (float*)(ws + OFF_X2);

    // ---- all weight prep: single launch ----
    prep_kernel<<<12304, 256, 0, stream>>>(
        Uq, Uk, Uv, Vq, Vk, Vv, Wo, U1, V1, U2, V2, bq, bk, bv, b1,
        UQKVT, VQKVT, WOB, U1T, V1TP, U2T, V2T, BQKV, B1P);

    // ---- LN1 ----
    ln_kernel<<<1024, 256, 0, stream>>>(x, ln1_g, ln1_b, xn);

    // ---- QKV ----
    gemm_bt64_kernel<<<dim3(24, 32), 256, 0, stream>>>(xn, 1024, UQKVT, tbuf, 1536,
                                                       nullptr, nullptr, 1024, 1);
    qkv2_kernel<<<dim3(8, 32, 3), 256, 0, stream>>>(tbuf, VQKVT, BQKV, qb, kb, vtb);

    // ---- attention ----
    attn_kernel<<<dim3(32, 16), 256, 0, stream>>>(qb, kb, vtb, ob);

    // ---- out proj + residual ----
    gemm_bt64_kernel<<<dim3(16, 32), 256, 0, stream>>>(ob, 1024, WOB, x2, 1024,
                                                       bo, x, 1024, 0);
    // ---- LN2 ----
    ln_kernel<<<1024, 256, 0, stream>>>(x2, ln2_g, ln2_b, xn);

    // ---- FFN ----
    gemm_bt64_kernel<<<dim3(16, 32), 256, 0, stream>>>(xn, 1024, U1T, tbuf, 1024,
                                                       nullptr, nullptr, 1024, 1);
    gemm256_geglu_kernel<0><<<dim3(256), 512, 0, stream>>>(tbuf, V1TP, hb, B1P, 1024);
    // keep V1..V4 instantiated (r9 codegen context, rule #19) without running:
    // in_sizes[0] is a positive byte count at runtime; compiler can't fold this.
    if (in_sizes[0] < 0) {
        gemm256_geglu_kernel<1><<<dim3(256), 512, 0, stream>>>(tbuf, V1TP, scr, B1P, 1024);
        gemm256_geglu_kernel<2><<<dim3(256), 512, 0, stream>>>(tbuf, V1TP, scr, B1P, 1024);
        gemm256_geglu_kernel<3><<<dim3(256), 512, 0, stream>>>(tbuf, V1TP, scr, B1P, 1024);
        gemm256_geglu_kernel<4><<<dim3(256), 512, 0, stream>>>(tbuf, V1TP, scr, B1P, 1024);
    }
    gemm_bt64_kernel<<<dim3(16, 32), 256, 0, stream>>>(hb, 2048, U2T, tbuf, 1024,
                                                       nullptr, nullptr, 2048, 1);
    gemm_bt64_kernel<<<dim3(16, 32), 256, 0, stream>>>(tbuf, 1024, V2T, out, 1024,
                                                       b2, x2, 1024, 0);
}

// Round 6
// 428.487 us; speedup vs baseline: 1.2370x; 1.1114x over previous
//
#include <hip/hip_runtime.h>

// ============================================================================
// ExplicitSVDBlock round 11:
//  - attn_kernel v6: REVERT to staged K/V (r10's direct-global was 2.1x slower
//    -- scattered 16-row segment loads, latency-bound). NEW: QBLK 128->64
//    (grid 512->1024, LDS 51200->41984 -> 3 blocks/CU = 12 waves/CU vs 8).
//    The kernel is dependency-latency-bound at exactly-2-blocks/CU; more TLP
//    is the lever. Same swizzles/algorithm, i-dimension removed.
//  - gemm256: V0 + phantom V1..V4 instantiations kept (r10 total-time math
//    confirmed V0 keeps r9's fast codegen context).
// ============================================================================

typedef unsigned short u16;
typedef unsigned int u32;
typedef u16 u16x8 __attribute__((ext_vector_type(8)));
typedef __bf16 bf16x8 __attribute__((ext_vector_type(8)));
typedef float f32x4 __attribute__((ext_vector_type(4)));

__device__ __forceinline__ u16 f2bf(float f) {
    u32 u = __builtin_bit_cast(u32, f);
    u += 0x7fff + ((u >> 16) & 1);          // RNE
    return (u16)(u >> 16);
}
__device__ __forceinline__ float bf2f(u16 h) {
    u32 u = ((u32)h) << 16;
    return __builtin_bit_cast(float, u);
}
__device__ __forceinline__ u32 packbf(float a, float b) {
    return __builtin_amdgcn_perm(__builtin_bit_cast(u32, b),
                                 __builtin_bit_cast(u32, a), 0x07060302u);
}

__device__ __forceinline__ void gload16(const void* g, void* l) {
    __builtin_amdgcn_global_load_lds(
        (const __attribute__((address_space(1))) void*)g,
        (__attribute__((address_space(3))) void*)l, 16, 0, 0);
}

// ---------------------------------------------------------------------------
// Workspace layout. Total 109 MB.
// ---------------------------------------------------------------------------
#define MB 1048576u
#define OFF_UQKVT (0*MB)    // bf16 [1536][1024]
#define OFF_VQKVT (3*MB)    // bf16 [3][1024][512]
#define OFF_WOB   (6*MB)    // bf16 [1024][1024]
#define OFF_U1T   (8*MB)    // bf16 [1024][1024]
#define OFF_V1TP  (10*MB)   // bf16 [4096][1024]  col-interleaved for geglu
#define OFF_U2T   (18*MB)   // bf16 [1024][2048]
#define OFF_V2T   (22*MB)   // bf16 [1024][1024]
#define OFF_BQKV  (24*MB)   // f32 [3][1024]; +16KB: b1p f32 [4096]
#define OFF_B1P   (24*MB + 16384u)
#define OFF_XN    (25*MB)   // bf16 [4096][1024]
#define OFF_TBUF  (33*MB)   // bf16 [4096][1536]
#define OFF_QB    (45*MB)   // bf16 [4096][1024] (q) -- dead after attn
#define OFF_KB    (53*MB)   // bf16 [4096][1024] (k) -- dead after attn
#define OFF_HB    (45*MB)   // bf16 [4096][2048] (h; reuses q/k space)
#define OFF_VTB   (61*MB)   // bf16 [32][64][2048] -- dead after attn (scratch)
#define OFF_OB    (69*MB)   // bf16 [4096][1024]
#define OFF_X2    (93*MB)   // f32  [4096][1024]

// ---------------------------------------------------------------------------
// Fused weight prep (single launch, block-range dispatch). Grid = 12304.
// ---------------------------------------------------------------------------
__global__ __launch_bounds__(256) void prep_kernel(
    const float* __restrict__ Uq, const float* __restrict__ Uk,
    const float* __restrict__ Uv, const float* __restrict__ Vq,
    const float* __restrict__ Vk, const float* __restrict__ Vv,
    const float* __restrict__ Wo, const float* __restrict__ U1,
    const float* __restrict__ V1, const float* __restrict__ U2,
    const float* __restrict__ V2,
    const float* __restrict__ bq, const float* __restrict__ bk,
    const float* __restrict__ bv, const float* __restrict__ b1,
    u16* __restrict__ UQKVT, u16* __restrict__ VQKVT, u16* __restrict__ WOB,
    u16* __restrict__ U1T, u16* __restrict__ V1TP, u16* __restrict__ U2T,
    u16* __restrict__ V2T, float* __restrict__ BQKV, float* __restrict__ B1P)
{
    __shared__ float tile[32][33];
    int bid = blockIdx.x;

    if (bid >= 12288) {            // biascat
        int id = (bid - 12288) * 256 + threadIdx.x;   // 0..4095
        if (id < 3072) {
            float v = (id < 1024) ? bq[id] : (id < 2048 ? bk[id - 1024] : bv[id - 2048]);
            BQKV[id] = v;
        }
        int g = id >> 7, q = id & 127;
        B1P[id] = b1[(q < 64) ? (g*64 + q) : (2048 + g*64 + (q - 64))];
        return;
    }
    if (bid >= 11264) {            // Wo convert
        int i4 = ((bid - 11264) * 256 + threadIdx.x) * 4;
        float4 v = *(const float4*)(Wo + i4);
        u16 tmp[4] = {f2bf(v.x), f2bf(v.y), f2bf(v.z), f2bf(v.w)};
        *(uint2*)(WOB + i4) = *(const uint2*)tmp;
        return;
    }

    const float* src; u16* dst; int K, N, src_ld, nx; bool gg = false;
    if (bid < 3072) {
        int t = bid / 512; bid -= t * 512;
        if (t < 3) { src = t==0 ? Uq : (t==1 ? Uk : Uv);
                     dst = UQKVT + t * 512*1024; K = 1024; N = 512; src_ld = 512; nx = 16; }
        else { int z = t - 3; src = z==0 ? Vq : (z==1 ? Vk : Vv);
               dst = VQKVT + z * 524288; K = 512; N = 1024; src_ld = 1024; nx = 32; }
    } else if (bid < 4096)  { src = U1; dst = U1T;  K = 1024; N = 1024; src_ld = 1024; nx = 32;  bid -= 3072; }
    else if (bid < 8192)    { src = V1; dst = V1TP; K = 1024; N = 4096; src_ld = 4096; nx = 128; bid -= 4096; gg = true; }
    else if (bid < 10240)   { src = U2; dst = U2T;  K = 2048; N = 1024; src_ld = 1024; nx = 32;  bid -= 8192; }
    else                    { src = V2; dst = V2T;  K = 1024; N = 1024; src_ld = 1024; nx = 32;  bid -= 10240; }

    int tx = threadIdx.x & 31, ty = threadIdx.x >> 5;
    int n0 = (bid % nx) * 32, k0 = (bid / nx) * 32;
    int srccol;
    if (gg) { int p = n0 + tx; int g = p >> 7, q = p & 127;
              srccol = (q < 64) ? (g*64 + q) : (2048 + g*64 + (q - 64)); }
    else srccol = n0 + tx;
    for (int i = 0; i < 4; i++)
        tile[ty + i*8][tx] = src[(size_t)(k0 + ty + i*8) * src_ld + srccol];
    __syncthreads();
    for (int i = 0; i < 4; i++)
        dst[(size_t)(n0 + ty + i*8) * K + k0 + tx] = f2bf(tile[tx][ty + i*8]);
}

// ---------------------------------------------------------------------------
// LayerNorm
// ---------------------------------------------------------------------------
__global__ __launch_bounds__(256) void ln_kernel(
    const float* __restrict__ x, const float* __restrict__ g,
    const float* __restrict__ bta, u16* __restrict__ out)
{
    int w = threadIdx.x >> 6, lane = threadIdx.x & 63;
    int row = blockIdx.x * 4 + w;
    const float* xr = x + (size_t)row * 1024;
    float vals[16];
    float s = 0.f, s2 = 0.f;
    #pragma unroll
    for (int ii = 0; ii < 16; ii++) {
        float v = xr[lane + ii*64];
        vals[ii] = v; s += v; s2 += v * v;
    }
    #pragma unroll
    for (int off = 1; off < 64; off <<= 1) {
        s  += __shfl_xor(s, off);
        s2 += __shfl_xor(s2, off);
    }
    float mu = s * (1.f/1024.f);
    float var = s2 * (1.f/1024.f) - mu * mu;
    float rs = rsqrtf(var + 1e-5f);
    #pragma unroll
    for (int ii = 0; ii < 16; ii++) {
        int col = lane + ii*64;
        out[(size_t)row * 1024 + col] = f2bf((vals[ii] - mu) * rs * g[col] + bta[col]);
    }
}

// ---------------------------------------------------------------------------
// 256x256 pipelined GEMM + fused GEGLU epilogue, template (V0 real;
// V1..V4 instantiated-only to preserve r9's codegen context, rule #19).
// ---------------------------------------------------------------------------
template<int V>
__global__ __launch_bounds__(512, 2) void gemm256_geglu_kernel(
    const u16* __restrict__ A, const u16* __restrict__ Bt,
    u16* __restrict__ hb, const float* __restrict__ bias, int Kdim)
{
    constexpr bool S = (V==0 || V==2 || V==3);   // in-loop staging + vmcnt
    constexpr bool D = (V==0 || V==1 || V==2);   // in-loop fragment ds_reads
    constexpr bool E = (V==0 || V==1 || V==3);   // full GEGLU epilogue

    __shared__ u16 As[2][16384];   // [256 rows][64 cols]
    __shared__ u16 Bs[2][16384];
    int tid = threadIdx.x;
    int wg = (blockIdx.x & 7) * 32 + (blockIdx.x >> 3);
    int m0 = (wg >> 4) * 256, n0 = (wg & 15) * 256;
    int w = tid >> 6, lane = tid & 63, quad = lane >> 4, l15 = lane & 15;
    int wr = (w >> 2) * 16, wc = (w & 3) * 16;
    int xsw = l15 & 7;
    int s0 = (quad ^ xsw) * 8, s1 = s0 ^ 32;   // swizzled K-slot offsets (elems)

    int srow = tid >> 3;                          // 0..63
    int scol = ((tid & 7) ^ (srow & 7)) * 8;      // inverse swizzle on source
    const u16* Ap = A  + (size_t)(m0 + srow) * Kdim + scol;
    const u16* Bp = Bt + (size_t)(n0 + srow) * Kdim + scol;

    int abase = (wr + l15) * 64;   // elem offset of A row (mi=0)
    int bbase = (wc + l15) * 64;   // elem offset of B row (ni=0)

    f32x4 acc[8][4] = {};

#define STG_A(buf, t, h) do {                                                      \
    gload16(Ap + (size_t)(t)*64 + (size_t)((h)*128     )*Kdim,                     \
            &As[buf][(h)*8192 + tid*8]);                                           \
    gload16(Ap + (size_t)(t)*64 + (size_t)((h)*128 + 64)*Kdim,                     \
            &As[buf][(h)*8192 + 4096 + tid*8]);                                    \
} while (0)
#define STG_B(buf, t, h) do {                                                      \
    gload16(Bp + (size_t)(t)*64 + (size_t)((h)*128     )*Kdim,                     \
            &Bs[buf][(h)*8192 + tid*8]);                                           \
    gload16(Bp + (size_t)(t)*64 + (size_t)((h)*128 + 64)*Kdim,                     \
            &Bs[buf][(h)*8192 + 4096 + tid*8]);                                    \
} while (0)
#define SB()  __builtin_amdgcn_sched_barrier(0)

    int nt = Kdim >> 6;   // K-tiles of 64 (V1: 16)

    // ---- prologue: stage tiles 0,1 fully; confirm t0; preload lo frags ----
    STG_A(0, 0, 0); STG_A(0, 0, 1); STG_B(0, 0, 0); STG_B(0, 0, 1);
    STG_A(1, 1, 0); STG_A(1, 1, 1); STG_B(1, 1, 0); STG_B(1, 1, 1);
    asm volatile("s_waitcnt vmcnt(8)" ::: "memory");
    __builtin_amdgcn_s_barrier();
    SB();

    bf16x8 afl[4][2], afh[4][2], bfl[2][2], bfh[2][2];
    {
        const u16* A0 = As[0];
        const u16* B0 = Bs[0];
        #pragma unroll
        for (int i = 0; i < 4; i++) {
            afl[i][0] = *(const bf16x8*)&A0[abase + i*2048 + s0];
            afl[i][1] = *(const bf16x8*)&A0[abase + i*2048 + s1];
        }
        #pragma unroll
        for (int j = 0; j < 2; j++) {
            bfl[j][0] = *(const bf16x8*)&B0[bbase + j*4096 + s0];
            bfl[j][1] = *(const bf16x8*)&B0[bbase + j*4096 + s1];
        }
    }
    if constexpr (!D) {   // V3/V4: init hi frags once (no in-loop reads)
        #pragma unroll
        for (int i = 0; i < 4; i++) { afh[i][0] = afl[i][0]; afh[i][1] = afl[i][1]; }
        #pragma unroll
        for (int j = 0; j < 2; j++) { bfh[j][0] = bfl[j][0]; bfh[j][1] = bfl[j][1]; }
    }

    for (int t = 0; t < nt; ++t) {
        int buf = t & 1;
        const u16* Asc = As[buf];
        const u16* Bsc = Bs[buf];
        const u16* Asn = As[buf ^ 1];
        const u16* Bsn = Bs[buf ^ 1];
        bool more = (t + 1 < nt);
        bool st   = (t + 2 < nt);

        // ---- q0: issue B-hi(t); MFMA lo x lo ----
        if constexpr (D) {
            #pragma unroll
            for (int j = 0; j < 2; j++) {
                bfh[j][0] = *(const bf16x8*)&Bsc[bbase + 8192 + j*4096 + s0];
                bfh[j][1] = *(const bf16x8*)&Bsc[bbase + 8192 + j*4096 + s1];
            }
            SB();
        }
        __builtin_amdgcn_s_setprio(1);
        #pragma unroll
        for (int i = 0; i < 4; i++)
            #pragma unroll
            for (int j = 0; j < 2; j++) {
                acc[i][j] = __builtin_amdgcn_mfma_f32_16x16x32_bf16(afl[i][0], bfl[j][0], acc[i][j], 0, 0, 0);
                acc[i][j] = __builtin_amdgcn_mfma_f32_16x16x32_bf16(afl[i][1], bfl[j][1], acc[i][j], 0, 0, 0);
            }
        __builtin_amdgcn_s_setprio(0);

        // ---- q1: issue A-hi(t); MFMA lo x hi ----
        if constexpr (D) {
            #pragma unroll
            for (int i = 0; i < 4; i++) {
                afh[i][0] = *(const bf16x8*)&Asc[abase + 8192 + i*2048 + s0];
                afh[i][1] = *(const bf16x8*)&Asc[abase + 8192 + i*2048 + s1];
            }
            SB();
        }
        __builtin_amdgcn_s_setprio(1);
        #pragma unroll
        for (int i = 0; i < 4; i++)
            #pragma unroll
            for (int j = 0; j < 2; j++) {
                acc[i][2+j] = __builtin_amdgcn_mfma_f32_16x16x32_bf16(afl[i][0], bfh[j][0], acc[i][2+j], 0, 0, 0);
                acc[i][2+j] = __builtin_amdgcn_mfma_f32_16x16x32_bf16(afl[i][1], bfh[j][1], acc[i][2+j], 0, 0, 0);
            }
        __builtin_amdgcn_s_setprio(0);

        // ---- sync block (once per tile) ----
        if (more) {
            SB();
            asm volatile("s_waitcnt lgkmcnt(0)" ::: "memory");
            __builtin_amdgcn_s_barrier();                        // B1: buf reusable
            SB();
            if constexpr (S) {
                if (st) { STG_A(buf, t+2, 0); STG_A(buf, t+2, 1);
                          STG_B(buf, t+2, 0); STG_B(buf, t+2, 1); }
                SB();
                if (st) asm volatile("s_waitcnt vmcnt(8)" ::: "memory");
                else    asm volatile("s_waitcnt vmcnt(0)" ::: "memory");
            }
            __builtin_amdgcn_s_barrier();                        // B2: buf^1 valid
            SB();
            if constexpr (D) {
                #pragma unroll
                for (int i = 0; i < 4; i++) {
                    afl[i][0] = *(const bf16x8*)&Asn[abase + i*2048 + s0];
                    afl[i][1] = *(const bf16x8*)&Asn[abase + i*2048 + s1];
                }
                SB();
            }
        }

        // ---- q2: MFMA hi x lo ----
        __builtin_amdgcn_s_setprio(1);
        #pragma unroll
        for (int i = 0; i < 4; i++)
            #pragma unroll
            for (int j = 0; j < 2; j++) {
                acc[4+i][j] = __builtin_amdgcn_mfma_f32_16x16x32_bf16(afh[i][0], bfl[j][0], acc[4+i][j], 0, 0, 0);
                acc[4+i][j] = __builtin_amdgcn_mfma_f32_16x16x32_bf16(afh[i][1], bfl[j][1], acc[4+i][j], 0, 0, 0);
            }
        __builtin_amdgcn_s_setprio(0);

        // ---- q3: issue B-lo(t+1); MFMA hi x hi ----
        if constexpr (D) {
            if (more) {
                #pragma unroll
                for (int j = 0; j < 2; j++) {
                    bfl[j][0] = *(const bf16x8*)&Bsn[bbase + j*4096 + s0];
                    bfl[j][1] = *(const bf16x8*)&Bsn[bbase + j*4096 + s1];
                }
                SB();
            }
        }
        __builtin_amdgcn_s_setprio(1);
        #pragma unroll
        for (int i = 0; i < 4; i++)
            #pragma unroll
            for (int j = 0; j < 2; j++) {
                acc[4+i][2+j] = __builtin_amdgcn_mfma_f32_16x16x32_bf16(afh[i][0], bfh[j][0], acc[4+i][2+j], 0, 0, 0);
                acc[4+i][2+j] = __builtin_amdgcn_mfma_f32_16x16x32_bf16(afh[i][1], bfh[j][1], acc[4+i][2+j], 0, 0, 0);
            }
        __builtin_amdgcn_s_setprio(0);
    }
#undef STG_A
#undef STG_B
#undef SB

    if constexpr (E) {
        // ---- GEGLU epilogue: pairs (ni=2p, ni=2p+1) = packed cols c, c+64 ----
        #pragma unroll
        for (int mi = 0; mi < 8; mi++) {
            int row = m0 + wr + mi*32 + quad*4;
            #pragma unroll
            for (int p = 0; p < 2; p++) {
                int c1 = n0 + p*128 + wc + l15;
                float bz1 = bias[c1], bz2 = bias[c1 + 64];
                int hcol = (n0 >> 1) + p*64 + wc + l15;
                #pragma unroll
                for (int r = 0; r < 4; r++) {
                    float z1 = acc[mi][2*p][r] + bz1;
                    float z2 = acc[mi][2*p+1][r] + bz2;
                    float uu = 0.7978845608028654f * (z1 + 0.044715f * z1 * z1 * z1);
                    float e = __expf(2.f * uu);
                    float th = (e - 1.f) / (e + 1.f);
                    float hv = 0.5f * z1 * (1.f + th) * z2;
                    hb[(size_t)(row + r) * 2048 + hcol] = f2bf(hv);
                }
            }
        }
    } else {
        // cheap keep-alive store: sum all acc (keeps every MFMA live, rule #17)
        f32x4 ssum = {};
        #pragma unroll
        for (int mi = 0; mi < 8; mi++)
            #pragma unroll
            for (int j = 0; j < 4; j++)
                ssum += acc[mi][j];
        ((f32x4*)hb)[(size_t)blockIdx.x * 512 + tid] = ssum;
    }
}

// ---------------------------------------------------------------------------
// Pipelined GEMM, 128x64 tile (qkv1, Wo, U1, U2, V2).
// ---------------------------------------------------------------------------
__global__ __launch_bounds__(256) void gemm_bt64_kernel(
    const u16* __restrict__ A, int lda, const u16* __restrict__ Bt,
    void* __restrict__ Cout, int ldc, const float* __restrict__ bias,
    const float* __restrict__ resid, int Kdim, int mode)
{
    __shared__ u16 As[2][4096];
    __shared__ u16 Bs[2][2048];
    int tid = threadIdx.x;
    int m0 = blockIdx.y * 128, n0 = blockIdx.x * 64;
    int w = tid >> 6, lane = tid & 63, quad = lane >> 4, l15 = lane & 15;
    int wm = (w >> 1) * 64, wn = (w & 1) * 32;
    int sr = tid >> 2, sc8 = (tid & 3) * 8;

    f32x4 acc[4][2] = {};

    const u16* Ap = A  + (size_t)(m0 + sr) * lda  + sc8;
    const u16* Bp = Bt + (size_t)(n0 + sr) * Kdim + sc8;   // sr<64 rows of B

    #define GSTAGE64(buf, koff) do {                                       \
        gload16(Ap + (koff),                     &As[buf][tid * 8]);       \
        gload16(Ap + (koff) + (size_t)64 * lda,  &As[buf][2048 + tid*8]);  \
        gload16(Bp + (koff),                     &Bs[buf][tid * 8]);       \
    } while (0)

    GSTAGE64(0, 0);
    __syncthreads();

    for (int k0 = 0; k0 < Kdim; k0 += 32) {
        int cur = (k0 >> 5) & 1;
        if (k0 + 32 < Kdim) GSTAGE64(cur ^ 1, k0 + 32);
        const u16* Asc = As[cur];
        const u16* Bsc = Bs[cur];
        bf16x8 af[4], bfr[2];
        #pragma unroll
        for (int i = 0; i < 4; i++)
            af[i] = *(const bf16x8*)&Asc[(wm + i*16 + l15) * 32 + quad * 8];
        #pragma unroll
        for (int j = 0; j < 2; j++)
            bfr[j] = *(const bf16x8*)&Bsc[(wn + j*16 + l15) * 32 + quad * 8];
        #pragma unroll
        for (int i = 0; i < 4; i++)
            #pragma unroll
            for (int j = 0; j < 2; j++)
                acc[i][j] = __builtin_amdgcn_mfma_f32_16x16x32_bf16(af[i], bfr[j], acc[i][j], 0, 0, 0);
        __syncthreads();
    }
    #undef GSTAGE64

    #pragma unroll
    for (int i = 0; i < 4; i++) {
        int row = m0 + wm + i*16 + quad*4;
        #pragma unroll
        for (int j = 0; j < 2; j++) {
            int col = n0 + wn + j*16 + l15;
            float bv = bias ? bias[col] : 0.f;
            #pragma unroll
            for (int r = 0; r < 4; r++) {
                float v = acc[i][j][r] + bv;
                size_t idx = (size_t)(row + r) * ldc + col;
                if (mode == 0) ((float*)Cout)[idx] = v + resid[idx];
                else           ((u16*)Cout)[idx] = f2bf(v);
            }
        }
    }
}

// ---------------------------------------------------------------------------
// QKV stage-2 batched pipelined GEMM (z: 0=q(+rope,pre-scale) 1=k(+rope) 2=v^T)
// ---------------------------------------------------------------------------
__global__ __launch_bounds__(256) void qkv2_kernel(
    const u16* __restrict__ T, const u16* __restrict__ Vw,
    const float* __restrict__ bqkv, u16* __restrict__ qout,
    u16* __restrict__ kout, u16* __restrict__ vtout)
{
    __shared__ u16 As[2][4096];
    __shared__ u16 Bs[2][4096];
    int tid = threadIdx.x;
    int z = blockIdx.z;
    int m0 = blockIdx.y * 128, n0 = blockIdx.x * 128;
    int w = tid >> 6, lane = tid & 63, quad = lane >> 4, l15 = lane & 15;
    int wm = (w >> 1) * 64, wn = (w & 1) * 64;
    int sr = tid >> 2, sc8 = (tid & 3) * 8;

    f32x4 acc[4][4] = {};

    const u16* Ap = T  + (size_t)z * 512 + (size_t)(m0 + sr) * 1536 + sc8;
    const u16* Bp = Vw + (size_t)z * 512 * 1024 + (size_t)(n0 + sr) * 512 + sc8;

    #define QSTAGE(buf, koff) do {                                        \
        gload16(Ap + (koff),                     &As[buf][tid * 8]);      \
        gload16(Ap + (koff) + (size_t)64 * 1536, &As[buf][2048 + tid*8]); \
        gload16(Bp + (koff),                     &Bs[buf][tid * 8]);      \
        gload16(Bp + (koff) + (size_t)64 * 512,  &Bs[buf][2048 + tid*8]); \
    } while (0)

    QSTAGE(0, 0);
    __syncthreads();

    for (int k0 = 0; k0 < 512; k0 += 32) {
        int cur = (k0 >> 5) & 1;
        if (k0 + 32 < 512) QSTAGE(cur ^ 1, k0 + 32);
        const u16* Asc = As[cur];
        const u16* Bsc = Bs[cur];
        bf16x8 af[4], bfr[4];
        #pragma unroll
        for (int i = 0; i < 4; i++)
            af[i] = *(const bf16x8*)&Asc[(wm + i*16 + l15) * 32 + quad * 8];
        #pragma unroll
        for (int j = 0; j < 4; j++)
            bfr[j] = *(const bf16x8*)&Bsc[(wn + j*16 + l15) * 32 + quad * 8];
        #pragma unroll
        for (int i = 0; i < 4; i++)
            #pragma unroll
            for (int j = 0; j < 4; j++)
                acc[i][j] = __builtin_amdgcn_mfma_f32_16x16x32_bf16(af[i], bfr[j], acc[i][j], 0, 0, 0);
        __syncthreads();
    }
    #undef QSTAGE

    const float* bias = bqkv + z * 1024;
    if (z < 2) {
        u16* Ob = z ? kout : qout;
        float qscale = z ? 1.f : 0.18033688011112042f;   // 0.125*log2(e) folded into q
        #pragma unroll
        for (int i = 0; i < 4; i++) {
            int row0 = m0 + wm + i*16 + quad*4;
            #pragma unroll
            for (int j = 0; j < 2; j++) {
                int col = n0 + wn + j*16 + l15;       // (col&63) < 32
                float bj = bias[col], bj2 = bias[col + 32];
                float invf = exp2f((float)(col & 31) * -0.4152410118609203f);
                #pragma unroll
                for (int r = 0; r < 4; r++) {
                    int t = row0 + r;
                    float fr = (float)(t & 2047) * invf;
                    float sn, cs;
                    __sincosf(fr, &sn, &cs);
                    sn *= qscale; cs *= qscale;
                    float v1 = acc[i][j][r] + bj;
                    float v2 = acc[i][j+2][r] + bj2;
                    Ob[(size_t)t * 1024 + col]      = f2bf(v1 * cs - v2 * sn);
                    Ob[(size_t)t * 1024 + col + 32] = f2bf(v2 * cs + v1 * sn);
                }
            }
        }
    } else {
        int bb = m0 >> 11;
        #pragma unroll
        for (int i = 0; i < 4; i++) {
            int row0 = m0 + wm + i*16 + quad*4;
            #pragma unroll
            for (int j = 0; j < 4; j++) {
                int col = n0 + wn + j*16 + l15;
                float bj = bias[col];
                u16 pack[4];
                #pragma unroll
                for (int r = 0; r < 4; r++) pack[r] = f2bf(acc[i][j][r] + bj);
                size_t dst = ((size_t)(bb * 16 + (col >> 6)) * 64 + (col & 63)) * 2048 + (row0 & 2047);
                *(uint2*)&vtout[dst] = *(const uint2*)pack;
            }
        }
    }
}

// ---------------------------------------------------------------------------
// Flash attention v6: staged K/V (reverted from v5), QBLK=64 for occupancy.
// Grid (32 bh, 32 m-tiles) = 1024 blocks -> 3 blocks/CU (LDS 41984B),
// 12 waves/CU vs v4's 8. Wave w owns qrows [m0+w*16, m0+w*16+16).
// ---------------------------------------------------------------------------
__global__ __launch_bounds__(256) void attn_kernel(
    const u16* __restrict__ Q, const u16* __restrict__ K,
    const u16* __restrict__ Vt, u16* __restrict__ O)
{
    __shared__ u16 Ks[2][64 * 64];
    __shared__ u16 Vs[2][64 * 64];
    __shared__ u16 Ps[64 * 72];
    int tid = threadIdx.x;
    int bh = blockIdx.x;
    int b = bh >> 4, h = bh & 15;
    int m0 = blockIdx.y * 64;
    int w = tid >> 6, lane = tid & 63, quad = lane >> 4, l15 = lane & 15;
    int wm = w * 16;
    size_t qkbase = (size_t)b * 2048 * 1024 + h * 64;
    const u16* Vg = Vt + (size_t)bh * 64 * 2048;

    bf16x8 qf[2];
    #pragma unroll
    for (int ks = 0; ks < 2; ks++)
        qf[ks] = *(const bf16x8*)(Q + qkbase +
            (size_t)(m0 + wm + l15) * 1024 + ks*32 + quad*8);

    f32x4 oacc[4] = {};
    float lsum = 0.f;       // per-lane partial row-sum for qrow = wm + l15

    int r0 = tid >> 3, p = tid & 7;
    int c0 = (p ^ (r0 & 7)) * 8;
    int xsw = l15 & 7;

    #define STAGE(buf, key0) do {                                               \
        gload16(K + qkbase + (size_t)((key0) + r0) * 1024 + c0,                 \
                &Ks[buf][r0 * 64 + p * 8]);                                     \
        gload16(K + qkbase + (size_t)((key0) + r0 + 32) * 1024 + c0,            \
                &Ks[buf][(r0 + 32) * 64 + p * 8]);                              \
        gload16(Vg + (size_t)r0 * 2048 + (key0) + c0,                           \
                &Vs[buf][r0 * 64 + p * 8]);                                     \
        gload16(Vg + (size_t)(r0 + 32) * 2048 + (key0) + c0,                    \
                &Vs[buf][(r0 + 32) * 64 + p * 8]);                              \
    } while (0)

    STAGE(0, 0);
    __syncthreads();

    for (int kt = 0; kt < 32; kt++) {
        int cur = kt & 1;
        if (kt < 31) STAGE(cur ^ 1, (kt + 1) * 64);
        const u16* Ksc = Ks[cur];
        const u16* Vsc = Vs[cur];

        // S^T = K Q^T: col(l15)=qrow, row(quad*4+r)=key jj*16+quad*4+r
        f32x4 sacc[4] = {};
        #pragma unroll
        for (int ks = 0; ks < 2; ks++) {
            bf16x8 kf[4];
            #pragma unroll
            for (int jj = 0; jj < 4; jj++)
                kf[jj] = *(const bf16x8*)&Ksc[(jj*16 + l15) * 64 + (((ks*4 + quad) ^ xsw) * 8)];
            #pragma unroll
            for (int jj = 0; jj < 4; jj++)
                sacc[jj] = __builtin_amdgcn_mfma_f32_16x16x32_bf16(kf[jj], qf[ks], sacc[jj], 0, 0, 0);
        }

        // p = 2^s; per-lane partials; packed b64 write to Ps[qrow][key]
        {
            int prow = (wm + l15) * 72 + quad*4;
            #pragma unroll
            for (int jj = 0; jj < 4; jj++) {
                float p0 = __builtin_amdgcn_exp2f(sacc[jj][0]);
                float p1 = __builtin_amdgcn_exp2f(sacc[jj][1]);
                float p2 = __builtin_amdgcn_exp2f(sacc[jj][2]);
                float p3 = __builtin_amdgcn_exp2f(sacc[jj][3]);
                lsum += (p0 + p1) + (p2 + p3);
                uint2 pk; pk.x = packbf(p0, p1); pk.y = packbf(p2, p3);
                *(uint2*)&Ps[prow + jj*16] = pk;
            }
        }

        // PV: O[qrow][d] += P[qrow][key] * Vt[d][key]^T
        #pragma unroll
        for (int ks = 0; ks < 2; ks++) {
            bf16x8 pf, vf[4];
            pf = *(const bf16x8*)&Ps[(wm + l15) * 72 + ks*32 + quad*8];
            #pragma unroll
            for (int j = 0; j < 4; j++)
                vf[j] = *(const bf16x8*)&Vsc[(j*16 + l15) * 64 + (((ks*4 + quad) ^ xsw) * 8)];
            #pragma unroll
            for (int j = 0; j < 4; j++)
                oacc[j] = __builtin_amdgcn_mfma_f32_16x16x32_bf16(pf, vf[j], oacc[j], 0, 0, 0);
        }
        __syncthreads();
    }
    #undef STAGE

    // finalize row sums: reduce across quads, then redistribute to C-layout rows
    float s = lsum;
    s += __shfl_xor(s, 16);
    s += __shfl_xor(s, 32);
    float inv[4];
    #pragma unroll
    for (int r = 0; r < 4; r++)
        inv[r] = 1.f / __shfl(s, (lane & 48) | (quad*4 + r));
    #pragma unroll
    for (int r = 0; r < 4; r++) {
        int row = m0 + wm + quad*4 + r;
        #pragma unroll
        for (int j = 0; j < 4; j++)
            O[qkbase + (size_t)row * 1024 + j*16 + l15] = f2bf(oacc[j][r] * inv[r]);
    }
}

// ---------------------------------------------------------------------------
// Launch
// ---------------------------------------------------------------------------
extern "C" void kernel_launch(void* const* d_in, const int* in_sizes, int n_in,
                              void* d_out, int out_size, void* d_ws, size_t ws_size,
                              hipStream_t stream) {
    (void)n_in; (void)out_size; (void)ws_size;
    const float* x     = (const float*)d_in[0];
    const float* ln1_g = (const float*)d_in[1];
    const float* ln1_b = (const float*)d_in[2];
    const float* Uq    = (const float*)d_in[3];
    const float* Vq    = (const float*)d_in[4];
    const float* bq    = (const float*)d_in[5];
    const float* Uk    = (const float*)d_in[6];
    const float* Vk    = (const float*)d_in[7];
    const float* bk    = (const float*)d_in[8];
    const float* Uv    = (const float*)d_in[9];
    const float* Vv    = (const float*)d_in[10];
    const float* bv    = (const float*)d_in[11];
    const float* Wo    = (const float*)d_in[12];
    const float* bo    = (const float*)d_in[13];
    const float* ln2_g = (const float*)d_in[14];
    const float* ln2_b = (const float*)d_in[15];
    const float* U1    = (const float*)d_in[16];
    const float* V1    = (const float*)d_in[17];
    const float* b1    = (const float*)d_in[18];
    const float* U2    = (const float*)d_in[19];
    const float* V2    = (const float*)d_in[20];
    const float* b2    = (const float*)d_in[21];
    float* out = (float*)d_out;
    char* ws = (char*)d_ws;

    u16* UQKVT = (u16*)(ws + OFF_UQKVT);
    u16* VQKVT = (u16*)(ws + OFF_VQKVT);
    u16* WOB   = (u16*)(ws + OFF_WOB);
    u16* U1T   = (u16*)(ws + OFF_U1T);
    u16* V1TP  = (u16*)(ws + OFF_V1TP);
    u16* U2T   = (u16*)(ws + OFF_U2T);
    u16* V2T   = (u16*)(ws + OFF_V2T);
    float* BQKV = (float*)(ws + OFF_BQKV);
    float* B1P  = (float*)(ws + OFF_B1P);
    u16* xn  = (u16*)(ws + OFF_XN);
    u16* tbuf= (u16*)(ws + OFF_TBUF);
    u16* qb  = (u16*)(ws + OFF_QB);
    u16* kb  = (u16*)(ws + OFF_KB);
    u16* vtb = (u16*)(ws + OFF_VTB);
    u16* ob  = (u16*)(ws + OFF_OB);
    u16* hb  = (u16*)(ws + OFF_HB);
    u16* scr = (u16*)(ws + OFF_VTB);   // dead scratch during FFN
    float* x2 = (float*)(ws + OFF_X2);

    // ---- all weight prep: single launch ----
    prep_kernel<<<12304, 256, 0, stream>>>(
        Uq, Uk, Uv, Vq, Vk, Vv, Wo, U1, V1, U2, V2, bq, bk, bv, b1,
        UQKVT, VQKVT, WOB, U1T, V1TP, U2T, V2T, BQKV, B1P);

    // ---- LN1 ----
    ln_kernel<<<1024, 256, 0, stream>>>(x, ln1_g, ln1_b, xn);

    // ---- QKV ----
    gemm_bt64_kernel<<<dim3(24, 32), 256, 0, stream>>>(xn, 1024, UQKVT, tbuf, 1536,
                                                       nullptr, nullptr, 1024, 1);
    qkv2_kernel<<<dim3(8, 32, 3), 256, 0, stream>>>(tbuf, VQKVT, BQKV, qb, kb, vtb);

    // ---- attention ----
    attn_kernel<<<dim3(32, 32), 256, 0, stream>>>(qb, kb, vtb, ob);

    // ---- out proj + residual ----
    gemm_bt64_kernel<<<dim3(16, 32), 256, 0, stream>>>(ob, 1024, WOB, x2, 1024,
                                                       bo, x, 1024, 0);
    // ---- LN2 ----
    ln_kernel<<<1024, 256, 0, stream>>>(x2, ln2_g, ln2_b, xn);

    // ---- FFN ----
    gemm_bt64_kernel<<<dim3(16, 32), 256, 0, stream>>>(xn, 1024, U1T, tbuf, 1024,
                                                       nullptr, nullptr, 1024, 1);
    gemm256_geglu_kernel<0><<<dim3(256), 512, 0, stream>>>(tbuf, V1TP, hb, B1P, 1024);
    // keep V1..V4 instantiated (r9 codegen context, rule #19) without running:
    if (in_sizes[0] < 0) {
        gemm256_geglu_kernel<1><<<dim3(256), 512, 0, stream>>>(tbuf, V1TP, scr, B1P, 1024);
        gemm256_geglu_kernel<2><<<dim3(256), 512, 0, stream>>>(tbuf, V1TP, scr, B1P, 1024);
        gemm256_geglu_kernel<3><<<dim3(256), 512, 0, stream>>>(tbuf, V1TP, scr, B1P, 1024);
        gemm256_geglu_kernel<4><<<dim3(256), 512, 0, stream>>>(tbuf, V1TP, scr, B1P, 1024);
    }
    gemm_bt64_kernel<<<dim3(16, 32), 256, 0, stream>>>(hb, 2048, U2T, tbuf, 1024,
                                                       nullptr, nullptr, 2048, 1);
    gemm_bt64_kernel<<<dim3(16, 32), 256, 0, stream>>>(tbuf, 1024, V2T, out, 1024,
                                                       b2, x2, 1024, 0);
}

// Round 7
// 415.328 us; speedup vs baseline: 1.2762x; 1.0317x over previous
//
#include <hip/hip_runtime.h>

// ============================================================================
// ExplicitSVDBlock round 12:
//  - attn_kernel v7 = v4 (QBLK=128, 4 waves, staged K/V) +
//      (a) Ps stride 72->88 u16 (176B): bank-conflict fix for P write/read
//      (b) triple-buffered K/V + counted vmcnt(8): prefetch stays in flight
//          ACROSS the barrier (raw s_barrier + lgkmcnt(0), no vmcnt(0) drain)
//      (c) grid back to (32,16)
//    r11 post-mortem: QBLK=64 doubled staging work per output, occupancy flat
//    -> regression. v4 counters show LDS-pipe-bound (~2400cyc/kt vs 310 MFMA);
//    conflicts 3.14M cyc/dispatch. These two changes attack exactly that.
//  - gemm256: V0 + phantom V1..V4 instantiations kept (rule #19 context).
// ============================================================================

typedef unsigned short u16;
typedef unsigned int u32;
typedef u16 u16x8 __attribute__((ext_vector_type(8)));
typedef __bf16 bf16x8 __attribute__((ext_vector_type(8)));
typedef float f32x4 __attribute__((ext_vector_type(4)));

__device__ __forceinline__ u16 f2bf(float f) {
    u32 u = __builtin_bit_cast(u32, f);
    u += 0x7fff + ((u >> 16) & 1);          // RNE
    return (u16)(u >> 16);
}
__device__ __forceinline__ float bf2f(u16 h) {
    u32 u = ((u32)h) << 16;
    return __builtin_bit_cast(float, u);
}
__device__ __forceinline__ u32 packbf(float a, float b) {
    return __builtin_amdgcn_perm(__builtin_bit_cast(u32, b),
                                 __builtin_bit_cast(u32, a), 0x07060302u);
}

__device__ __forceinline__ void gload16(const void* g, void* l) {
    __builtin_amdgcn_global_load_lds(
        (const __attribute__((address_space(1))) void*)g,
        (__attribute__((address_space(3))) void*)l, 16, 0, 0);
}

// ---------------------------------------------------------------------------
// Workspace layout. Total 109 MB.
// ---------------------------------------------------------------------------
#define MB 1048576u
#define OFF_UQKVT (0*MB)    // bf16 [1536][1024]
#define OFF_VQKVT (3*MB)    // bf16 [3][1024][512]
#define OFF_WOB   (6*MB)    // bf16 [1024][1024]
#define OFF_U1T   (8*MB)    // bf16 [1024][1024]
#define OFF_V1TP  (10*MB)   // bf16 [4096][1024]  col-interleaved for geglu
#define OFF_U2T   (18*MB)   // bf16 [1024][2048]
#define OFF_V2T   (22*MB)   // bf16 [1024][1024]
#define OFF_BQKV  (24*MB)   // f32 [3][1024]; +16KB: b1p f32 [4096]
#define OFF_B1P   (24*MB + 16384u)
#define OFF_XN    (25*MB)   // bf16 [4096][1024]
#define OFF_TBUF  (33*MB)   // bf16 [4096][1536]
#define OFF_QB    (45*MB)   // bf16 [4096][1024] (q) -- dead after attn
#define OFF_KB    (53*MB)   // bf16 [4096][1024] (k) -- dead after attn
#define OFF_HB    (45*MB)   // bf16 [4096][2048] (h; reuses q/k space)
#define OFF_VTB   (61*MB)   // bf16 [32][64][2048] -- dead after attn (scratch)
#define OFF_OB    (69*MB)   // bf16 [4096][1024]
#define OFF_X2    (93*MB)   // f32  [4096][1024]

// ---------------------------------------------------------------------------
// Fused weight prep (single launch, block-range dispatch). Grid = 12304.
// ---------------------------------------------------------------------------
__global__ __launch_bounds__(256) void prep_kernel(
    const float* __restrict__ Uq, const float* __restrict__ Uk,
    const float* __restrict__ Uv, const float* __restrict__ Vq,
    const float* __restrict__ Vk, const float* __restrict__ Vv,
    const float* __restrict__ Wo, const float* __restrict__ U1,
    const float* __restrict__ V1, const float* __restrict__ U2,
    const float* __restrict__ V2,
    const float* __restrict__ bq, const float* __restrict__ bk,
    const float* __restrict__ bv, const float* __restrict__ b1,
    u16* __restrict__ UQKVT, u16* __restrict__ VQKVT, u16* __restrict__ WOB,
    u16* __restrict__ U1T, u16* __restrict__ V1TP, u16* __restrict__ U2T,
    u16* __restrict__ V2T, float* __restrict__ BQKV, float* __restrict__ B1P)
{
    __shared__ float tile[32][33];
    int bid = blockIdx.x;

    if (bid >= 12288) {            // biascat
        int id = (bid - 12288) * 256 + threadIdx.x;   // 0..4095
        if (id < 3072) {
            float v = (id < 1024) ? bq[id] : (id < 2048 ? bk[id - 1024] : bv[id - 2048]);
            BQKV[id] = v;
        }
        int g = id >> 7, q = id & 127;
        B1P[id] = b1[(q < 64) ? (g*64 + q) : (2048 + g*64 + (q - 64))];
        return;
    }
    if (bid >= 11264) {            // Wo convert
        int i4 = ((bid - 11264) * 256 + threadIdx.x) * 4;
        float4 v = *(const float4*)(Wo + i4);
        u16 tmp[4] = {f2bf(v.x), f2bf(v.y), f2bf(v.z), f2bf(v.w)};
        *(uint2*)(WOB + i4) = *(const uint2*)tmp;
        return;
    }

    const float* src; u16* dst; int K, N, src_ld, nx; bool gg = false;
    if (bid < 3072) {
        int t = bid / 512; bid -= t * 512;
        if (t < 3) { src = t==0 ? Uq : (t==1 ? Uk : Uv);
                     dst = UQKVT + t * 512*1024; K = 1024; N = 512; src_ld = 512; nx = 16; }
        else { int z = t - 3; src = z==0 ? Vq : (z==1 ? Vk : Vv);
               dst = VQKVT + z * 524288; K = 512; N = 1024; src_ld = 1024; nx = 32; }
    } else if (bid < 4096)  { src = U1; dst = U1T;  K = 1024; N = 1024; src_ld = 1024; nx = 32;  bid -= 3072; }
    else if (bid < 8192)    { src = V1; dst = V1TP; K = 1024; N = 4096; src_ld = 4096; nx = 128; bid -= 4096; gg = true; }
    else if (bid < 10240)   { src = U2; dst = U2T;  K = 2048; N = 1024; src_ld = 1024; nx = 32;  bid -= 8192; }
    else                    { src = V2; dst = V2T;  K = 1024; N = 1024; src_ld = 1024; nx = 32;  bid -= 10240; }

    int tx = threadIdx.x & 31, ty = threadIdx.x >> 5;
    int n0 = (bid % nx) * 32, k0 = (bid / nx) * 32;
    int srccol;
    if (gg) { int p = n0 + tx; int g = p >> 7, q = p & 127;
              srccol = (q < 64) ? (g*64 + q) : (2048 + g*64 + (q - 64)); }
    else srccol = n0 + tx;
    for (int i = 0; i < 4; i++)
        tile[ty + i*8][tx] = src[(size_t)(k0 + ty + i*8) * src_ld + srccol];
    __syncthreads();
    for (int i = 0; i < 4; i++)
        dst[(size_t)(n0 + ty + i*8) * K + k0 + tx] = f2bf(tile[tx][ty + i*8]);
}

// ---------------------------------------------------------------------------
// LayerNorm
// ---------------------------------------------------------------------------
__global__ __launch_bounds__(256) void ln_kernel(
    const float* __restrict__ x, const float* __restrict__ g,
    const float* __restrict__ bta, u16* __restrict__ out)
{
    int w = threadIdx.x >> 6, lane = threadIdx.x & 63;
    int row = blockIdx.x * 4 + w;
    const float* xr = x + (size_t)row * 1024;
    float vals[16];
    float s = 0.f, s2 = 0.f;
    #pragma unroll
    for (int ii = 0; ii < 16; ii++) {
        float v = xr[lane + ii*64];
        vals[ii] = v; s += v; s2 += v * v;
    }
    #pragma unroll
    for (int off = 1; off < 64; off <<= 1) {
        s  += __shfl_xor(s, off);
        s2 += __shfl_xor(s2, off);
    }
    float mu = s * (1.f/1024.f);
    float var = s2 * (1.f/1024.f) - mu * mu;
    float rs = rsqrtf(var + 1e-5f);
    #pragma unroll
    for (int ii = 0; ii < 16; ii++) {
        int col = lane + ii*64;
        out[(size_t)row * 1024 + col] = f2bf((vals[ii] - mu) * rs * g[col] + bta[col]);
    }
}

// ---------------------------------------------------------------------------
// 256x256 pipelined GEMM + fused GEGLU epilogue, template (V0 real;
// V1..V4 instantiated-only to preserve r9's codegen context, rule #19).
// ---------------------------------------------------------------------------
template<int V>
__global__ __launch_bounds__(512, 2) void gemm256_geglu_kernel(
    const u16* __restrict__ A, const u16* __restrict__ Bt,
    u16* __restrict__ hb, const float* __restrict__ bias, int Kdim)
{
    constexpr bool S = (V==0 || V==2 || V==3);   // in-loop staging + vmcnt
    constexpr bool D = (V==0 || V==1 || V==2);   // in-loop fragment ds_reads
    constexpr bool E = (V==0 || V==1 || V==3);   // full GEGLU epilogue

    __shared__ u16 As[2][16384];   // [256 rows][64 cols]
    __shared__ u16 Bs[2][16384];
    int tid = threadIdx.x;
    int wg = (blockIdx.x & 7) * 32 + (blockIdx.x >> 3);
    int m0 = (wg >> 4) * 256, n0 = (wg & 15) * 256;
    int w = tid >> 6, lane = tid & 63, quad = lane >> 4, l15 = lane & 15;
    int wr = (w >> 2) * 16, wc = (w & 3) * 16;
    int xsw = l15 & 7;
    int s0 = (quad ^ xsw) * 8, s1 = s0 ^ 32;   // swizzled K-slot offsets (elems)

    int srow = tid >> 3;                          // 0..63
    int scol = ((tid & 7) ^ (srow & 7)) * 8;      // inverse swizzle on source
    const u16* Ap = A  + (size_t)(m0 + srow) * Kdim + scol;
    const u16* Bp = Bt + (size_t)(n0 + srow) * Kdim + scol;

    int abase = (wr + l15) * 64;   // elem offset of A row (mi=0)
    int bbase = (wc + l15) * 64;   // elem offset of B row (ni=0)

    f32x4 acc[8][4] = {};

#define STG_A(buf, t, h) do {                                                      \
    gload16(Ap + (size_t)(t)*64 + (size_t)((h)*128     )*Kdim,                     \
            &As[buf][(h)*8192 + tid*8]);                                           \
    gload16(Ap + (size_t)(t)*64 + (size_t)((h)*128 + 64)*Kdim,                     \
            &As[buf][(h)*8192 + 4096 + tid*8]);                                    \
} while (0)
#define STG_B(buf, t, h) do {                                                      \
    gload16(Bp + (size_t)(t)*64 + (size_t)((h)*128     )*Kdim,                     \
            &Bs[buf][(h)*8192 + tid*8]);                                           \
    gload16(Bp + (size_t)(t)*64 + (size_t)((h)*128 + 64)*Kdim,                     \
            &Bs[buf][(h)*8192 + 4096 + tid*8]);                                    \
} while (0)
#define SB()  __builtin_amdgcn_sched_barrier(0)

    int nt = Kdim >> 6;   // K-tiles of 64 (V1: 16)

    // ---- prologue: stage tiles 0,1 fully; confirm t0; preload lo frags ----
    STG_A(0, 0, 0); STG_A(0, 0, 1); STG_B(0, 0, 0); STG_B(0, 0, 1);
    STG_A(1, 1, 0); STG_A(1, 1, 1); STG_B(1, 1, 0); STG_B(1, 1, 1);
    asm volatile("s_waitcnt vmcnt(8)" ::: "memory");
    __builtin_amdgcn_s_barrier();
    SB();

    bf16x8 afl[4][2], afh[4][2], bfl[2][2], bfh[2][2];
    {
        const u16* A0 = As[0];
        const u16* B0 = Bs[0];
        #pragma unroll
        for (int i = 0; i < 4; i++) {
            afl[i][0] = *(const bf16x8*)&A0[abase + i*2048 + s0];
            afl[i][1] = *(const bf16x8*)&A0[abase + i*2048 + s1];
        }
        #pragma unroll
        for (int j = 0; j < 2; j++) {
            bfl[j][0] = *(const bf16x8*)&B0[bbase + j*4096 + s0];
            bfl[j][1] = *(const bf16x8*)&B0[bbase + j*4096 + s1];
        }
    }
    if constexpr (!D) {   // V3/V4: init hi frags once (no in-loop reads)
        #pragma unroll
        for (int i = 0; i < 4; i++) { afh[i][0] = afl[i][0]; afh[i][1] = afl[i][1]; }
        #pragma unroll
        for (int j = 0; j < 2; j++) { bfh[j][0] = bfl[j][0]; bfh[j][1] = bfl[j][1]; }
    }

    for (int t = 0; t < nt; ++t) {
        int buf = t & 1;
        const u16* Asc = As[buf];
        const u16* Bsc = Bs[buf];
        const u16* Asn = As[buf ^ 1];
        const u16* Bsn = Bs[buf ^ 1];
        bool more = (t + 1 < nt);
        bool st   = (t + 2 < nt);

        // ---- q0: issue B-hi(t); MFMA lo x lo ----
        if constexpr (D) {
            #pragma unroll
            for (int j = 0; j < 2; j++) {
                bfh[j][0] = *(const bf16x8*)&Bsc[bbase + 8192 + j*4096 + s0];
                bfh[j][1] = *(const bf16x8*)&Bsc[bbase + 8192 + j*4096 + s1];
            }
            SB();
        }
        __builtin_amdgcn_s_setprio(1);
        #pragma unroll
        for (int i = 0; i < 4; i++)
            #pragma unroll
            for (int j = 0; j < 2; j++) {
                acc[i][j] = __builtin_amdgcn_mfma_f32_16x16x32_bf16(afl[i][0], bfl[j][0], acc[i][j], 0, 0, 0);
                acc[i][j] = __builtin_amdgcn_mfma_f32_16x16x32_bf16(afl[i][1], bfl[j][1], acc[i][j], 0, 0, 0);
            }
        __builtin_amdgcn_s_setprio(0);

        // ---- q1: issue A-hi(t); MFMA lo x hi ----
        if constexpr (D) {
            #pragma unroll
            for (int i = 0; i < 4; i++) {
                afh[i][0] = *(const bf16x8*)&Asc[abase + 8192 + i*2048 + s0];
                afh[i][1] = *(const bf16x8*)&Asc[abase + 8192 + i*2048 + s1];
            }
            SB();
        }
        __builtin_amdgcn_s_setprio(1);
        #pragma unroll
        for (int i = 0; i < 4; i++)
            #pragma unroll
            for (int j = 0; j < 2; j++) {
                acc[i][2+j] = __builtin_amdgcn_mfma_f32_16x16x32_bf16(afl[i][0], bfh[j][0], acc[i][2+j], 0, 0, 0);
                acc[i][2+j] = __builtin_amdgcn_mfma_f32_16x16x32_bf16(afl[i][1], bfh[j][1], acc[i][2+j], 0, 0, 0);
            }
        __builtin_amdgcn_s_setprio(0);

        // ---- sync block (once per tile) ----
        if (more) {
            SB();
            asm volatile("s_waitcnt lgkmcnt(0)" ::: "memory");
            __builtin_amdgcn_s_barrier();                        // B1: buf reusable
            SB();
            if constexpr (S) {
                if (st) { STG_A(buf, t+2, 0); STG_A(buf, t+2, 1);
                          STG_B(buf, t+2, 0); STG_B(buf, t+2, 1); }
                SB();
                if (st) asm volatile("s_waitcnt vmcnt(8)" ::: "memory");
                else    asm volatile("s_waitcnt vmcnt(0)" ::: "memory");
            }
            __builtin_amdgcn_s_barrier();                        // B2: buf^1 valid
            SB();
            if constexpr (D) {
                #pragma unroll
                for (int i = 0; i < 4; i++) {
                    afl[i][0] = *(const bf16x8*)&Asn[abase + i*2048 + s0];
                    afl[i][1] = *(const bf16x8*)&Asn[abase + i*2048 + s1];
                }
                SB();
            }
        }

        // ---- q2: MFMA hi x lo ----
        __builtin_amdgcn_s_setprio(1);
        #pragma unroll
        for (int i = 0; i < 4; i++)
            #pragma unroll
            for (int j = 0; j < 2; j++) {
                acc[4+i][j] = __builtin_amdgcn_mfma_f32_16x16x32_bf16(afh[i][0], bfl[j][0], acc[4+i][j], 0, 0, 0);
                acc[4+i][j] = __builtin_amdgcn_mfma_f32_16x16x32_bf16(afh[i][1], bfl[j][1], acc[4+i][j], 0, 0, 0);
            }
        __builtin_amdgcn_s_setprio(0);

        // ---- q3: issue B-lo(t+1); MFMA hi x hi ----
        if constexpr (D) {
            if (more) {
                #pragma unroll
                for (int j = 0; j < 2; j++) {
                    bfl[j][0] = *(const bf16x8*)&Bsn[bbase + j*4096 + s0];
                    bfl[j][1] = *(const bf16x8*)&Bsn[bbase + j*4096 + s1];
                }
                SB();
            }
        }
        __builtin_amdgcn_s_setprio(1);
        #pragma unroll
        for (int i = 0; i < 4; i++)
            #pragma unroll
            for (int j = 0; j < 2; j++) {
                acc[4+i][2+j] = __builtin_amdgcn_mfma_f32_16x16x32_bf16(afh[i][0], bfh[j][0], acc[4+i][2+j], 0, 0, 0);
                acc[4+i][2+j] = __builtin_amdgcn_mfma_f32_16x16x32_bf16(afh[i][1], bfh[j][1], acc[4+i][2+j], 0, 0, 0);
            }
        __builtin_amdgcn_s_setprio(0);
    }
#undef STG_A
#undef STG_B
#undef SB

    if constexpr (E) {
        // ---- GEGLU epilogue: pairs (ni=2p, ni=2p+1) = packed cols c, c+64 ----
        #pragma unroll
        for (int mi = 0; mi < 8; mi++) {
            int row = m0 + wr + mi*32 + quad*4;
            #pragma unroll
            for (int p = 0; p < 2; p++) {
                int c1 = n0 + p*128 + wc + l15;
                float bz1 = bias[c1], bz2 = bias[c1 + 64];
                int hcol = (n0 >> 1) + p*64 + wc + l15;
                #pragma unroll
                for (int r = 0; r < 4; r++) {
                    float z1 = acc[mi][2*p][r] + bz1;
                    float z2 = acc[mi][2*p+1][r] + bz2;
                    float uu = 0.7978845608028654f * (z1 + 0.044715f * z1 * z1 * z1);
                    float e = __expf(2.f * uu);
                    float th = (e - 1.f) / (e + 1.f);
                    float hv = 0.5f * z1 * (1.f + th) * z2;
                    hb[(size_t)(row + r) * 2048 + hcol] = f2bf(hv);
                }
            }
        }
    } else {
        // cheap keep-alive store: sum all acc (keeps every MFMA live, rule #17)
        f32x4 ssum = {};
        #pragma unroll
        for (int mi = 0; mi < 8; mi++)
            #pragma unroll
            for (int j = 0; j < 4; j++)
                ssum += acc[mi][j];
        ((f32x4*)hb)[(size_t)blockIdx.x * 512 + tid] = ssum;
    }
}

// ---------------------------------------------------------------------------
// Pipelined GEMM, 128x64 tile (qkv1, Wo, U1, U2, V2).
// ---------------------------------------------------------------------------
__global__ __launch_bounds__(256) void gemm_bt64_kernel(
    const u16* __restrict__ A, int lda, const u16* __restrict__ Bt,
    void* __restrict__ Cout, int ldc, const float* __restrict__ bias,
    const float* __restrict__ resid, int Kdim, int mode)
{
    __shared__ u16 As[2][4096];
    __shared__ u16 Bs[2][2048];
    int tid = threadIdx.x;
    int m0 = blockIdx.y * 128, n0 = blockIdx.x * 64;
    int w = tid >> 6, lane = tid & 63, quad = lane >> 4, l15 = lane & 15;
    int wm = (w >> 1) * 64, wn = (w & 1) * 32;
    int sr = tid >> 2, sc8 = (tid & 3) * 8;

    f32x4 acc[4][2] = {};

    const u16* Ap = A  + (size_t)(m0 + sr) * lda  + sc8;
    const u16* Bp = Bt + (size_t)(n0 + sr) * Kdim + sc8;   // sr<64 rows of B

    #define GSTAGE64(buf, koff) do {                                       \
        gload16(Ap + (koff),                     &As[buf][tid * 8]);       \
        gload16(Ap + (koff) + (size_t)64 * lda,  &As[buf][2048 + tid*8]);  \
        gload16(Bp + (koff),                     &Bs[buf][tid * 8]);       \
    } while (0)

    GSTAGE64(0, 0);
    __syncthreads();

    for (int k0 = 0; k0 < Kdim; k0 += 32) {
        int cur = (k0 >> 5) & 1;
        if (k0 + 32 < Kdim) GSTAGE64(cur ^ 1, k0 + 32);
        const u16* Asc = As[cur];
        const u16* Bsc = Bs[cur];
        bf16x8 af[4], bfr[2];
        #pragma unroll
        for (int i = 0; i < 4; i++)
            af[i] = *(const bf16x8*)&Asc[(wm + i*16 + l15) * 32 + quad * 8];
        #pragma unroll
        for (int j = 0; j < 2; j++)
            bfr[j] = *(const bf16x8*)&Bsc[(wn + j*16 + l15) * 32 + quad * 8];
        #pragma unroll
        for (int i = 0; i < 4; i++)
            #pragma unroll
            for (int j = 0; j < 2; j++)
                acc[i][j] = __builtin_amdgcn_mfma_f32_16x16x32_bf16(af[i], bfr[j], acc[i][j], 0, 0, 0);
        __syncthreads();
    }
    #undef GSTAGE64

    #pragma unroll
    for (int i = 0; i < 4; i++) {
        int row = m0 + wm + i*16 + quad*4;
        #pragma unroll
        for (int j = 0; j < 2; j++) {
            int col = n0 + wn + j*16 + l15;
            float bv = bias ? bias[col] : 0.f;
            #pragma unroll
            for (int r = 0; r < 4; r++) {
                float v = acc[i][j][r] + bv;
                size_t idx = (size_t)(row + r) * ldc + col;
                if (mode == 0) ((float*)Cout)[idx] = v + resid[idx];
                else           ((u16*)Cout)[idx] = f2bf(v);
            }
        }
    }
}

// ---------------------------------------------------------------------------
// QKV stage-2 batched pipelined GEMM (z: 0=q(+rope,pre-scale) 1=k(+rope) 2=v^T)
// ---------------------------------------------------------------------------
__global__ __launch_bounds__(256) void qkv2_kernel(
    const u16* __restrict__ T, const u16* __restrict__ Vw,
    const float* __restrict__ bqkv, u16* __restrict__ qout,
    u16* __restrict__ kout, u16* __restrict__ vtout)
{
    __shared__ u16 As[2][4096];
    __shared__ u16 Bs[2][4096];
    int tid = threadIdx.x;
    int z = blockIdx.z;
    int m0 = blockIdx.y * 128, n0 = blockIdx.x * 128;
    int w = tid >> 6, lane = tid & 63, quad = lane >> 4, l15 = lane & 15;
    int wm = (w >> 1) * 64, wn = (w & 1) * 64;
    int sr = tid >> 2, sc8 = (tid & 3) * 8;

    f32x4 acc[4][4] = {};

    const u16* Ap = T  + (size_t)z * 512 + (size_t)(m0 + sr) * 1536 + sc8;
    const u16* Bp = Vw + (size_t)z * 512 * 1024 + (size_t)(n0 + sr) * 512 + sc8;

    #define QSTAGE(buf, koff) do {                                        \
        gload16(Ap + (koff),                     &As[buf][tid * 8]);      \
        gload16(Ap + (koff) + (size_t)64 * 1536, &As[buf][2048 + tid*8]); \
        gload16(Bp + (koff),                     &Bs[buf][tid * 8]);      \
        gload16(Bp + (koff) + (size_t)64 * 512,  &Bs[buf][2048 + tid*8]); \
    } while (0)

    QSTAGE(0, 0);
    __syncthreads();

    for (int k0 = 0; k0 < 512; k0 += 32) {
        int cur = (k0 >> 5) & 1;
        if (k0 + 32 < 512) QSTAGE(cur ^ 1, k0 + 32);
        const u16* Asc = As[cur];
        const u16* Bsc = Bs[cur];
        bf16x8 af[4], bfr[4];
        #pragma unroll
        for (int i = 0; i < 4; i++)
            af[i] = *(const bf16x8*)&Asc[(wm + i*16 + l15) * 32 + quad * 8];
        #pragma unroll
        for (int j = 0; j < 4; j++)
            bfr[j] = *(const bf16x8*)&Bsc[(wn + j*16 + l15) * 32 + quad * 8];
        #pragma unroll
        for (int i = 0; i < 4; i++)
            #pragma unroll
            for (int j = 0; j < 4; j++)
                acc[i][j] = __builtin_amdgcn_mfma_f32_16x16x32_bf16(af[i], bfr[j], acc[i][j], 0, 0, 0);
        __syncthreads();
    }
    #undef QSTAGE

    const float* bias = bqkv + z * 1024;
    if (z < 2) {
        u16* Ob = z ? kout : qout;
        float qscale = z ? 1.f : 0.18033688011112042f;   // 0.125*log2(e) folded into q
        #pragma unroll
        for (int i = 0; i < 4; i++) {
            int row0 = m0 + wm + i*16 + quad*4;
            #pragma unroll
            for (int j = 0; j < 2; j++) {
                int col = n0 + wn + j*16 + l15;       // (col&63) < 32
                float bj = bias[col], bj2 = bias[col + 32];
                float invf = exp2f((float)(col & 31) * -0.4152410118609203f);
                #pragma unroll
                for (int r = 0; r < 4; r++) {
                    int t = row0 + r;
                    float fr = (float)(t & 2047) * invf;
                    float sn, cs;
                    __sincosf(fr, &sn, &cs);
                    sn *= qscale; cs *= qscale;
                    float v1 = acc[i][j][r] + bj;
                    float v2 = acc[i][j+2][r] + bj2;
                    Ob[(size_t)t * 1024 + col]      = f2bf(v1 * cs - v2 * sn);
                    Ob[(size_t)t * 1024 + col + 32] = f2bf(v2 * cs + v1 * sn);
                }
            }
        }
    } else {
        int bb = m0 >> 11;
        #pragma unroll
        for (int i = 0; i < 4; i++) {
            int row0 = m0 + wm + i*16 + quad*4;
            #pragma unroll
            for (int j = 0; j < 4; j++) {
                int col = n0 + wn + j*16 + l15;
                float bj = bias[col];
                u16 pack[4];
                #pragma unroll
                for (int r = 0; r < 4; r++) pack[r] = f2bf(acc[i][j][r] + bj);
                size_t dst = ((size_t)(bb * 16 + (col >> 6)) * 64 + (col & 63)) * 2048 + (row0 & 2047);
                *(uint2*)&vtout[dst] = *(const uint2*)pack;
            }
        }
    }
}

// ---------------------------------------------------------------------------
// Flash attention v7: QBLK=128 (v4 structure) + Ps stride 88 (conflict fix)
// + triple-buffered K/V with counted vmcnt(8) across raw s_barrier.
// LDS = 3*8K(K) + 3*8K(V) + 128*88*2 (Ps) = 70.5KB -> 2 blocks/CU (grid-lim).
// ---------------------------------------------------------------------------
#define PSTR 88
__global__ __launch_bounds__(256) void attn_kernel(
    const u16* __restrict__ Q, const u16* __restrict__ K,
    const u16* __restrict__ Vt, u16* __restrict__ O)
{
    __shared__ u16 Ks[3][64 * 64];
    __shared__ u16 Vs[3][64 * 64];
    __shared__ u16 Ps[128 * PSTR];
    int tid = threadIdx.x;
    int bh = blockIdx.x;
    int b = bh >> 4, h = bh & 15;
    int m0 = blockIdx.y * 128;
    int w = tid >> 6, lane = tid & 63, quad = lane >> 4, l15 = lane & 15;
    int wm = w * 32;
    size_t qkbase = (size_t)b * 2048 * 1024 + h * 64;
    const u16* Vg = Vt + (size_t)bh * 64 * 2048;

    bf16x8 qf[2][2];
    #pragma unroll
    for (int i = 0; i < 2; i++)
        #pragma unroll
        for (int ks = 0; ks < 2; ks++)
            qf[i][ks] = *(const bf16x8*)(Q + qkbase +
                (size_t)(m0 + wm + i*16 + l15) * 1024 + ks*32 + quad*8);

    f32x4 oacc[2][4] = {};
    float lsum[2] = {};     // per-lane partial row-sum for qrow = wm + i*16 + l15

    int r0 = tid >> 3, p = tid & 7;
    int c0 = (p ^ (r0 & 7)) * 8;
    int xsw = l15 & 7;

    #define STAGE(buf, key0) do {                                               \
        gload16(K + qkbase + (size_t)((key0) + r0) * 1024 + c0,                 \
                &Ks[buf][r0 * 64 + p * 8]);                                     \
        gload16(K + qkbase + (size_t)((key0) + r0 + 32) * 1024 + c0,            \
                &Ks[buf][(r0 + 32) * 64 + p * 8]);                              \
        gload16(Vg + (size_t)r0 * 2048 + (key0) + c0,                           \
                &Vs[buf][r0 * 64 + p * 8]);                                     \
        gload16(Vg + (size_t)(r0 + 32) * 2048 + (key0) + c0,                    \
                &Vs[buf][(r0 + 32) * 64 + p * 8]);                              \
    } while (0)

    // prologue: stage kt=0,1; kt0 landed (8 of kt1 in flight)
    STAGE(0, 0);
    STAGE(1, 64);
    asm volatile("s_waitcnt vmcnt(8)" ::: "memory");
    __builtin_amdgcn_s_barrier();

    int cur = 0;
    for (int kt = 0; kt < 32; kt++) {
        // stage kt+2 into the buffer freed at the PREVIOUS barrier
        int nx2 = (cur >= 1) ? cur - 1 : cur + 2;   // (cur+2)%3
        if (kt + 2 < 32) STAGE(nx2, (kt + 2) * 64);
        const u16* Ksc = Ks[cur];
        const u16* Vsc = Vs[cur];

        // S^T = K Q^T: sacc[jj][i]; col(l15)=qrow, row(quad*4+r)=key jj*16+quad*4+r
        f32x4 sacc[4][2] = {};
        #pragma unroll
        for (int ks = 0; ks < 2; ks++) {
            bf16x8 kf[4];
            #pragma unroll
            for (int jj = 0; jj < 4; jj++)
                kf[jj] = *(const bf16x8*)&Ksc[(jj*16 + l15) * 64 + (((ks*4 + quad) ^ xsw) * 8)];
            #pragma unroll
            for (int jj = 0; jj < 4; jj++)
                #pragma unroll
                for (int i = 0; i < 2; i++)
                    sacc[jj][i] = __builtin_amdgcn_mfma_f32_16x16x32_bf16(kf[jj], qf[i][ks], sacc[jj][i], 0, 0, 0);
        }

        // p = 2^s; per-lane partials; packed b64 write to Ps[qrow][key]
        #pragma unroll
        for (int i = 0; i < 2; i++) {
            int prow = (wm + i*16 + l15) * PSTR + quad*4;
            #pragma unroll
            for (int jj = 0; jj < 4; jj++) {
                float p0 = __builtin_amdgcn_exp2f(sacc[jj][i][0]);
                float p1 = __builtin_amdgcn_exp2f(sacc[jj][i][1]);
                float p2 = __builtin_amdgcn_exp2f(sacc[jj][i][2]);
                float p3 = __builtin_amdgcn_exp2f(sacc[jj][i][3]);
                lsum[i] += (p0 + p1) + (p2 + p3);
                uint2 pk; pk.x = packbf(p0, p1); pk.y = packbf(p2, p3);
                *(uint2*)&Ps[prow + jj*16] = pk;
            }
        }

        // PV: O[qrow][d] += P[qrow][key] * Vt[d][key]^T
        #pragma unroll
        for (int ks = 0; ks < 2; ks++) {
            bf16x8 pf[2], vf[4];
            #pragma unroll
            for (int i = 0; i < 2; i++)
                pf[i] = *(const bf16x8*)&Ps[(wm + i*16 + l15) * PSTR + ks*32 + quad*8];
            #pragma unroll
            for (int j = 0; j < 4; j++)
                vf[j] = *(const bf16x8*)&Vsc[(j*16 + l15) * 64 + (((ks*4 + quad) ^ xsw) * 8)];
            #pragma unroll
            for (int i = 0; i < 2; i++)
                #pragma unroll
                for (int j = 0; j < 4; j++)
                    oacc[i][j] = __builtin_amdgcn_mfma_f32_16x16x32_bf16(pf[i], vf[j], oacc[i][j], 0, 0, 0);
        }

        // end-of-iter: my LDS reads of cur retired; kt+1's loads landed
        // (kt+2's 8 loads stay in flight ACROSS the barrier -- counted vmcnt)
        if (kt + 1 < 32) {
            asm volatile("s_waitcnt lgkmcnt(0)" ::: "memory");
            if (kt + 2 < 32) asm volatile("s_waitcnt vmcnt(8)" ::: "memory");
            else             asm volatile("s_waitcnt vmcnt(0)" ::: "memory");
            __builtin_amdgcn_s_barrier();
        }
        cur = (cur >= 2) ? 0 : cur + 1;
    }
    #undef STAGE

    // finalize row sums: reduce across quads, then redistribute to C-layout rows
    float inv[2][4];
    #pragma unroll
    for (int i = 0; i < 2; i++) {
        float s = lsum[i];
        s += __shfl_xor(s, 16);
        s += __shfl_xor(s, 32);
        #pragma unroll
        for (int r = 0; r < 4; r++)
            inv[i][r] = 1.f / __shfl(s, (lane & 48) | (quad*4 + r));
    }
    #pragma unroll
    for (int i = 0; i < 2; i++)
        #pragma unroll
        for (int r = 0; r < 4; r++) {
            int row = m0 + wm + i*16 + quad*4 + r;
            #pragma unroll
            for (int j = 0; j < 4; j++)
                O[qkbase + (size_t)row * 1024 + j*16 + l15] = f2bf(oacc[i][j][r] * inv[i][r]);
        }
}

// ---------------------------------------------------------------------------
// Launch
// ---------------------------------------------------------------------------
extern "C" void kernel_launch(void* const* d_in, const int* in_sizes, int n_in,
                              void* d_out, int out_size, void* d_ws, size_t ws_size,
                              hipStream_t stream) {
    (void)n_in; (void)out_size; (void)ws_size;
    const float* x     = (const float*)d_in[0];
    const float* ln1_g = (const float*)d_in[1];
    const float* ln1_b = (const float*)d_in[2];
    const float* Uq    = (const float*)d_in[3];
    const float* Vq    = (const float*)d_in[4];
    const float* bq    = (const float*)d_in[5];
    const float* Uk    = (const float*)d_in[6];
    const float* Vk    = (const float*)d_in[7];
    const float* bk    = (const float*)d_in[8];
    const float* Uv    = (const float*)d_in[9];
    const float* Vv    = (const float*)d_in[10];
    const float* bv    = (const float*)d_in[11];
    const float* Wo    = (const float*)d_in[12];
    const float* bo    = (const float*)d_in[13];
    const float* ln2_g = (const float*)d_in[14];
    const float* ln2_b = (const float*)d_in[15];
    const float* U1    = (const float*)d_in[16];
    const float* V1    = (const float*)d_in[17];
    const float* b1    = (const float*)d_in[18];
    const float* U2    = (const float*)d_in[19];
    const float* V2    = (const float*)d_in[20];
    const float* b2    = (const float*)d_in[21];
    float* out = (float*)d_out;
    char* ws = (char*)d_ws;

    u16* UQKVT = (u16*)(ws + OFF_UQKVT);
    u16* VQKVT = (u16*)(ws + OFF_VQKVT);
    u16* WOB   = (u16*)(ws + OFF_WOB);
    u16* U1T   = (u16*)(ws + OFF_U1T);
    u16* V1TP  = (u16*)(ws + OFF_V1TP);
    u16* U2T   = (u16*)(ws + OFF_U2T);
    u16* V2T   = (u16*)(ws + OFF_V2T);
    float* BQKV = (float*)(ws + OFF_BQKV);
    float* B1P  = (float*)(ws + OFF_B1P);
    u16* xn  = (u16*)(ws + OFF_XN);
    u16* tbuf= (u16*)(ws + OFF_TBUF);
    u16* qb  = (u16*)(ws + OFF_QB);
    u16* kb  = (u16*)(ws + OFF_KB);
    u16* vtb = (u16*)(ws + OFF_VTB);
    u16* ob  = (u16*)(ws + OFF_OB);
    u16* hb  = (u16*)(ws + OFF_HB);
    u16* scr = (u16*)(ws + OFF_VTB);   // dead scratch during FFN
    float* x2 = (float*)(ws + OFF_X2);

    // ---- all weight prep: single launch ----
    prep_kernel<<<12304, 256, 0, stream>>>(
        Uq, Uk, Uv, Vq, Vk, Vv, Wo, U1, V1, U2, V2, bq, bk, bv, b1,
        UQKVT, VQKVT, WOB, U1T, V1TP, U2T, V2T, BQKV, B1P);

    // ---- LN1 ----
    ln_kernel<<<1024, 256, 0, stream>>>(x, ln1_g, ln1_b, xn);

    // ---- QKV ----
    gemm_bt64_kernel<<<dim3(24, 32), 256, 0, stream>>>(xn, 1024, UQKVT, tbuf, 1536,
                                                       nullptr, nullptr, 1024, 1);
    qkv2_kernel<<<dim3(8, 32, 3), 256, 0, stream>>>(tbuf, VQKVT, BQKV, qb, kb, vtb);

    // ---- attention ----
    attn_kernel<<<dim3(32, 16), 256, 0, stream>>>(qb, kb, vtb, ob);

    // ---- out proj + residual ----
    gemm_bt64_kernel<<<dim3(16, 32), 256, 0, stream>>>(ob, 1024, WOB, x2, 1024,
                                                       bo, x, 1024, 0);
    // ---- LN2 ----
    ln_kernel<<<1024, 256, 0, stream>>>(x2, ln2_g, ln2_b, xn);

    // ---- FFN ----
    gemm_bt64_kernel<<<dim3(16, 32), 256, 0, stream>>>(xn, 1024, U1T, tbuf, 1024,
                                                       nullptr, nullptr, 1024, 1);
    gemm256_geglu_kernel<0><<<dim3(256), 512, 0, stream>>>(tbuf, V1TP, hb, B1P, 1024);
    // keep V1..V4 instantiated (rule #19 codegen context) without running:
    if (in_sizes[0] < 0) {
        gemm256_geglu_kernel<1><<<dim3(256), 512, 0, stream>>>(tbuf, V1TP, scr, B1P, 1024);
        gemm256_geglu_kernel<2><<<dim3(256), 512, 0, stream>>>(tbuf, V1TP, scr, B1P, 1024);
        gemm256_geglu_kernel<3><<<dim3(256), 512, 0, stream>>>(tbuf, V1TP, scr, B1P, 1024);
        gemm256_geglu_kernel<4><<<dim3(256), 512, 0, stream>>>(tbuf, V1TP, scr, B1P, 1024);
    }
    gemm_bt64_kernel<<<dim3(16, 32), 256, 0, stream>>>(hb, 2048, U2T, tbuf, 1024,
                                                       nullptr, nullptr, 2048, 1);
    gemm_bt64_kernel<<<dim3(16, 32), 256, 0, stream>>>(tbuf, 1024, V2T, out, 1024,
                                                       b2, x2, 1024, 0);
}

// Round 8
// 409.255 us; speedup vs baseline: 1.2952x; 1.0148x over previous
//
#include <hip/hip_runtime.h>

// ============================================================================
// ExplicitSVDBlock round 13:
//  - attn_kernel v8: ADDRESS-HOIST round. r12 showed VALUBusy 45% with a
//    ~100cyc algorithmic VALU floor -> ~7x addressing overhead: STAGE
//    recomputed 4 full 64-bit addresses per kt, and v7's dynamic Ks[cur]
//    made all 16 fragment ds_reads dynamic-base. v8: 2 LDS buffers with
//    COMPILE-TIME indices (unroll-by-2), hoisted kp/vp global pointers
//    advanced by constants, v4-style sync. Same math, same swizzles.
//  - everything else unchanged from r12.
// ============================================================================

typedef unsigned short u16;
typedef unsigned int u32;
typedef u16 u16x8 __attribute__((ext_vector_type(8)));
typedef __bf16 bf16x8 __attribute__((ext_vector_type(8)));
typedef float f32x4 __attribute__((ext_vector_type(4)));

__device__ __forceinline__ u16 f2bf(float f) {
    u32 u = __builtin_bit_cast(u32, f);
    u += 0x7fff + ((u >> 16) & 1);          // RNE
    return (u16)(u >> 16);
}
__device__ __forceinline__ float bf2f(u16 h) {
    u32 u = ((u32)h) << 16;
    return __builtin_bit_cast(float, u);
}
__device__ __forceinline__ u32 packbf(float a, float b) {
    return __builtin_amdgcn_perm(__builtin_bit_cast(u32, b),
                                 __builtin_bit_cast(u32, a), 0x07060302u);
}

__device__ __forceinline__ void gload16(const void* g, void* l) {
    __builtin_amdgcn_global_load_lds(
        (const __attribute__((address_space(1))) void*)g,
        (__attribute__((address_space(3))) void*)l, 16, 0, 0);
}

// ---------------------------------------------------------------------------
// Workspace layout. Total 109 MB.
// ---------------------------------------------------------------------------
#define MB 1048576u
#define OFF_UQKVT (0*MB)    // bf16 [1536][1024]
#define OFF_VQKVT (3*MB)    // bf16 [3][1024][512]
#define OFF_WOB   (6*MB)    // bf16 [1024][1024]
#define OFF_U1T   (8*MB)    // bf16 [1024][1024]
#define OFF_V1TP  (10*MB)   // bf16 [4096][1024]  col-interleaved for geglu
#define OFF_U2T   (18*MB)   // bf16 [1024][2048]
#define OFF_V2T   (22*MB)   // bf16 [1024][1024]
#define OFF_BQKV  (24*MB)   // f32 [3][1024]; +16KB: b1p f32 [4096]
#define OFF_B1P   (24*MB + 16384u)
#define OFF_XN    (25*MB)   // bf16 [4096][1024]
#define OFF_TBUF  (33*MB)   // bf16 [4096][1536]
#define OFF_QB    (45*MB)   // bf16 [4096][1024] (q) -- dead after attn
#define OFF_KB    (53*MB)   // bf16 [4096][1024] (k) -- dead after attn
#define OFF_HB    (45*MB)   // bf16 [4096][2048] (h; reuses q/k space)
#define OFF_VTB   (61*MB)   // bf16 [32][64][2048] -- dead after attn (scratch)
#define OFF_OB    (69*MB)   // bf16 [4096][1024]
#define OFF_X2    (93*MB)   // f32  [4096][1024]

// ---------------------------------------------------------------------------
// Fused weight prep (single launch, block-range dispatch). Grid = 12304.
// ---------------------------------------------------------------------------
__global__ __launch_bounds__(256) void prep_kernel(
    const float* __restrict__ Uq, const float* __restrict__ Uk,
    const float* __restrict__ Uv, const float* __restrict__ Vq,
    const float* __restrict__ Vk, const float* __restrict__ Vv,
    const float* __restrict__ Wo, const float* __restrict__ U1,
    const float* __restrict__ V1, const float* __restrict__ U2,
    const float* __restrict__ V2,
    const float* __restrict__ bq, const float* __restrict__ bk,
    const float* __restrict__ bv, const float* __restrict__ b1,
    u16* __restrict__ UQKVT, u16* __restrict__ VQKVT, u16* __restrict__ WOB,
    u16* __restrict__ U1T, u16* __restrict__ V1TP, u16* __restrict__ U2T,
    u16* __restrict__ V2T, float* __restrict__ BQKV, float* __restrict__ B1P)
{
    __shared__ float tile[32][33];
    int bid = blockIdx.x;

    if (bid >= 12288) {            // biascat
        int id = (bid - 12288) * 256 + threadIdx.x;   // 0..4095
        if (id < 3072) {
            float v = (id < 1024) ? bq[id] : (id < 2048 ? bk[id - 1024] : bv[id - 2048]);
            BQKV[id] = v;
        }
        int g = id >> 7, q = id & 127;
        B1P[id] = b1[(q < 64) ? (g*64 + q) : (2048 + g*64 + (q - 64))];
        return;
    }
    if (bid >= 11264) {            // Wo convert
        int i4 = ((bid - 11264) * 256 + threadIdx.x) * 4;
        float4 v = *(const float4*)(Wo + i4);
        u16 tmp[4] = {f2bf(v.x), f2bf(v.y), f2bf(v.z), f2bf(v.w)};
        *(uint2*)(WOB + i4) = *(const uint2*)tmp;
        return;
    }

    const float* src; u16* dst; int K, N, src_ld, nx; bool gg = false;
    if (bid < 3072) {
        int t = bid / 512; bid -= t * 512;
        if (t < 3) { src = t==0 ? Uq : (t==1 ? Uk : Uv);
                     dst = UQKVT + t * 512*1024; K = 1024; N = 512; src_ld = 512; nx = 16; }
        else { int z = t - 3; src = z==0 ? Vq : (z==1 ? Vk : Vv);
               dst = VQKVT + z * 524288; K = 512; N = 1024; src_ld = 1024; nx = 32; }
    } else if (bid < 4096)  { src = U1; dst = U1T;  K = 1024; N = 1024; src_ld = 1024; nx = 32;  bid -= 3072; }
    else if (bid < 8192)    { src = V1; dst = V1TP; K = 1024; N = 4096; src_ld = 4096; nx = 128; bid -= 4096; gg = true; }
    else if (bid < 10240)   { src = U2; dst = U2T;  K = 2048; N = 1024; src_ld = 1024; nx = 32;  bid -= 8192; }
    else                    { src = V2; dst = V2T;  K = 1024; N = 1024; src_ld = 1024; nx = 32;  bid -= 10240; }

    int tx = threadIdx.x & 31, ty = threadIdx.x >> 5;
    int n0 = (bid % nx) * 32, k0 = (bid / nx) * 32;
    int srccol;
    if (gg) { int p = n0 + tx; int g = p >> 7, q = p & 127;
              srccol = (q < 64) ? (g*64 + q) : (2048 + g*64 + (q - 64)); }
    else srccol = n0 + tx;
    for (int i = 0; i < 4; i++)
        tile[ty + i*8][tx] = src[(size_t)(k0 + ty + i*8) * src_ld + srccol];
    __syncthreads();
    for (int i = 0; i < 4; i++)
        dst[(size_t)(n0 + ty + i*8) * K + k0 + tx] = f2bf(tile[tx][ty + i*8]);
}

// ---------------------------------------------------------------------------
// LayerNorm
// ---------------------------------------------------------------------------
__global__ __launch_bounds__(256) void ln_kernel(
    const float* __restrict__ x, const float* __restrict__ g,
    const float* __restrict__ bta, u16* __restrict__ out)
{
    int w = threadIdx.x >> 6, lane = threadIdx.x & 63;
    int row = blockIdx.x * 4 + w;
    const float* xr = x + (size_t)row * 1024;
    float vals[16];
    float s = 0.f, s2 = 0.f;
    #pragma unroll
    for (int ii = 0; ii < 16; ii++) {
        float v = xr[lane + ii*64];
        vals[ii] = v; s += v; s2 += v * v;
    }
    #pragma unroll
    for (int off = 1; off < 64; off <<= 1) {
        s  += __shfl_xor(s, off);
        s2 += __shfl_xor(s2, off);
    }
    float mu = s * (1.f/1024.f);
    float var = s2 * (1.f/1024.f) - mu * mu;
    float rs = rsqrtf(var + 1e-5f);
    #pragma unroll
    for (int ii = 0; ii < 16; ii++) {
        int col = lane + ii*64;
        out[(size_t)row * 1024 + col] = f2bf((vals[ii] - mu) * rs * g[col] + bta[col]);
    }
}

// ---------------------------------------------------------------------------
// 256x256 pipelined GEMM + fused GEGLU epilogue, template (V0 real;
// V1..V4 instantiated-only to preserve codegen context, rule #19).
// ---------------------------------------------------------------------------
template<int V>
__global__ __launch_bounds__(512, 2) void gemm256_geglu_kernel(
    const u16* __restrict__ A, const u16* __restrict__ Bt,
    u16* __restrict__ hb, const float* __restrict__ bias, int Kdim)
{
    constexpr bool S = (V==0 || V==2 || V==3);   // in-loop staging + vmcnt
    constexpr bool D = (V==0 || V==1 || V==2);   // in-loop fragment ds_reads
    constexpr bool E = (V==0 || V==1 || V==3);   // full GEGLU epilogue

    __shared__ u16 As[2][16384];   // [256 rows][64 cols]
    __shared__ u16 Bs[2][16384];
    int tid = threadIdx.x;
    int wg = (blockIdx.x & 7) * 32 + (blockIdx.x >> 3);
    int m0 = (wg >> 4) * 256, n0 = (wg & 15) * 256;
    int w = tid >> 6, lane = tid & 63, quad = lane >> 4, l15 = lane & 15;
    int wr = (w >> 2) * 16, wc = (w & 3) * 16;
    int xsw = l15 & 7;
    int s0 = (quad ^ xsw) * 8, s1 = s0 ^ 32;   // swizzled K-slot offsets (elems)

    int srow = tid >> 3;                          // 0..63
    int scol = ((tid & 7) ^ (srow & 7)) * 8;      // inverse swizzle on source
    const u16* Ap = A  + (size_t)(m0 + srow) * Kdim + scol;
    const u16* Bp = Bt + (size_t)(n0 + srow) * Kdim + scol;

    int abase = (wr + l15) * 64;   // elem offset of A row (mi=0)
    int bbase = (wc + l15) * 64;   // elem offset of B row (ni=0)

    f32x4 acc[8][4] = {};

#define STG_A(buf, t, h) do {                                                      \
    gload16(Ap + (size_t)(t)*64 + (size_t)((h)*128     )*Kdim,                     \
            &As[buf][(h)*8192 + tid*8]);                                           \
    gload16(Ap + (size_t)(t)*64 + (size_t)((h)*128 + 64)*Kdim,                     \
            &As[buf][(h)*8192 + 4096 + tid*8]);                                    \
} while (0)
#define STG_B(buf, t, h) do {                                                      \
    gload16(Bp + (size_t)(t)*64 + (size_t)((h)*128     )*Kdim,                     \
            &Bs[buf][(h)*8192 + tid*8]);                                           \
    gload16(Bp + (size_t)(t)*64 + (size_t)((h)*128 + 64)*Kdim,                     \
            &Bs[buf][(h)*8192 + 4096 + tid*8]);                                    \
} while (0)
#define SB()  __builtin_amdgcn_sched_barrier(0)

    int nt = Kdim >> 6;   // K-tiles of 64 (V1: 16)

    // ---- prologue: stage tiles 0,1 fully; confirm t0; preload lo frags ----
    STG_A(0, 0, 0); STG_A(0, 0, 1); STG_B(0, 0, 0); STG_B(0, 0, 1);
    STG_A(1, 1, 0); STG_A(1, 1, 1); STG_B(1, 1, 0); STG_B(1, 1, 1);
    asm volatile("s_waitcnt vmcnt(8)" ::: "memory");
    __builtin_amdgcn_s_barrier();
    SB();

    bf16x8 afl[4][2], afh[4][2], bfl[2][2], bfh[2][2];
    {
        const u16* A0 = As[0];
        const u16* B0 = Bs[0];
        #pragma unroll
        for (int i = 0; i < 4; i++) {
            afl[i][0] = *(const bf16x8*)&A0[abase + i*2048 + s0];
            afl[i][1] = *(const bf16x8*)&A0[abase + i*2048 + s1];
        }
        #pragma unroll
        for (int j = 0; j < 2; j++) {
            bfl[j][0] = *(const bf16x8*)&B0[bbase + j*4096 + s0];
            bfl[j][1] = *(const bf16x8*)&B0[bbase + j*4096 + s1];
        }
    }
    if constexpr (!D) {   // V3/V4: init hi frags once (no in-loop reads)
        #pragma unroll
        for (int i = 0; i < 4; i++) { afh[i][0] = afl[i][0]; afh[i][1] = afl[i][1]; }
        #pragma unroll
        for (int j = 0; j < 2; j++) { bfh[j][0] = bfl[j][0]; bfh[j][1] = bfl[j][1]; }
    }

    for (int t = 0; t < nt; ++t) {
        int buf = t & 1;
        const u16* Asc = As[buf];
        const u16* Bsc = Bs[buf];
        const u16* Asn = As[buf ^ 1];
        const u16* Bsn = Bs[buf ^ 1];
        bool more = (t + 1 < nt);
        bool st   = (t + 2 < nt);

        // ---- q0: issue B-hi(t); MFMA lo x lo ----
        if constexpr (D) {
            #pragma unroll
            for (int j = 0; j < 2; j++) {
                bfh[j][0] = *(const bf16x8*)&Bsc[bbase + 8192 + j*4096 + s0];
                bfh[j][1] = *(const bf16x8*)&Bsc[bbase + 8192 + j*4096 + s1];
            }
            SB();
        }
        __builtin_amdgcn_s_setprio(1);
        #pragma unroll
        for (int i = 0; i < 4; i++)
            #pragma unroll
            for (int j = 0; j < 2; j++) {
                acc[i][j] = __builtin_amdgcn_mfma_f32_16x16x32_bf16(afl[i][0], bfl[j][0], acc[i][j], 0, 0, 0);
                acc[i][j] = __builtin_amdgcn_mfma_f32_16x16x32_bf16(afl[i][1], bfl[j][1], acc[i][j], 0, 0, 0);
            }
        __builtin_amdgcn_s_setprio(0);

        // ---- q1: issue A-hi(t); MFMA lo x hi ----
        if constexpr (D) {
            #pragma unroll
            for (int i = 0; i < 4; i++) {
                afh[i][0] = *(const bf16x8*)&Asc[abase + 8192 + i*2048 + s0];
                afh[i][1] = *(const bf16x8*)&Asc[abase + 8192 + i*2048 + s1];
            }
            SB();
        }
        __builtin_amdgcn_s_setprio(1);
        #pragma unroll
        for (int i = 0; i < 4; i++)
            #pragma unroll
            for (int j = 0; j < 2; j++) {
                acc[i][2+j] = __builtin_amdgcn_mfma_f32_16x16x32_bf16(afl[i][0], bfh[j][0], acc[i][2+j], 0, 0, 0);
                acc[i][2+j] = __builtin_amdgcn_mfma_f32_16x16x32_bf16(afl[i][1], bfh[j][1], acc[i][2+j], 0, 0, 0);
            }
        __builtin_amdgcn_s_setprio(0);

        // ---- sync block (once per tile) ----
        if (more) {
            SB();
            asm volatile("s_waitcnt lgkmcnt(0)" ::: "memory");
            __builtin_amdgcn_s_barrier();                        // B1: buf reusable
            SB();
            if constexpr (S) {
                if (st) { STG_A(buf, t+2, 0); STG_A(buf, t+2, 1);
                          STG_B(buf, t+2, 0); STG_B(buf, t+2, 1); }
                SB();
                if (st) asm volatile("s_waitcnt vmcnt(8)" ::: "memory");
                else    asm volatile("s_waitcnt vmcnt(0)" ::: "memory");
            }
            __builtin_amdgcn_s_barrier();                        // B2: buf^1 valid
            SB();
            if constexpr (D) {
                #pragma unroll
                for (int i = 0; i < 4; i++) {
                    afl[i][0] = *(const bf16x8*)&Asn[abase + i*2048 + s0];
                    afl[i][1] = *(const bf16x8*)&Asn[abase + i*2048 + s1];
                }
                SB();
            }
        }

        // ---- q2: MFMA hi x lo ----
        __builtin_amdgcn_s_setprio(1);
        #pragma unroll
        for (int i = 0; i < 4; i++)
            #pragma unroll
            for (int j = 0; j < 2; j++) {
                acc[4+i][j] = __builtin_amdgcn_mfma_f32_16x16x32_bf16(afh[i][0], bfl[j][0], acc[4+i][j], 0, 0, 0);
                acc[4+i][j] = __builtin_amdgcn_mfma_f32_16x16x32_bf16(afh[i][1], bfl[j][1], acc[4+i][j], 0, 0, 0);
            }
        __builtin_amdgcn_s_setprio(0);

        // ---- q3: issue B-lo(t+1); MFMA hi x hi ----
        if constexpr (D) {
            if (more) {
                #pragma unroll
                for (int j = 0; j < 2; j++) {
                    bfl[j][0] = *(const bf16x8*)&Bsn[bbase + j*4096 + s0];
                    bfl[j][1] = *(const bf16x8*)&Bsn[bbase + j*4096 + s1];
                }
                SB();
            }
        }
        __builtin_amdgcn_s_setprio(1);
        #pragma unroll
        for (int i = 0; i < 4; i++)
            #pragma unroll
            for (int j = 0; j < 2; j++) {
                acc[4+i][2+j] = __builtin_amdgcn_mfma_f32_16x16x32_bf16(afh[i][0], bfh[j][0], acc[4+i][2+j], 0, 0, 0);
                acc[4+i][2+j] = __builtin_amdgcn_mfma_f32_16x16x32_bf16(afh[i][1], bfh[j][1], acc[4+i][2+j], 0, 0, 0);
            }
        __builtin_amdgcn_s_setprio(0);
    }
#undef STG_A
#undef STG_B
#undef SB

    if constexpr (E) {
        // ---- GEGLU epilogue: pairs (ni=2p, ni=2p+1) = packed cols c, c+64 ----
        #pragma unroll
        for (int mi = 0; mi < 8; mi++) {
            int row = m0 + wr + mi*32 + quad*4;
            #pragma unroll
            for (int p = 0; p < 2; p++) {
                int c1 = n0 + p*128 + wc + l15;
                float bz1 = bias[c1], bz2 = bias[c1 + 64];
                int hcol = (n0 >> 1) + p*64 + wc + l15;
                #pragma unroll
                for (int r = 0; r < 4; r++) {
                    float z1 = acc[mi][2*p][r] + bz1;
                    float z2 = acc[mi][2*p+1][r] + bz2;
                    float uu = 0.7978845608028654f * (z1 + 0.044715f * z1 * z1 * z1);
                    float e = __expf(2.f * uu);
                    float th = (e - 1.f) / (e + 1.f);
                    float hv = 0.5f * z1 * (1.f + th) * z2;
                    hb[(size_t)(row + r) * 2048 + hcol] = f2bf(hv);
                }
            }
        }
    } else {
        // cheap keep-alive store: sum all acc (keeps every MFMA live, rule #17)
        f32x4 ssum = {};
        #pragma unroll
        for (int mi = 0; mi < 8; mi++)
            #pragma unroll
            for (int j = 0; j < 4; j++)
                ssum += acc[mi][j];
        ((f32x4*)hb)[(size_t)blockIdx.x * 512 + tid] = ssum;
    }
}

// ---------------------------------------------------------------------------
// Pipelined GEMM, 128x64 tile (qkv1, Wo, U1, U2, V2).
// ---------------------------------------------------------------------------
__global__ __launch_bounds__(256) void gemm_bt64_kernel(
    const u16* __restrict__ A, int lda, const u16* __restrict__ Bt,
    void* __restrict__ Cout, int ldc, const float* __restrict__ bias,
    const float* __restrict__ resid, int Kdim, int mode)
{
    __shared__ u16 As[2][4096];
    __shared__ u16 Bs[2][2048];
    int tid = threadIdx.x;
    int m0 = blockIdx.y * 128, n0 = blockIdx.x * 64;
    int w = tid >> 6, lane = tid & 63, quad = lane >> 4, l15 = lane & 15;
    int wm = (w >> 1) * 64, wn = (w & 1) * 32;
    int sr = tid >> 2, sc8 = (tid & 3) * 8;

    f32x4 acc[4][2] = {};

    const u16* Ap = A  + (size_t)(m0 + sr) * lda  + sc8;
    const u16* Bp = Bt + (size_t)(n0 + sr) * Kdim + sc8;   // sr<64 rows of B

    #define GSTAGE64(buf, koff) do {                                       \
        gload16(Ap + (koff),                     &As[buf][tid * 8]);       \
        gload16(Ap + (koff) + (size_t)64 * lda,  &As[buf][2048 + tid*8]);  \
        gload16(Bp + (koff),                     &Bs[buf][tid * 8]);       \
    } while (0)

    GSTAGE64(0, 0);
    __syncthreads();

    for (int k0 = 0; k0 < Kdim; k0 += 32) {
        int cur = (k0 >> 5) & 1;
        if (k0 + 32 < Kdim) GSTAGE64(cur ^ 1, k0 + 32);
        const u16* Asc = As[cur];
        const u16* Bsc = Bs[cur];
        bf16x8 af[4], bfr[2];
        #pragma unroll
        for (int i = 0; i < 4; i++)
            af[i] = *(const bf16x8*)&Asc[(wm + i*16 + l15) * 32 + quad * 8];
        #pragma unroll
        for (int j = 0; j < 2; j++)
            bfr[j] = *(const bf16x8*)&Bsc[(wn + j*16 + l15) * 32 + quad * 8];
        #pragma unroll
        for (int i = 0; i < 4; i++)
            #pragma unroll
            for (int j = 0; j < 2; j++)
                acc[i][j] = __builtin_amdgcn_mfma_f32_16x16x32_bf16(af[i], bfr[j], acc[i][j], 0, 0, 0);
        __syncthreads();
    }
    #undef GSTAGE64

    #pragma unroll
    for (int i = 0; i < 4; i++) {
        int row = m0 + wm + i*16 + quad*4;
        #pragma unroll
        for (int j = 0; j < 2; j++) {
            int col = n0 + wn + j*16 + l15;
            float bv = bias ? bias[col] : 0.f;
            #pragma unroll
            for (int r = 0; r < 4; r++) {
                float v = acc[i][j][r] + bv;
                size_t idx = (size_t)(row + r) * ldc + col;
                if (mode == 0) ((float*)Cout)[idx] = v + resid[idx];
                else           ((u16*)Cout)[idx] = f2bf(v);
            }
        }
    }
}

// ---------------------------------------------------------------------------
// QKV stage-2 batched pipelined GEMM (z: 0=q(+rope,pre-scale) 1=k(+rope) 2=v^T)
// ---------------------------------------------------------------------------
__global__ __launch_bounds__(256) void qkv2_kernel(
    const u16* __restrict__ T, const u16* __restrict__ Vw,
    const float* __restrict__ bqkv, u16* __restrict__ qout,
    u16* __restrict__ kout, u16* __restrict__ vtout)
{
    __shared__ u16 As[2][4096];
    __shared__ u16 Bs[2][4096];
    int tid = threadIdx.x;
    int z = blockIdx.z;
    int m0 = blockIdx.y * 128, n0 = blockIdx.x * 128;
    int w = tid >> 6, lane = tid & 63, quad = lane >> 4, l15 = lane & 15;
    int wm = (w >> 1) * 64, wn = (w & 1) * 64;
    int sr = tid >> 2, sc8 = (tid & 3) * 8;

    f32x4 acc[4][4] = {};

    const u16* Ap = T  + (size_t)z * 512 + (size_t)(m0 + sr) * 1536 + sc8;
    const u16* Bp = Vw + (size_t)z * 512 * 1024 + (size_t)(n0 + sr) * 512 + sc8;

    #define QSTAGE(buf, koff) do {                                        \
        gload16(Ap + (koff),                     &As[buf][tid * 8]);      \
        gload16(Ap + (koff) + (size_t)64 * 1536, &As[buf][2048 + tid*8]); \
        gload16(Bp + (koff),                     &Bs[buf][tid * 8]);      \
        gload16(Bp + (koff) + (size_t)64 * 512,  &Bs[buf][2048 + tid*8]); \
    } while (0)

    QSTAGE(0, 0);
    __syncthreads();

    for (int k0 = 0; k0 < 512; k0 += 32) {
        int cur = (k0 >> 5) & 1;
        if (k0 + 32 < 512) QSTAGE(cur ^ 1, k0 + 32);
        const u16* Asc = As[cur];
        const u16* Bsc = Bs[cur];
        bf16x8 af[4], bfr[4];
        #pragma unroll
        for (int i = 0; i < 4; i++)
            af[i] = *(const bf16x8*)&Asc[(wm + i*16 + l15) * 32 + quad * 8];
        #pragma unroll
        for (int j = 0; j < 4; j++)
            bfr[j] = *(const bf16x8*)&Bsc[(wn + j*16 + l15) * 32 + quad * 8];
        #pragma unroll
        for (int i = 0; i < 4; i++)
            #pragma unroll
            for (int j = 0; j < 4; j++)
                acc[i][j] = __builtin_amdgcn_mfma_f32_16x16x32_bf16(af[i], bfr[j], acc[i][j], 0, 0, 0);
        __syncthreads();
    }
    #undef QSTAGE

    const float* bias = bqkv + z * 1024;
    if (z < 2) {
        u16* Ob = z ? kout : qout;
        float qscale = z ? 1.f : 0.18033688011112042f;   // 0.125*log2(e) folded into q
        #pragma unroll
        for (int i = 0; i < 4; i++) {
            int row0 = m0 + wm + i*16 + quad*4;
            #pragma unroll
            for (int j = 0; j < 2; j++) {
                int col = n0 + wn + j*16 + l15;       // (col&63) < 32
                float bj = bias[col], bj2 = bias[col + 32];
                float invf = exp2f((float)(col & 31) * -0.4152410118609203f);
                #pragma unroll
                for (int r = 0; r < 4; r++) {
                    int t = row0 + r;
                    float fr = (float)(t & 2047) * invf;
                    float sn, cs;
                    __sincosf(fr, &sn, &cs);
                    sn *= qscale; cs *= qscale;
                    float v1 = acc[i][j][r] + bj;
                    float v2 = acc[i][j+2][r] + bj2;
                    Ob[(size_t)t * 1024 + col]      = f2bf(v1 * cs - v2 * sn);
                    Ob[(size_t)t * 1024 + col + 32] = f2bf(v2 * cs + v1 * sn);
                }
            }
        }
    } else {
        int bb = m0 >> 11;
        #pragma unroll
        for (int i = 0; i < 4; i++) {
            int row0 = m0 + wm + i*16 + quad*4;
            #pragma unroll
            for (int j = 0; j < 4; j++) {
                int col = n0 + wn + j*16 + l15;
                float bj = bias[col];
                u16 pack[4];
                #pragma unroll
                for (int r = 0; r < 4; r++) pack[r] = f2bf(acc[i][j][r] + bj);
                size_t dst = ((size_t)(bb * 16 + (col >> 6)) * 64 + (col & 63)) * 2048 + (row0 & 2047);
                *(uint2*)&vtout[dst] = *(const uint2*)pack;
            }
        }
    }
}

// ---------------------------------------------------------------------------
// Flash attention v8: QBLK=128, 2 LDS buffers with COMPILE-TIME indices
// (unroll-by-2), hoisted global staging pointers (+= const per kt).
// Same math/swizzles as v4/v7. LDS = 16K(K)+16K(V)+22.5K(Ps) = 54.5KB.
// ---------------------------------------------------------------------------
#define PSTR 88
__global__ __launch_bounds__(256) void attn_kernel(
    const u16* __restrict__ Q, const u16* __restrict__ K,
    const u16* __restrict__ Vt, u16* __restrict__ O)
{
    __shared__ u16 Ks[2][64 * 64];
    __shared__ u16 Vs[2][64 * 64];
    __shared__ u16 Ps[128 * PSTR];
    int tid = threadIdx.x;
    int bh = blockIdx.x;
    int b = bh >> 4, h = bh & 15;
    int m0 = blockIdx.y * 128;
    int w = tid >> 6, lane = tid & 63, quad = lane >> 4, l15 = lane & 15;
    int wm = w * 32;
    size_t qkbase = (size_t)b * 2048 * 1024 + h * 64;
    const u16* Vg = Vt + (size_t)bh * 64 * 2048;

    bf16x8 qf[2][2];
    #pragma unroll
    for (int i = 0; i < 2; i++)
        #pragma unroll
        for (int ks = 0; ks < 2; ks++)
            qf[i][ks] = *(const bf16x8*)(Q + qkbase +
                (size_t)(m0 + wm + i*16 + l15) * 1024 + ks*32 + quad*8);

    f32x4 oacc[2][4] = {};
    float lsum[2] = {};     // per-lane partial row-sum for qrow = wm + i*16 + l15

    int r0 = tid >> 3, p = tid & 7;
    int c0 = (p ^ (r0 & 7)) * 8;
    int xsw = l15 & 7;

    // hoisted staging pointers (currently at kt=0 tile); advance by consts
    const u16* kp = K + qkbase + (size_t)r0 * 1024 + c0;
    const u16* vp = Vg + (size_t)r0 * 2048 + c0;

    // STG(bufl): stage current-kp/vp tile into LDS buffer literal bufl
    #define STG(bufl) do {                                                      \
        gload16(kp,             &Ks[bufl][r0 * 64 + p * 8]);                    \
        gload16(kp + 32*1024,   &Ks[bufl][(r0 + 32) * 64 + p * 8]);             \
        gload16(vp,             &Vs[bufl][r0 * 64 + p * 8]);                    \
        gload16(vp + 32*2048,   &Vs[bufl][(r0 + 32) * 64 + p * 8]);             \
        kp += 64*1024; vp += 64;                                                \
    } while (0)

    #define SYNC() do {                                                         \
        asm volatile("s_waitcnt lgkmcnt(0)" ::: "memory");                      \
        asm volatile("s_waitcnt vmcnt(0)" ::: "memory");                        \
        __builtin_amdgcn_s_barrier();                                           \
    } while (0)

    // BODY(bufl): QK^T -> softmax/pack -> PV against LDS buffer literal bufl
    #define BODY(bufl) do {                                                     \
        f32x4 sacc[4][2] = {};                                                  \
        _Pragma("unroll")                                                       \
        for (int ks = 0; ks < 2; ks++) {                                        \
            bf16x8 kf[4];                                                       \
            _Pragma("unroll")                                                   \
            for (int jj = 0; jj < 4; jj++)                                      \
                kf[jj] = *(const bf16x8*)&Ks[bufl][(jj*16 + l15) * 64 +         \
                                                   (((ks*4 + quad) ^ xsw) * 8)];\
            _Pragma("unroll")                                                   \
            for (int jj = 0; jj < 4; jj++)                                      \
                _Pragma("unroll")                                               \
                for (int i = 0; i < 2; i++)                                     \
                    sacc[jj][i] = __builtin_amdgcn_mfma_f32_16x16x32_bf16(      \
                        kf[jj], qf[i][ks], sacc[jj][i], 0, 0, 0);               \
        }                                                                       \
        _Pragma("unroll")                                                       \
        for (int i = 0; i < 2; i++) {                                           \
            int prow = (wm + i*16 + l15) * PSTR + quad*4;                       \
            _Pragma("unroll")                                                   \
            for (int jj = 0; jj < 4; jj++) {                                    \
                float p0 = __builtin_amdgcn_exp2f(sacc[jj][i][0]);              \
                float p1 = __builtin_amdgcn_exp2f(sacc[jj][i][1]);              \
                float p2 = __builtin_amdgcn_exp2f(sacc[jj][i][2]);              \
                float p3 = __builtin_amdgcn_exp2f(sacc[jj][i][3]);              \
                lsum[i] += (p0 + p1) + (p2 + p3);                               \
                uint2 pk; pk.x = packbf(p0, p1); pk.y = packbf(p2, p3);         \
                *(uint2*)&Ps[prow + jj*16] = pk;                                \
            }                                                                   \
        }                                                                       \
        _Pragma("unroll")                                                       \
        for (int ks = 0; ks < 2; ks++) {                                        \
            bf16x8 pf[2], vf[4];                                                \
            _Pragma("unroll")                                                   \
            for (int i = 0; i < 2; i++)                                         \
                pf[i] = *(const bf16x8*)&Ps[(wm + i*16 + l15) * PSTR +          \
                                            ks*32 + quad*8];                    \
            _Pragma("unroll")                                                   \
            for (int j = 0; j < 4; j++)                                         \
                vf[j] = *(const bf16x8*)&Vs[bufl][(j*16 + l15) * 64 +           \
                                                  (((ks*4 + quad) ^ xsw) * 8)]; \
            _Pragma("unroll")                                                   \
            for (int i = 0; i < 2; i++)                                         \
                _Pragma("unroll")                                               \
                for (int j = 0; j < 4; j++)                                     \
                    oacc[i][j] = __builtin_amdgcn_mfma_f32_16x16x32_bf16(       \
                        pf[i], vf[j], oacc[i][j], 0, 0, 0);                     \
        }                                                                       \
    } while (0)

    // prologue: stage kt=0 into buf0 (pointers advance to kt=1)
    STG(0);
    SYNC();

    for (int kt2 = 0; kt2 < 16; ++kt2) {
        // half A: kt = 2*kt2, read buf0; stage kt+1 into buf1 (always valid)
        STG(1);
        BODY(0);
        SYNC();
        // half B: kt = 2*kt2+1, read buf1; stage kt+1 into buf0 (if any)
        if (kt2 < 15) {
            STG(0);
            BODY(1);
            SYNC();
        } else {
            BODY(1);
        }
    }
    #undef STG
    #undef SYNC
    #undef BODY

    // finalize row sums: reduce across quads, then redistribute to C-layout rows
    float inv[2][4];
    #pragma unroll
    for (int i = 0; i < 2; i++) {
        float s = lsum[i];
        s += __shfl_xor(s, 16);
        s += __shfl_xor(s, 32);
        #pragma unroll
        for (int r = 0; r < 4; r++)
            inv[i][r] = 1.f / __shfl(s, (lane & 48) | (quad*4 + r));
    }
    #pragma unroll
    for (int i = 0; i < 2; i++)
        #pragma unroll
        for (int r = 0; r < 4; r++) {
            int row = m0 + wm + i*16 + quad*4 + r;
            #pragma unroll
            for (int j = 0; j < 4; j++)
                O[qkbase + (size_t)row * 1024 + j*16 + l15] = f2bf(oacc[i][j][r] * inv[i][r]);
        }
}

// ---------------------------------------------------------------------------
// Launch
// ---------------------------------------------------------------------------
extern "C" void kernel_launch(void* const* d_in, const int* in_sizes, int n_in,
                              void* d_out, int out_size, void* d_ws, size_t ws_size,
                              hipStream_t stream) {
    (void)n_in; (void)out_size; (void)ws_size;
    const float* x     = (const float*)d_in[0];
    const float* ln1_g = (const float*)d_in[1];
    const float* ln1_b = (const float*)d_in[2];
    const float* Uq    = (const float*)d_in[3];
    const float* Vq    = (const float*)d_in[4];
    const float* bq    = (const float*)d_in[5];
    const float* Uk    = (const float*)d_in[6];
    const float* Vk    = (const float*)d_in[7];
    const float* bk    = (const float*)d_in[8];
    const float* Uv    = (const float*)d_in[9];
    const float* Vv    = (const float*)d_in[10];
    const float* bv    = (const float*)d_in[11];
    const float* Wo    = (const float*)d_in[12];
    const float* bo    = (const float*)d_in[13];
    const float* ln2_g = (const float*)d_in[14];
    const float* ln2_b = (const float*)d_in[15];
    const float* U1    = (const float*)d_in[16];
    const float* V1    = (const float*)d_in[17];
    const float* b1    = (const float*)d_in[18];
    const float* U2    = (const float*)d_in[19];
    const float* V2    = (const float*)d_in[20];
    const float* b2    = (const float*)d_in[21];
    float* out = (float*)d_out;
    char* ws = (char*)d_ws;

    u16* UQKVT = (u16*)(ws + OFF_UQKVT);
    u16* VQKVT = (u16*)(ws + OFF_VQKVT);
    u16* WOB   = (u16*)(ws + OFF_WOB);
    u16* U1T   = (u16*)(ws + OFF_U1T);
    u16* V1TP  = (u16*)(ws + OFF_V1TP);
    u16* U2T   = (u16*)(ws + OFF_U2T);
    u16* V2T   = (u16*)(ws + OFF_V2T);
    float* BQKV = (float*)(ws + OFF_BQKV);
    float* B1P  = (float*)(ws + OFF_B1P);
    u16* xn  = (u16*)(ws + OFF_XN);
    u16* tbuf= (u16*)(ws + OFF_TBUF);
    u16* qb  = (u16*)(ws + OFF_QB);
    u16* kb  = (u16*)(ws + OFF_KB);
    u16* vtb = (u16*)(ws + OFF_VTB);
    u16* ob  = (u16*)(ws + OFF_OB);
    u16* hb  = (u16*)(ws + OFF_HB);
    u16* scr = (u16*)(ws + OFF_VTB);   // dead scratch during FFN
    float* x2 = (float*)(ws + OFF_X2);

    // ---- all weight prep: single launch ----
    prep_kernel<<<12304, 256, 0, stream>>>(
        Uq, Uk, Uv, Vq, Vk, Vv, Wo, U1, V1, U2, V2, bq, bk, bv, b1,
        UQKVT, VQKVT, WOB, U1T, V1TP, U2T, V2T, BQKV, B1P);

    // ---- LN1 ----
    ln_kernel<<<1024, 256, 0, stream>>>(x, ln1_g, ln1_b, xn);

    // ---- QKV ----
    gemm_bt64_kernel<<<dim3(24, 32), 256, 0, stream>>>(xn, 1024, UQKVT, tbuf, 1536,
                                                       nullptr, nullptr, 1024, 1);
    qkv2_kernel<<<dim3(8, 32, 3), 256, 0, stream>>>(tbuf, VQKVT, BQKV, qb, kb, vtb);

    // ---- attention ----
    attn_kernel<<<dim3(32, 16), 256, 0, stream>>>(qb, kb, vtb, ob);

    // ---- out proj + residual ----
    gemm_bt64_kernel<<<dim3(16, 32), 256, 0, stream>>>(ob, 1024, WOB, x2, 1024,
                                                       bo, x, 1024, 0);
    // ---- LN2 ----
    ln_kernel<<<1024, 256, 0, stream>>>(x2, ln2_g, ln2_b, xn);

    // ---- FFN ----
    gemm_bt64_kernel<<<dim3(16, 32), 256, 0, stream>>>(xn, 1024, U1T, tbuf, 1024,
                                                       nullptr, nullptr, 1024, 1);
    gemm256_geglu_kernel<0><<<dim3(256), 512, 0, stream>>>(tbuf, V1TP, hb, B1P, 1024);
    // keep V1..V4 instantiated (rule #19 codegen context) without running:
    if (in_sizes[0] < 0) {
        gemm256_geglu_kernel<1><<<dim3(256), 512, 0, stream>>>(tbuf, V1TP, scr, B1P, 1024);
        gemm256_geglu_kernel<2><<<dim3(256), 512, 0, stream>>>(tbuf, V1TP, scr, B1P, 1024);
        gemm256_geglu_kernel<3><<<dim3(256), 512, 0, stream>>>(tbuf, V1TP, scr, B1P, 1024);
        gemm256_geglu_kernel<4><<<dim3(256), 512, 0, stream>>>(tbuf, V1TP, scr, B1P, 1024);
    }
    gemm_bt64_kernel<<<dim3(16, 32), 256, 0, stream>>>(hb, 2048, U2T, tbuf, 1024,
                                                       nullptr, nullptr, 2048, 1);
    gemm_bt64_kernel<<<dim3(16, 32), 256, 0, stream>>>(tbuf, 1024, V2T, out, 1024,
                                                       b2, x2, 1024, 0);
}

// Round 9
// 409.252 us; speedup vs baseline: 1.2952x; 1.0000x over previous
//
#include <hip/hip_runtime.h>

// ============================================================================
// ExplicitSVDBlock round 14:
//  - attn_kernel v9: QBLK 128->256 via 8 waves (512 thr), grid (32,8)=256
//    blocks. Halves K/V staging instrs + LDS-write traffic per output
//    (the one cost that scales with tiling, ~25% of the kt cycle budget).
//    Same math/swizzles/addressing as v8 (r13's +14% win). r11's QBLK=64
//    regression was the inverse move (doubled staging) -- this halves it.
//  - everything else unchanged from r13.
// ============================================================================

typedef unsigned short u16;
typedef unsigned int u32;
typedef u16 u16x8 __attribute__((ext_vector_type(8)));
typedef __bf16 bf16x8 __attribute__((ext_vector_type(8)));
typedef float f32x4 __attribute__((ext_vector_type(4)));

__device__ __forceinline__ u16 f2bf(float f) {
    u32 u = __builtin_bit_cast(u32, f);
    u += 0x7fff + ((u >> 16) & 1);          // RNE
    return (u16)(u >> 16);
}
__device__ __forceinline__ float bf2f(u16 h) {
    u32 u = ((u32)h) << 16;
    return __builtin_bit_cast(float, u);
}
__device__ __forceinline__ u32 packbf(float a, float b) {
    return __builtin_amdgcn_perm(__builtin_bit_cast(u32, b),
                                 __builtin_bit_cast(u32, a), 0x07060302u);
}

__device__ __forceinline__ void gload16(const void* g, void* l) {
    __builtin_amdgcn_global_load_lds(
        (const __attribute__((address_space(1))) void*)g,
        (__attribute__((address_space(3))) void*)l, 16, 0, 0);
}

// ---------------------------------------------------------------------------
// Workspace layout. Total 109 MB.
// ---------------------------------------------------------------------------
#define MB 1048576u
#define OFF_UQKVT (0*MB)    // bf16 [1536][1024]
#define OFF_VQKVT (3*MB)    // bf16 [3][1024][512]
#define OFF_WOB   (6*MB)    // bf16 [1024][1024]
#define OFF_U1T   (8*MB)    // bf16 [1024][1024]
#define OFF_V1TP  (10*MB)   // bf16 [4096][1024]  col-interleaved for geglu
#define OFF_U2T   (18*MB)   // bf16 [1024][2048]
#define OFF_V2T   (22*MB)   // bf16 [1024][1024]
#define OFF_BQKV  (24*MB)   // f32 [3][1024]; +16KB: b1p f32 [4096]
#define OFF_B1P   (24*MB + 16384u)
#define OFF_XN    (25*MB)   // bf16 [4096][1024]
#define OFF_TBUF  (33*MB)   // bf16 [4096][1536]
#define OFF_QB    (45*MB)   // bf16 [4096][1024] (q) -- dead after attn
#define OFF_KB    (53*MB)   // bf16 [4096][1024] (k) -- dead after attn
#define OFF_HB    (45*MB)   // bf16 [4096][2048] (h; reuses q/k space)
#define OFF_VTB   (61*MB)   // bf16 [32][64][2048] -- dead after attn (scratch)
#define OFF_OB    (69*MB)   // bf16 [4096][1024]
#define OFF_X2    (93*MB)   // f32  [4096][1024]

// ---------------------------------------------------------------------------
// Fused weight prep (single launch, block-range dispatch). Grid = 12304.
// ---------------------------------------------------------------------------
__global__ __launch_bounds__(256) void prep_kernel(
    const float* __restrict__ Uq, const float* __restrict__ Uk,
    const float* __restrict__ Uv, const float* __restrict__ Vq,
    const float* __restrict__ Vk, const float* __restrict__ Vv,
    const float* __restrict__ Wo, const float* __restrict__ U1,
    const float* __restrict__ V1, const float* __restrict__ U2,
    const float* __restrict__ V2,
    const float* __restrict__ bq, const float* __restrict__ bk,
    const float* __restrict__ bv, const float* __restrict__ b1,
    u16* __restrict__ UQKVT, u16* __restrict__ VQKVT, u16* __restrict__ WOB,
    u16* __restrict__ U1T, u16* __restrict__ V1TP, u16* __restrict__ U2T,
    u16* __restrict__ V2T, float* __restrict__ BQKV, float* __restrict__ B1P)
{
    __shared__ float tile[32][33];
    int bid = blockIdx.x;

    if (bid >= 12288) {            // biascat
        int id = (bid - 12288) * 256 + threadIdx.x;   // 0..4095
        if (id < 3072) {
            float v = (id < 1024) ? bq[id] : (id < 2048 ? bk[id - 1024] : bv[id - 2048]);
            BQKV[id] = v;
        }
        int g = id >> 7, q = id & 127;
        B1P[id] = b1[(q < 64) ? (g*64 + q) : (2048 + g*64 + (q - 64))];
        return;
    }
    if (bid >= 11264) {            // Wo convert
        int i4 = ((bid - 11264) * 256 + threadIdx.x) * 4;
        float4 v = *(const float4*)(Wo + i4);
        u16 tmp[4] = {f2bf(v.x), f2bf(v.y), f2bf(v.z), f2bf(v.w)};
        *(uint2*)(WOB + i4) = *(const uint2*)tmp;
        return;
    }

    const float* src; u16* dst; int K, N, src_ld, nx; bool gg = false;
    if (bid < 3072) {
        int t = bid / 512; bid -= t * 512;
        if (t < 3) { src = t==0 ? Uq : (t==1 ? Uk : Uv);
                     dst = UQKVT + t * 512*1024; K = 1024; N = 512; src_ld = 512; nx = 16; }
        else { int z = t - 3; src = z==0 ? Vq : (z==1 ? Vk : Vv);
               dst = VQKVT + z * 524288; K = 512; N = 1024; src_ld = 1024; nx = 32; }
    } else if (bid < 4096)  { src = U1; dst = U1T;  K = 1024; N = 1024; src_ld = 1024; nx = 32;  bid -= 3072; }
    else if (bid < 8192)    { src = V1; dst = V1TP; K = 1024; N = 4096; src_ld = 4096; nx = 128; bid -= 4096; gg = true; }
    else if (bid < 10240)   { src = U2; dst = U2T;  K = 2048; N = 1024; src_ld = 1024; nx = 32;  bid -= 8192; }
    else                    { src = V2; dst = V2T;  K = 1024; N = 1024; src_ld = 1024; nx = 32;  bid -= 10240; }

    int tx = threadIdx.x & 31, ty = threadIdx.x >> 5;
    int n0 = (bid % nx) * 32, k0 = (bid / nx) * 32;
    int srccol;
    if (gg) { int p = n0 + tx; int g = p >> 7, q = p & 127;
              srccol = (q < 64) ? (g*64 + q) : (2048 + g*64 + (q - 64)); }
    else srccol = n0 + tx;
    for (int i = 0; i < 4; i++)
        tile[ty + i*8][tx] = src[(size_t)(k0 + ty + i*8) * src_ld + srccol];
    __syncthreads();
    for (int i = 0; i < 4; i++)
        dst[(size_t)(n0 + ty + i*8) * K + k0 + tx] = f2bf(tile[tx][ty + i*8]);
}

// ---------------------------------------------------------------------------
// LayerNorm
// ---------------------------------------------------------------------------
__global__ __launch_bounds__(256) void ln_kernel(
    const float* __restrict__ x, const float* __restrict__ g,
    const float* __restrict__ bta, u16* __restrict__ out)
{
    int w = threadIdx.x >> 6, lane = threadIdx.x & 63;
    int row = blockIdx.x * 4 + w;
    const float* xr = x + (size_t)row * 1024;
    float vals[16];
    float s = 0.f, s2 = 0.f;
    #pragma unroll
    for (int ii = 0; ii < 16; ii++) {
        float v = xr[lane + ii*64];
        vals[ii] = v; s += v; s2 += v * v;
    }
    #pragma unroll
    for (int off = 1; off < 64; off <<= 1) {
        s  += __shfl_xor(s, off);
        s2 += __shfl_xor(s2, off);
    }
    float mu = s * (1.f/1024.f);
    float var = s2 * (1.f/1024.f) - mu * mu;
    float rs = rsqrtf(var + 1e-5f);
    #pragma unroll
    for (int ii = 0; ii < 16; ii++) {
        int col = lane + ii*64;
        out[(size_t)row * 1024 + col] = f2bf((vals[ii] - mu) * rs * g[col] + bta[col]);
    }
}

// ---------------------------------------------------------------------------
// 256x256 pipelined GEMM + fused GEGLU epilogue, template (V0 real;
// V1..V4 instantiated-only to preserve codegen context, rule #19).
// ---------------------------------------------------------------------------
template<int V>
__global__ __launch_bounds__(512, 2) void gemm256_geglu_kernel(
    const u16* __restrict__ A, const u16* __restrict__ Bt,
    u16* __restrict__ hb, const float* __restrict__ bias, int Kdim)
{
    constexpr bool S = (V==0 || V==2 || V==3);   // in-loop staging + vmcnt
    constexpr bool D = (V==0 || V==1 || V==2);   // in-loop fragment ds_reads
    constexpr bool E = (V==0 || V==1 || V==3);   // full GEGLU epilogue

    __shared__ u16 As[2][16384];   // [256 rows][64 cols]
    __shared__ u16 Bs[2][16384];
    int tid = threadIdx.x;
    int wg = (blockIdx.x & 7) * 32 + (blockIdx.x >> 3);
    int m0 = (wg >> 4) * 256, n0 = (wg & 15) * 256;
    int w = tid >> 6, lane = tid & 63, quad = lane >> 4, l15 = lane & 15;
    int wr = (w >> 2) * 16, wc = (w & 3) * 16;
    int xsw = l15 & 7;
    int s0 = (quad ^ xsw) * 8, s1 = s0 ^ 32;   // swizzled K-slot offsets (elems)

    int srow = tid >> 3;                          // 0..63
    int scol = ((tid & 7) ^ (srow & 7)) * 8;      // inverse swizzle on source
    const u16* Ap = A  + (size_t)(m0 + srow) * Kdim + scol;
    const u16* Bp = Bt + (size_t)(n0 + srow) * Kdim + scol;

    int abase = (wr + l15) * 64;   // elem offset of A row (mi=0)
    int bbase = (wc + l15) * 64;   // elem offset of B row (ni=0)

    f32x4 acc[8][4] = {};

#define STG_A(buf, t, h) do {                                                      \
    gload16(Ap + (size_t)(t)*64 + (size_t)((h)*128     )*Kdim,                     \
            &As[buf][(h)*8192 + tid*8]);                                           \
    gload16(Ap + (size_t)(t)*64 + (size_t)((h)*128 + 64)*Kdim,                     \
            &As[buf][(h)*8192 + 4096 + tid*8]);                                    \
} while (0)
#define STG_B(buf, t, h) do {                                                      \
    gload16(Bp + (size_t)(t)*64 + (size_t)((h)*128     )*Kdim,                     \
            &Bs[buf][(h)*8192 + tid*8]);                                           \
    gload16(Bp + (size_t)(t)*64 + (size_t)((h)*128 + 64)*Kdim,                     \
            &Bs[buf][(h)*8192 + 4096 + tid*8]);                                    \
} while (0)
#define SB()  __builtin_amdgcn_sched_barrier(0)

    int nt = Kdim >> 6;   // K-tiles of 64 (V1: 16)

    // ---- prologue: stage tiles 0,1 fully; confirm t0; preload lo frags ----
    STG_A(0, 0, 0); STG_A(0, 0, 1); STG_B(0, 0, 0); STG_B(0, 0, 1);
    STG_A(1, 1, 0); STG_A(1, 1, 1); STG_B(1, 1, 0); STG_B(1, 1, 1);
    asm volatile("s_waitcnt vmcnt(8)" ::: "memory");
    __builtin_amdgcn_s_barrier();
    SB();

    bf16x8 afl[4][2], afh[4][2], bfl[2][2], bfh[2][2];
    {
        const u16* A0 = As[0];
        const u16* B0 = Bs[0];
        #pragma unroll
        for (int i = 0; i < 4; i++) {
            afl[i][0] = *(const bf16x8*)&A0[abase + i*2048 + s0];
            afl[i][1] = *(const bf16x8*)&A0[abase + i*2048 + s1];
        }
        #pragma unroll
        for (int j = 0; j < 2; j++) {
            bfl[j][0] = *(const bf16x8*)&B0[bbase + j*4096 + s0];
            bfl[j][1] = *(const bf16x8*)&B0[bbase + j*4096 + s1];
        }
    }
    if constexpr (!D) {   // V3/V4: init hi frags once (no in-loop reads)
        #pragma unroll
        for (int i = 0; i < 4; i++) { afh[i][0] = afl[i][0]; afh[i][1] = afl[i][1]; }
        #pragma unroll
        for (int j = 0; j < 2; j++) { bfh[j][0] = bfl[j][0]; bfh[j][1] = bfl[j][1]; }
    }

    for (int t = 0; t < nt; ++t) {
        int buf = t & 1;
        const u16* Asc = As[buf];
        const u16* Bsc = Bs[buf];
        const u16* Asn = As[buf ^ 1];
        const u16* Bsn = Bs[buf ^ 1];
        bool more = (t + 1 < nt);
        bool st   = (t + 2 < nt);

        // ---- q0: issue B-hi(t); MFMA lo x lo ----
        if constexpr (D) {
            #pragma unroll
            for (int j = 0; j < 2; j++) {
                bfh[j][0] = *(const bf16x8*)&Bsc[bbase + 8192 + j*4096 + s0];
                bfh[j][1] = *(const bf16x8*)&Bsc[bbase + 8192 + j*4096 + s1];
            }
            SB();
        }
        __builtin_amdgcn_s_setprio(1);
        #pragma unroll
        for (int i = 0; i < 4; i++)
            #pragma unroll
            for (int j = 0; j < 2; j++) {
                acc[i][j] = __builtin_amdgcn_mfma_f32_16x16x32_bf16(afl[i][0], bfl[j][0], acc[i][j], 0, 0, 0);
                acc[i][j] = __builtin_amdgcn_mfma_f32_16x16x32_bf16(afl[i][1], bfl[j][1], acc[i][j], 0, 0, 0);
            }
        __builtin_amdgcn_s_setprio(0);

        // ---- q1: issue A-hi(t); MFMA lo x hi ----
        if constexpr (D) {
            #pragma unroll
            for (int i = 0; i < 4; i++) {
                afh[i][0] = *(const bf16x8*)&Asc[abase + 8192 + i*2048 + s0];
                afh[i][1] = *(const bf16x8*)&Asc[abase + 8192 + i*2048 + s1];
            }
            SB();
        }
        __builtin_amdgcn_s_setprio(1);
        #pragma unroll
        for (int i = 0; i < 4; i++)
            #pragma unroll
            for (int j = 0; j < 2; j++) {
                acc[i][2+j] = __builtin_amdgcn_mfma_f32_16x16x32_bf16(afl[i][0], bfh[j][0], acc[i][2+j], 0, 0, 0);
                acc[i][2+j] = __builtin_amdgcn_mfma_f32_16x16x32_bf16(afl[i][1], bfh[j][1], acc[i][2+j], 0, 0, 0);
            }
        __builtin_amdgcn_s_setprio(0);

        // ---- sync block (once per tile) ----
        if (more) {
            SB();
            asm volatile("s_waitcnt lgkmcnt(0)" ::: "memory");
            __builtin_amdgcn_s_barrier();                        // B1: buf reusable
            SB();
            if constexpr (S) {
                if (st) { STG_A(buf, t+2, 0); STG_A(buf, t+2, 1);
                          STG_B(buf, t+2, 0); STG_B(buf, t+2, 1); }
                SB();
                if (st) asm volatile("s_waitcnt vmcnt(8)" ::: "memory");
                else    asm volatile("s_waitcnt vmcnt(0)" ::: "memory");
            }
            __builtin_amdgcn_s_barrier();                        // B2: buf^1 valid
            SB();
            if constexpr (D) {
                #pragma unroll
                for (int i = 0; i < 4; i++) {
                    afl[i][0] = *(const bf16x8*)&Asn[abase + i*2048 + s0];
                    afl[i][1] = *(const bf16x8*)&Asn[abase + i*2048 + s1];
                }
                SB();
            }
        }

        // ---- q2: MFMA hi x lo ----
        __builtin_amdgcn_s_setprio(1);
        #pragma unroll
        for (int i = 0; i < 4; i++)
            #pragma unroll
            for (int j = 0; j < 2; j++) {
                acc[4+i][j] = __builtin_amdgcn_mfma_f32_16x16x32_bf16(afh[i][0], bfl[j][0], acc[4+i][j], 0, 0, 0);
                acc[4+i][j] = __builtin_amdgcn_mfma_f32_16x16x32_bf16(afh[i][1], bfl[j][1], acc[4+i][j], 0, 0, 0);
            }
        __builtin_amdgcn_s_setprio(0);

        // ---- q3: issue B-lo(t+1); MFMA hi x hi ----
        if constexpr (D) {
            if (more) {
                #pragma unroll
                for (int j = 0; j < 2; j++) {
                    bfl[j][0] = *(const bf16x8*)&Bsn[bbase + j*4096 + s0];
                    bfl[j][1] = *(const bf16x8*)&Bsn[bbase + j*4096 + s1];
                }
                SB();
            }
        }
        __builtin_amdgcn_s_setprio(1);
        #pragma unroll
        for (int i = 0; i < 4; i++)
            #pragma unroll
            for (int j = 0; j < 2; j++) {
                acc[4+i][2+j] = __builtin_amdgcn_mfma_f32_16x16x32_bf16(afh[i][0], bfh[j][0], acc[4+i][2+j], 0, 0, 0);
                acc[4+i][2+j] = __builtin_amdgcn_mfma_f32_16x16x32_bf16(afh[i][1], bfh[j][1], acc[4+i][2+j], 0, 0, 0);
            }
        __builtin_amdgcn_s_setprio(0);
    }
#undef STG_A
#undef STG_B
#undef SB

    if constexpr (E) {
        // ---- GEGLU epilogue: pairs (ni=2p, ni=2p+1) = packed cols c, c+64 ----
        #pragma unroll
        for (int mi = 0; mi < 8; mi++) {
            int row = m0 + wr + mi*32 + quad*4;
            #pragma unroll
            for (int p = 0; p < 2; p++) {
                int c1 = n0 + p*128 + wc + l15;
                float bz1 = bias[c1], bz2 = bias[c1 + 64];
                int hcol = (n0 >> 1) + p*64 + wc + l15;
                #pragma unroll
                for (int r = 0; r < 4; r++) {
                    float z1 = acc[mi][2*p][r] + bz1;
                    float z2 = acc[mi][2*p+1][r] + bz2;
                    float uu = 0.7978845608028654f * (z1 + 0.044715f * z1 * z1 * z1);
                    float e = __expf(2.f * uu);
                    float th = (e - 1.f) / (e + 1.f);
                    float hv = 0.5f * z1 * (1.f + th) * z2;
                    hb[(size_t)(row + r) * 2048 + hcol] = f2bf(hv);
                }
            }
        }
    } else {
        // cheap keep-alive store: sum all acc (keeps every MFMA live, rule #17)
        f32x4 ssum = {};
        #pragma unroll
        for (int mi = 0; mi < 8; mi++)
            #pragma unroll
            for (int j = 0; j < 4; j++)
                ssum += acc[mi][j];
        ((f32x4*)hb)[(size_t)blockIdx.x * 512 + tid] = ssum;
    }
}

// ---------------------------------------------------------------------------
// Pipelined GEMM, 128x64 tile (qkv1, Wo, U1, U2, V2).
// ---------------------------------------------------------------------------
__global__ __launch_bounds__(256) void gemm_bt64_kernel(
    const u16* __restrict__ A, int lda, const u16* __restrict__ Bt,
    void* __restrict__ Cout, int ldc, const float* __restrict__ bias,
    const float* __restrict__ resid, int Kdim, int mode)
{
    __shared__ u16 As[2][4096];
    __shared__ u16 Bs[2][2048];
    int tid = threadIdx.x;
    int m0 = blockIdx.y * 128, n0 = blockIdx.x * 64;
    int w = tid >> 6, lane = tid & 63, quad = lane >> 4, l15 = lane & 15;
    int wm = (w >> 1) * 64, wn = (w & 1) * 32;
    int sr = tid >> 2, sc8 = (tid & 3) * 8;

    f32x4 acc[4][2] = {};

    const u16* Ap = A  + (size_t)(m0 + sr) * lda  + sc8;
    const u16* Bp = Bt + (size_t)(n0 + sr) * Kdim + sc8;   // sr<64 rows of B

    #define GSTAGE64(buf, koff) do {                                       \
        gload16(Ap + (koff),                     &As[buf][tid * 8]);       \
        gload16(Ap + (koff) + (size_t)64 * lda,  &As[buf][2048 + tid*8]);  \
        gload16(Bp + (koff),                     &Bs[buf][tid * 8]);       \
    } while (0)

    GSTAGE64(0, 0);
    __syncthreads();

    for (int k0 = 0; k0 < Kdim; k0 += 32) {
        int cur = (k0 >> 5) & 1;
        if (k0 + 32 < Kdim) GSTAGE64(cur ^ 1, k0 + 32);
        const u16* Asc = As[cur];
        const u16* Bsc = Bs[cur];
        bf16x8 af[4], bfr[2];
        #pragma unroll
        for (int i = 0; i < 4; i++)
            af[i] = *(const bf16x8*)&Asc[(wm + i*16 + l15) * 32 + quad * 8];
        #pragma unroll
        for (int j = 0; j < 2; j++)
            bfr[j] = *(const bf16x8*)&Bsc[(wn + j*16 + l15) * 32 + quad * 8];
        #pragma unroll
        for (int i = 0; i < 4; i++)
            #pragma unroll
            for (int j = 0; j < 2; j++)
                acc[i][j] = __builtin_amdgcn_mfma_f32_16x16x32_bf16(af[i], bfr[j], acc[i][j], 0, 0, 0);
        __syncthreads();
    }
    #undef GSTAGE64

    #pragma unroll
    for (int i = 0; i < 4; i++) {
        int row = m0 + wm + i*16 + quad*4;
        #pragma unroll
        for (int j = 0; j < 2; j++) {
            int col = n0 + wn + j*16 + l15;
            float bv = bias ? bias[col] : 0.f;
            #pragma unroll
            for (int r = 0; r < 4; r++) {
                float v = acc[i][j][r] + bv;
                size_t idx = (size_t)(row + r) * ldc + col;
                if (mode == 0) ((float*)Cout)[idx] = v + resid[idx];
                else           ((u16*)Cout)[idx] = f2bf(v);
            }
        }
    }
}

// ---------------------------------------------------------------------------
// QKV stage-2 batched pipelined GEMM (z: 0=q(+rope,pre-scale) 1=k(+rope) 2=v^T)
// ---------------------------------------------------------------------------
__global__ __launch_bounds__(256) void qkv2_kernel(
    const u16* __restrict__ T, const u16* __restrict__ Vw,
    const float* __restrict__ bqkv, u16* __restrict__ qout,
    u16* __restrict__ kout, u16* __restrict__ vtout)
{
    __shared__ u16 As[2][4096];
    __shared__ u16 Bs[2][4096];
    int tid = threadIdx.x;
    int z = blockIdx.z;
    int m0 = blockIdx.y * 128, n0 = blockIdx.x * 128;
    int w = tid >> 6, lane = tid & 63, quad = lane >> 4, l15 = lane & 15;
    int wm = (w >> 1) * 64, wn = (w & 1) * 64;
    int sr = tid >> 2, sc8 = (tid & 3) * 8;

    f32x4 acc[4][4] = {};

    const u16* Ap = T  + (size_t)z * 512 + (size_t)(m0 + sr) * 1536 + sc8;
    const u16* Bp = Vw + (size_t)z * 512 * 1024 + (size_t)(n0 + sr) * 512 + sc8;

    #define QSTAGE(buf, koff) do {                                        \
        gload16(Ap + (koff),                     &As[buf][tid * 8]);      \
        gload16(Ap + (koff) + (size_t)64 * 1536, &As[buf][2048 + tid*8]); \
        gload16(Bp + (koff),                     &Bs[buf][tid * 8]);      \
        gload16(Bp + (koff) + (size_t)64 * 512,  &Bs[buf][2048 + tid*8]); \
    } while (0)

    QSTAGE(0, 0);
    __syncthreads();

    for (int k0 = 0; k0 < 512; k0 += 32) {
        int cur = (k0 >> 5) & 1;
        if (k0 + 32 < 512) QSTAGE(cur ^ 1, k0 + 32);
        const u16* Asc = As[cur];
        const u16* Bsc = Bs[cur];
        bf16x8 af[4], bfr[4];
        #pragma unroll
        for (int i = 0; i < 4; i++)
            af[i] = *(const bf16x8*)&Asc[(wm + i*16 + l15) * 32 + quad * 8];
        #pragma unroll
        for (int j = 0; j < 4; j++)
            bfr[j] = *(const bf16x8*)&Bsc[(wn + j*16 + l15) * 32 + quad * 8];
        #pragma unroll
        for (int i = 0; i < 4; i++)
            #pragma unroll
            for (int j = 0; j < 4; j++)
                acc[i][j] = __builtin_amdgcn_mfma_f32_16x16x32_bf16(af[i], bfr[j], acc[i][j], 0, 0, 0);
        __syncthreads();
    }
    #undef QSTAGE

    const float* bias = bqkv + z * 1024;
    if (z < 2) {
        u16* Ob = z ? kout : qout;
        float qscale = z ? 1.f : 0.18033688011112042f;   // 0.125*log2(e) folded into q
        #pragma unroll
        for (int i = 0; i < 4; i++) {
            int row0 = m0 + wm + i*16 + quad*4;
            #pragma unroll
            for (int j = 0; j < 2; j++) {
                int col = n0 + wn + j*16 + l15;       // (col&63) < 32
                float bj = bias[col], bj2 = bias[col + 32];
                float invf = exp2f((float)(col & 31) * -0.4152410118609203f);
                #pragma unroll
                for (int r = 0; r < 4; r++) {
                    int t = row0 + r;
                    float fr = (float)(t & 2047) * invf;
                    float sn, cs;
                    __sincosf(fr, &sn, &cs);
                    sn *= qscale; cs *= qscale;
                    float v1 = acc[i][j][r] + bj;
                    float v2 = acc[i][j+2][r] + bj2;
                    Ob[(size_t)t * 1024 + col]      = f2bf(v1 * cs - v2 * sn);
                    Ob[(size_t)t * 1024 + col + 32] = f2bf(v2 * cs + v1 * sn);
                }
            }
        }
    } else {
        int bb = m0 >> 11;
        #pragma unroll
        for (int i = 0; i < 4; i++) {
            int row0 = m0 + wm + i*16 + quad*4;
            #pragma unroll
            for (int j = 0; j < 4; j++) {
                int col = n0 + wn + j*16 + l15;
                float bj = bias[col];
                u16 pack[4];
                #pragma unroll
                for (int r = 0; r < 4; r++) pack[r] = f2bf(acc[i][j][r] + bj);
                size_t dst = ((size_t)(bb * 16 + (col >> 6)) * 64 + (col & 63)) * 2048 + (row0 & 2047);
                *(uint2*)&vtout[dst] = *(const uint2*)pack;
            }
        }
    }
}

// ---------------------------------------------------------------------------
// Flash attention v9: QBLK=256, 8 waves (512 thr), grid (32,8)=256 blocks.
// Halves K/V staging per output vs v8. 2 LDS buffers, compile-time indices,
// hoisted pointers. LDS = 16K(K)+16K(V)+45K(Ps) = 77KB -> 1 block/CU.
// ---------------------------------------------------------------------------
#define PSTR 88
__global__ __launch_bounds__(512) void attn_kernel(
    const u16* __restrict__ Q, const u16* __restrict__ K,
    const u16* __restrict__ Vt, u16* __restrict__ O)
{
    __shared__ u16 Ks[2][64 * 64];
    __shared__ u16 Vs[2][64 * 64];
    __shared__ u16 Ps[256 * PSTR];
    int tid = threadIdx.x;
    int bh = blockIdx.x;
    int b = bh >> 4, h = bh & 15;
    int m0 = blockIdx.y * 256;
    int w = tid >> 6, lane = tid & 63, quad = lane >> 4, l15 = lane & 15;
    int wm = w * 32;                    // 8 waves x 32 q-rows
    size_t qkbase = (size_t)b * 2048 * 1024 + h * 64;
    const u16* Vg = Vt + (size_t)bh * 64 * 2048;

    bf16x8 qf[2][2];
    #pragma unroll
    for (int i = 0; i < 2; i++)
        #pragma unroll
        for (int ks = 0; ks < 2; ks++)
            qf[i][ks] = *(const bf16x8*)(Q + qkbase +
                (size_t)(m0 + wm + i*16 + l15) * 1024 + ks*32 + quad*8);

    f32x4 oacc[2][4] = {};
    float lsum[2] = {};     // per-lane partial row-sum for qrow = wm + i*16 + l15

    int r0 = tid >> 3, p = tid & 7;     // r0: 0..63 with 512 threads
    int c0 = (p ^ (r0 & 7)) * 8;
    int xsw = l15 & 7;

    // hoisted staging pointers (currently at kt=0 tile); advance by consts
    const u16* kp = K + qkbase + (size_t)r0 * 1024 + c0;
    const u16* vp = Vg + (size_t)r0 * 2048 + c0;

    // STG(bufl): stage current-kp/vp tile into LDS buffer literal bufl
    // (512 threads cover the full 64-row K + V tile with 2 loads each)
    #define STG(bufl) do {                                                      \
        gload16(kp, &Ks[bufl][r0 * 64 + p * 8]);                                \
        gload16(vp, &Vs[bufl][r0 * 64 + p * 8]);                                \
        kp += 64*1024; vp += 64;                                                \
    } while (0)

    #define SYNC() do {                                                         \
        asm volatile("s_waitcnt lgkmcnt(0)" ::: "memory");                      \
        asm volatile("s_waitcnt vmcnt(0)" ::: "memory");                        \
        __builtin_amdgcn_s_barrier();                                           \
    } while (0)

    // BODY(bufl): QK^T -> softmax/pack -> PV against LDS buffer literal bufl
    #define BODY(bufl) do {                                                     \
        f32x4 sacc[4][2] = {};                                                  \
        _Pragma("unroll")                                                       \
        for (int ks = 0; ks < 2; ks++) {                                        \
            bf16x8 kf[4];                                                       \
            _Pragma("unroll")                                                   \
            for (int jj = 0; jj < 4; jj++)                                      \
                kf[jj] = *(const bf16x8*)&Ks[bufl][(jj*16 + l15) * 64 +         \
                                                   (((ks*4 + quad) ^ xsw) * 8)];\
            _Pragma("unroll")                                                   \
            for (int jj = 0; jj < 4; jj++)                                      \
                _Pragma("unroll")                                               \
                for (int i = 0; i < 2; i++)                                     \
                    sacc[jj][i] = __builtin_amdgcn_mfma_f32_16x16x32_bf16(      \
                        kf[jj], qf[i][ks], sacc[jj][i], 0, 0, 0);               \
        }                                                                       \
        _Pragma("unroll")                                                       \
        for (int i = 0; i < 2; i++) {                                           \
            int prow = (wm + i*16 + l15) * PSTR + quad*4;                       \
            _Pragma("unroll")                                                   \
            for (int jj = 0; jj < 4; jj++) {                                    \
                float p0 = __builtin_amdgcn_exp2f(sacc[jj][i][0]);              \
                float p1 = __builtin_amdgcn_exp2f(sacc[jj][i][1]);              \
                float p2 = __builtin_amdgcn_exp2f(sacc[jj][i][2]);              \
                float p3 = __builtin_amdgcn_exp2f(sacc[jj][i][3]);              \
                lsum[i] += (p0 + p1) + (p2 + p3);                               \
                uint2 pk; pk.x = packbf(p0, p1); pk.y = packbf(p2, p3);         \
                *(uint2*)&Ps[prow + jj*16] = pk;                                \
            }                                                                   \
        }                                                                       \
        _Pragma("unroll")                                                       \
        for (int ks = 0; ks < 2; ks++) {                                        \
            bf16x8 pf[2], vf[4];                                                \
            _Pragma("unroll")                                                   \
            for (int i = 0; i < 2; i++)                                         \
                pf[i] = *(const bf16x8*)&Ps[(wm + i*16 + l15) * PSTR +          \
                                            ks*32 + quad*8];                    \
            _Pragma("unroll")                                                   \
            for (int j = 0; j < 4; j++)                                         \
                vf[j] = *(const bf16x8*)&Vs[bufl][(j*16 + l15) * 64 +           \
                                                  (((ks*4 + quad) ^ xsw) * 8)]; \
            _Pragma("unroll")                                                   \
            for (int i = 0; i < 2; i++)                                         \
                _Pragma("unroll")                                               \
                for (int j = 0; j < 4; j++)                                     \
                    oacc[i][j] = __builtin_amdgcn_mfma_f32_16x16x32_bf16(       \
                        pf[i], vf[j], oacc[i][j], 0, 0, 0);                     \
        }                                                                       \
    } while (0)

    // prologue: stage kt=0 into buf0 (pointers advance to kt=1)
    STG(0);
    SYNC();

    for (int kt2 = 0; kt2 < 16; ++kt2) {
        // half A: kt = 2*kt2, read buf0; stage kt+1 into buf1 (always valid)
        STG(1);
        BODY(0);
        SYNC();
        // half B: kt = 2*kt2+1, read buf1; stage kt+1 into buf0 (if any)
        if (kt2 < 15) {
            STG(0);
            BODY(1);
            SYNC();
        } else {
            BODY(1);
        }
    }
    #undef STG
    #undef SYNC
    #undef BODY

    // finalize row sums: reduce across quads, then redistribute to C-layout rows
    float inv[2][4];
    #pragma unroll
    for (int i = 0; i < 2; i++) {
        float s = lsum[i];
        s += __shfl_xor(s, 16);
        s += __shfl_xor(s, 32);
        #pragma unroll
        for (int r = 0; r < 4; r++)
            inv[i][r] = 1.f / __shfl(s, (lane & 48) | (quad*4 + r));
    }
    #pragma unroll
    for (int i = 0; i < 2; i++)
        #pragma unroll
        for (int r = 0; r < 4; r++) {
            int row = m0 + wm + i*16 + quad*4 + r;
            #pragma unroll
            for (int j = 0; j < 4; j++)
                O[qkbase + (size_t)row * 1024 + j*16 + l15] = f2bf(oacc[i][j][r] * inv[i][r]);
        }
}

// ---------------------------------------------------------------------------
// Launch
// ---------------------------------------------------------------------------
extern "C" void kernel_launch(void* const* d_in, const int* in_sizes, int n_in,
                              void* d_out, int out_size, void* d_ws, size_t ws_size,
                              hipStream_t stream) {
    (void)n_in; (void)out_size; (void)ws_size;
    const float* x     = (const float*)d_in[0];
    const float* ln1_g = (const float*)d_in[1];
    const float* ln1_b = (const float*)d_in[2];
    const float* Uq    = (const float*)d_in[3];
    const float* Vq    = (const float*)d_in[4];
    const float* bq    = (const float*)d_in[5];
    const float* Uk    = (const float*)d_in[6];
    const float* Vk    = (const float*)d_in[7];
    const float* bk    = (const float*)d_in[8];
    const float* Uv    = (const float*)d_in[9];
    const float* Vv    = (const float*)d_in[10];
    const float* bv    = (const float*)d_in[11];
    const float* Wo    = (const float*)d_in[12];
    const float* bo    = (const float*)d_in[13];
    const float* ln2_g = (const float*)d_in[14];
    const float* ln2_b = (const float*)d_in[15];
    const float* U1    = (const float*)d_in[16];
    const float* V1    = (const float*)d_in[17];
    const float* b1    = (const float*)d_in[18];
    const float* U2    = (const float*)d_in[19];
    const float* V2    = (const float*)d_in[20];
    const float* b2    = (const float*)d_in[21];
    float* out = (float*)d_out;
    char* ws = (char*)d_ws;

    u16* UQKVT = (u16*)(ws + OFF_UQKVT);
    u16* VQKVT = (u16*)(ws + OFF_VQKVT);
    u16* WOB   = (u16*)(ws + OFF_WOB);
    u16* U1T   = (u16*)(ws + OFF_U1T);
    u16* V1TP  = (u16*)(ws + OFF_V1TP);
    u16* U2T   = (u16*)(ws + OFF_U2T);
    u16* V2T   = (u16*)(ws + OFF_V2T);
    float* BQKV = (float*)(ws + OFF_BQKV);
    float* B1P  = (float*)(ws + OFF_B1P);
    u16* xn  = (u16*)(ws + OFF_XN);
    u16* tbuf= (u16*)(ws + OFF_TBUF);
    u16* qb  = (u16*)(ws + OFF_QB);
    u16* kb  = (u16*)(ws + OFF_KB);
    u16* vtb = (u16*)(ws + OFF_VTB);
    u16* ob  = (u16*)(ws + OFF_OB);
    u16* hb  = (u16*)(ws + OFF_HB);
    u16* scr = (u16*)(ws + OFF_VTB);   // dead scratch during FFN
    float* x2 = (float*)(ws + OFF_X2);

    // ---- all weight prep: single launch ----
    prep_kernel<<<12304, 256, 0, stream>>>(
        Uq, Uk, Uv, Vq, Vk, Vv, Wo, U1, V1, U2, V2, bq, bk, bv, b1,
        UQKVT, VQKVT, WOB, U1T, V1TP, U2T, V2T, BQKV, B1P);

    // ---- LN1 ----
    ln_kernel<<<1024, 256, 0, stream>>>(x, ln1_g, ln1_b, xn);

    // ---- QKV ----
    gemm_bt64_kernel<<<dim3(24, 32), 256, 0, stream>>>(xn, 1024, UQKVT, tbuf, 1536,
                                                       nullptr, nullptr, 1024, 1);
    qkv2_kernel<<<dim3(8, 32, 3), 256, 0, stream>>>(tbuf, VQKVT, BQKV, qb, kb, vtb);

    // ---- attention ----
    attn_kernel<<<dim3(32, 8), 512, 0, stream>>>(qb, kb, vtb, ob);

    // ---- out proj + residual ----
    gemm_bt64_kernel<<<dim3(16, 32), 256, 0, stream>>>(ob, 1024, WOB, x2, 1024,
                                                       bo, x, 1024, 0);
    // ---- LN2 ----
    ln_kernel<<<1024, 256, 0, stream>>>(x2, ln2_g, ln2_b, xn);

    // ---- FFN ----
    gemm_bt64_kernel<<<dim3(16, 32), 256, 0, stream>>>(xn, 1024, U1T, tbuf, 1024,
                                                       nullptr, nullptr, 1024, 1);
    gemm256_geglu_kernel<0><<<dim3(256), 512, 0, stream>>>(tbuf, V1TP, hb, B1P, 1024);
    // keep V1..V4 instantiated (rule #19 codegen context) without running:
    if (in_sizes[0] < 0) {
        gemm256_geglu_kernel<1><<<dim3(256), 512, 0, stream>>>(tbuf, V1TP, scr, B1P, 1024);
        gemm256_geglu_kernel<2><<<dim3(256), 512, 0, stream>>>(tbuf, V1TP, scr, B1P, 1024);
        gemm256_geglu_kernel<3><<<dim3(256), 512, 0, stream>>>(tbuf, V1TP, scr, B1P, 1024);
        gemm256_geglu_kernel<4><<<dim3(256), 512, 0, stream>>>(tbuf, V1TP, scr, B1P, 1024);
    }
    gemm_bt64_kernel<<<dim3(16, 32), 256, 0, stream>>>(hb, 2048, U2T, tbuf, 1024,
                                                       nullptr, nullptr, 2048, 1);
    gemm_bt64_kernel<<<dim3(16, 32), 256, 0, stream>>>(tbuf, 1024, V2T, out, 1024,
                                                       b2, x2, 1024, 0);
}